// Round 4
// baseline (3481.544 us; speedup 1.0000x reference)
//
#include <hip/hip_runtime.h>

// TransformerDecoder on MI355X. Round 3: f32-output fix (d_out is float*, not bf16).
// Internals: bf16 MFMA GEMMs, f32 accumulate. Scratch:
//   d_ws: x (2048x1024 f32, 8 MiB) — only ws use
//   d_out logits region (262 MB f32, dead until final GEMM) hosts:
//     [0,8)   S0 f32   \
//     [8,16)  S1 f32    \ q/k/v/attn scratch; S0..S3 doubles as FFN hidden
//     [16,24) S2 f32    /
//     [24,32) S3 f32   /
//     [32,40) S4 f32  FFN2 out
//     [40,44) vt bf16 (B,H,dk,T)

typedef unsigned short u16;
typedef __bf16 v8bf __attribute__((ext_vector_type(8)));
typedef float v4f __attribute__((ext_vector_type(4)));

namespace {
constexpr int kB = 4, kT = 512, kD = 1024, kH = 16, kDK = 64, kF = 4096, kV = 32000, kL = 4;
constexpr int kM = kB * kT;                       // 2048 rows
constexpr long kTD = (long)kT * kD;               // 524288
constexpr long kTT = (long)kT * kT;               // 262144
constexpr long kHTT = (long)kH * kTT;             // 4194304 (per batch b)
constexpr long kBHTT = (long)kB * kHTT;           // 16777216 (per layer)
constexpr long kLOG = (long)kM * kV;              // 65536000 logits elems
}

__device__ __forceinline__ u16 f2bf(float f) {
  union { float f; unsigned u; } v; v.f = f;
  unsigned r = v.u + 0x7FFFu + ((v.u >> 16) & 1u);
  return (u16)(r >> 16);
}
__device__ __forceinline__ float bf2f(u16 h) {
  union { unsigned u; float f; } v; v.u = ((unsigned)h) << 16;
  return v.f;
}

// ---------------------------------------------------------------------------
// Generic GEMM: C[m][n] = scale * sum_k A[m][k] * B(n,k) + bias[n]  (opt relu)
// A: (M,K) lda, f32 or bf16.
// BKN=0: B is (N,K) ldb, f32 or bf16.  BKN=1: B is (K,N) ldb, f32 only
// (weights as stored; transposed into LDS on the fly).
// Batched via blockIdx.z with (b,h) = (z/nH, z%nH) offsets. C written f32.
// 256 threads = 4 waves (2x2), per-wave (BM/2)x(BN/2), mfma_f32_16x16x32_bf16.
// ---------------------------------------------------------------------------
template <int BM, int BN, typename TA, typename TB, int BKN>
__global__ __launch_bounds__(256)
void gemm_kernel(const void* __restrict__ Av, const void* __restrict__ Bv,
                 const float* __restrict__ bias, float* __restrict__ Cv,
                 const int K, const int lda, const int ldb, const int ldc,
                 const int nH, const long sAb, const long sAh,
                 const long sBb, const long sBh, const long sCb, const long sCh,
                 const float scale, const int relu) {
  static_assert(BM % 32 == 0 && BN % 32 == 0, "tiles");
  static_assert(BKN == 0 || sizeof(TB) == 4, "BKN path is f32 only");
  constexpr int LP = 40;  // padded LDS stride (u16): 80B rows -> conflict-free b128
  __shared__ u16 As[BM][LP];
  __shared__ u16 Bs[BN][LP];
  const int tid = threadIdx.x;
  const int z = blockIdx.z;
  const int zb = z / nH, zh = z - zb * nH;
  const TA* A = (const TA*)Av + zb * sAb + zh * sAh + (long)blockIdx.y * BM * lda;
  const TB* Bp;
  if constexpr (BKN)
    Bp = (const TB*)Bv + zb * sBb + zh * sBh + (long)blockIdx.x * BN;       // col offset
  else
    Bp = (const TB*)Bv + zb * sBb + zh * sBh + (long)blockIdx.x * BN * ldb; // row offset
  const long offC = zb * sCb + zh * sCh;
  const int lane = tid & 63;
  const int wm = (tid >> 7) & 1, wn = (tid >> 6) & 1;
  constexpr int FM = BM / 32, FN = BN / 32;
  v4f acc[FM][FN];
  const v4f zero = {0.f, 0.f, 0.f, 0.f};
#pragma unroll
  for (int i = 0; i < FM; ++i)
#pragma unroll
    for (int j = 0; j < FN; ++j) acc[i][j] = zero;
  const int l15 = lane & 15, lk = lane >> 4;

  for (int k0 = 0; k0 < K; k0 += 32) {
    __syncthreads();
    // ---- stage A tile into LDS (bf16) ----
    if constexpr (sizeof(TA) == 4) {
      const int r = tid >> 3, c = (tid & 7) * 4;
#pragma unroll
      for (int rr = 0; rr < BM; rr += 32) {
        float4 vv = *(const float4*)((const float*)A + (long)(rr + r) * lda + k0 + c);
        unsigned lo = (unsigned)f2bf(vv.x) | ((unsigned)f2bf(vv.y) << 16);
        unsigned hi = (unsigned)f2bf(vv.z) | ((unsigned)f2bf(vv.w) << 16);
        *(uint2*)&As[rr + r][c] = make_uint2(lo, hi);
      }
    } else {
      const int r = tid >> 2, c = (tid & 3) * 8;
#pragma unroll
      for (int rr = 0; rr < BM; rr += 64) {
        uint4 vv = *(const uint4*)((const u16*)A + (long)(rr + r) * lda + k0 + c);
        *(uint4*)&As[rr + r][c] = vv;
      }
    }
    // ---- stage B tile ----
    if constexpr (BKN) {
      // B is (K,N): read 32 k-rows x BN cols, write transposed into Bs[n][k]
      const int r = tid >> 3, c = (tid & 7) * 4;
#pragma unroll
      for (int nn = 0; nn < BN; nn += 32) {
        float4 vv = *(const float4*)((const float*)Bp + (long)(k0 + r) * ldb + nn + c);
        Bs[nn + c + 0][r] = f2bf(vv.x);
        Bs[nn + c + 1][r] = f2bf(vv.y);
        Bs[nn + c + 2][r] = f2bf(vv.z);
        Bs[nn + c + 3][r] = f2bf(vv.w);
      }
    } else if constexpr (sizeof(TB) == 4) {
      const int r = tid >> 3, c = (tid & 7) * 4;
#pragma unroll
      for (int rr = 0; rr < BN; rr += 32) {
        float4 vv = *(const float4*)((const float*)Bp + (long)(rr + r) * ldb + k0 + c);
        unsigned lo = (unsigned)f2bf(vv.x) | ((unsigned)f2bf(vv.y) << 16);
        unsigned hi = (unsigned)f2bf(vv.z) | ((unsigned)f2bf(vv.w) << 16);
        *(uint2*)&Bs[rr + r][c] = make_uint2(lo, hi);
      }
    } else {
      const int r = tid >> 2, c = (tid & 3) * 8;
#pragma unroll
      for (int rr = 0; rr < BN; rr += 64) {
        uint4 vv = *(const uint4*)((const u16*)Bp + (long)(rr + r) * ldb + k0 + c);
        *(uint4*)&Bs[rr + r][c] = vv;
      }
    }
    __syncthreads();
    // ---- fragments + MFMA ----
    v8bf af[FM], bfr[FN];
#pragma unroll
    for (int i = 0; i < FM; ++i)
      af[i] = *(const v8bf*)&As[wm * (BM / 2) + i * 16 + l15][lk * 8];
#pragma unroll
    for (int j = 0; j < FN; ++j)
      bfr[j] = *(const v8bf*)&Bs[wn * (BN / 2) + j * 16 + l15][lk * 8];
#pragma unroll
    for (int i = 0; i < FM; ++i)
#pragma unroll
      for (int j = 0; j < FN; ++j)
        acc[i][j] = __builtin_amdgcn_mfma_f32_16x16x32_bf16(af[i], bfr[j], acc[i][j], 0, 0, 0);
  }

  // ---- epilogue: C/D layout col=lane&15, row=(lane>>4)*4+r ----
  const long m0 = (long)blockIdx.y * BM + wm * (BM / 2);
  const int n0 = blockIdx.x * BN + wn * (BN / 2);
#pragma unroll
  for (int j = 0; j < FN; ++j) {
    const int col = n0 + j * 16 + l15;
    const float bv = bias ? bias[col] : 0.0f;
#pragma unroll
    for (int i = 0; i < FM; ++i) {
      const long row = m0 + i * 16 + lk * 4;
#pragma unroll
      for (int r = 0; r < 4; ++r) {
        float v = acc[i][j][r] * scale + bv;
        if (relu) v = fmaxf(v, 0.0f);
        Cv[offC + (row + r) * ldc + col] = v;
      }
    }
  }
}

// ---------------------------------------------------------------------------
// x[b,t,:] = emb[tgt[b,t],:] * 32 + PE(t,:)
// ---------------------------------------------------------------------------
__global__ void embed_kernel(const int* __restrict__ tgt, const float* __restrict__ emb,
                             float* __restrict__ x) {
  const int row = blockIdx.x;           // b*T + t
  const int t = row & (kT - 1);
  const int tok = tgt[row];
  const int c = threadIdx.x * 4;
  float4 e = *(const float4*)(emb + (long)tok * kD + c);
  const float nl = -9.210340371976184f / (float)kD;   // -ln(10000)/D
  const float a0 = (float)t * expf((float)c * nl);
  const float a1 = (float)t * expf((float)(c + 2) * nl);
  float4 o;
  o.x = e.x * 32.0f + sinf(a0);
  o.y = e.y * 32.0f + cosf(a0);
  o.z = e.z * 32.0f + sinf(a1);
  o.w = e.w * 32.0f + cosf(a1);
  *(float4*)(x + (long)row * kD + c) = o;
}

// v (B,T,D) f32, head-sliced -> vt (B*H, dk, T) bf16
__global__ void transpose_v_kernel(const float* __restrict__ v, u16* __restrict__ vt) {
  __shared__ float tile[32][33];
  const int z = blockIdx.z;             // b*H + h
  const int b = z >> 4, h = z & 15;
  const int t0 = blockIdx.x * 32, d0 = blockIdx.y * 32;
  const int tx = threadIdx.x, ty = threadIdx.y;
  const float* in = v + (long)b * kTD + (long)h * kDK;
#pragma unroll
  for (int i = 0; i < 4; ++i)
    tile[ty + 8 * i][tx] = in[(long)(t0 + ty + 8 * i) * kD + d0 + tx];
  __syncthreads();
  u16* o = vt + (long)z * kDK * kT;
#pragma unroll
  for (int i = 0; i < 4; ++i)
    o[(long)(d0 + ty + 8 * i) * kT + t0 + tx] = f2bf(tile[tx][ty + 8 * i]);
}

// ---------------------------------------------------------------------------
// In-place row softmax over f32 rows of 512. One wave per row, 4 rows/block.
// causal: cols > (row % 512) -> exactly 0 (matches ref's exp(-1e9-max) underflow).
// ---------------------------------------------------------------------------
__global__ void softmax_kernel(float* __restrict__ w, const int causal) {
  const int rowg = blockIdx.x * 4 + (threadIdx.x >> 6);
  const int lane = threadIdx.x & 63;
  const int q = rowg & (kT - 1);
  float* p = w + (long)rowg * kT + lane * 8;
  float4 v0 = *(const float4*)p;
  float4 v1 = *(const float4*)(p + 4);
  float f[8] = {v0.x, v0.y, v0.z, v0.w, v1.x, v1.y, v1.z, v1.w};
  const int base = lane * 8;
  float mx = -3.0e38f;
#pragma unroll
  for (int j = 0; j < 8; ++j)
    if (!causal || base + j <= q) mx = fmaxf(mx, f[j]);
#pragma unroll
  for (int o = 32; o > 0; o >>= 1) mx = fmaxf(mx, __shfl_xor(mx, o));
  float s = 0.0f;
#pragma unroll
  for (int j = 0; j < 8; ++j) {
    float e = (!causal || base + j <= q) ? __expf(f[j] - mx) : 0.0f;
    f[j] = e; s += e;
  }
#pragma unroll
  for (int o = 32; o > 0; o >>= 1) s += __shfl_xor(s, o);
  const float inv = 1.0f / s;
  float4 o0 = {f[0] * inv, f[1] * inv, f[2] * inv, f[3] * inv};
  float4 o1 = {f[4] * inv, f[5] * inv, f[6] * inv, f[7] * inv};
  *(float4*)p = o0;
  *(float4*)(p + 4) = o1;
}

// ---------------------------------------------------------------------------
// x = LayerNorm(x + res) * g + b, in place on x. One block per row of 1024.
// ---------------------------------------------------------------------------
__global__ void add_ln_kernel(float* __restrict__ x, const float* __restrict__ res,
                              const float* __restrict__ g, const float* __restrict__ b) {
  const int row = blockIdx.x;
  const int c = threadIdx.x * 4;
  float4 xv = *(const float4*)(x + (long)row * kD + c);
  float4 rv = *(const float4*)(res + (long)row * kD + c);
  const float v0 = xv.x + rv.x, v1 = xv.y + rv.y, v2 = xv.z + rv.z, v3 = xv.w + rv.w;
  float s = v0 + v1 + v2 + v3;
  float ss = v0 * v0 + v1 * v1 + v2 * v2 + v3 * v3;
#pragma unroll
  for (int o = 32; o > 0; o >>= 1) { s += __shfl_xor(s, o); ss += __shfl_xor(ss, o); }
  __shared__ float red[4][2];
  const int wv = threadIdx.x >> 6;
  if ((threadIdx.x & 63) == 0) { red[wv][0] = s; red[wv][1] = ss; }
  __syncthreads();
  s  = red[0][0] + red[1][0] + red[2][0] + red[3][0];
  ss = red[0][1] + red[1][1] + red[2][1] + red[3][1];
  const float mean = s * (1.0f / kD);
  const float var = ss * (1.0f / kD) - mean * mean;
  const float rs = rsqrtf(var + 1e-5f);
  float4 gv = *(const float4*)(g + c);
  float4 bv = *(const float4*)(b + c);
  float4 o;
  o.x = gv.x * (v0 - mean) * rs + bv.x;
  o.y = gv.y * (v1 - mean) * rs + bv.y;
  o.z = gv.z * (v2 - mean) * rs + bv.z;
  o.w = gv.w * (v3 - mean) * rs + bv.w;
  *(float4*)(x + (long)row * kD + c) = o;
}

// ---------------------------------------------------------------------------
extern "C" void kernel_launch(void* const* d_in, const int* in_sizes, int n_in,
                              void* d_out, int out_size, void* d_ws, size_t ws_size,
                              hipStream_t stream) {
  const int*   tgt  = (const int*)d_in[0];
  const float* enc  = (const float*)d_in[1];
  const float* emb  = (const float*)d_in[3];
  const float* Wout = (const float*)d_in[4];
  const float* bout = (const float*)d_in[5];
  const float* Wq_s = (const float*)d_in[6];
  const float* bq_s = (const float*)d_in[7];
  const float* Wk_s = (const float*)d_in[8];
  const float* bk_s = (const float*)d_in[9];
  const float* Wv_s = (const float*)d_in[10];
  const float* bv_s = (const float*)d_in[11];
  const float* Wo_s = (const float*)d_in[12];
  const float* bo_s = (const float*)d_in[13];
  const float* Wq_c = (const float*)d_in[14];
  const float* bq_c = (const float*)d_in[15];
  const float* Wk_c = (const float*)d_in[16];
  const float* bk_c = (const float*)d_in[17];
  const float* Wv_c = (const float*)d_in[18];
  const float* bv_c = (const float*)d_in[19];
  const float* Wo_c = (const float*)d_in[20];
  const float* bo_c = (const float*)d_in[21];
  const float* W1   = (const float*)d_in[22];
  const float* b1   = (const float*)d_in[23];
  const float* W2   = (const float*)d_in[24];
  const float* b2   = (const float*)d_in[25];
  const float* ln1g = (const float*)d_in[26];
  const float* ln1b = (const float*)d_in[27];
  const float* ln2g = (const float*)d_in[28];
  const float* ln2b = (const float*)d_in[29];
  const float* ln3g = (const float*)d_in[30];
  const float* ln3b = (const float*)d_in[31];

  float* out = (float*)d_out;           // f32 output!
  float* x = (float*)d_ws;              // 8 MiB — only ws use

  // Scratch inside the logits region of d_out (262 MB f32, dead until final GEMM).
  char* sc = (char*)d_out;
  float* S0 = (float*)sc;
  float* S1 = (float*)(sc + (8l  << 20));
  float* S2 = (float*)(sc + (16l << 20));
  float* S3 = (float*)(sc + (24l << 20));
  float* S4 = (float*)(sc + (32l << 20));
  u16*   vt = (u16*)  (sc + (40l << 20));  // 4 MiB

  const long DD = (long)kD * kD;
  const dim3 blk256(256), blkT(32, 8);

  embed_kernel<<<dim3(kM), blk256, 0, stream>>>(tgt, emb, x);

  // (M=2048, N=1024, K=1024): C = A @ W + bias, W given as (K,N) f32
  auto wgemm = [&](const float* A, const float* W, const float* bias, float* C) {
    gemm_kernel<128, 128, float, float, 1><<<dim3(kD / 128, kM / 128, 1), blk256, 0, stream>>>(
        A, W, bias, C, kD, kD, kD, kD, 1, 0, 0, 0, 0, 0, 0, 1.0f, 0);
  };

  for (int i = 0; i < kL; ++i) {
    const long wOff = (long)i * DD;
    float* wSelf  = out + kLOG + (long)i * kBHTT;
    float* wCross = out + kLOG + (long)kL * kBHTT + (long)i * kBHTT;

    // ---------------- self attention ----------------
    wgemm(x, Wq_s + wOff, bq_s + (long)i * kD, S0);
    wgemm(x, Wk_s + wOff, bk_s + (long)i * kD, S1);
    wgemm(x, Wv_s + wOff, bv_s + (long)i * kD, S2);
    transpose_v_kernel<<<dim3(16, 2, 64), blkT, 0, stream>>>(S2, vt);
    // scores = q @ k^T / 8 -> f32 into d_out
    gemm_kernel<128, 128, float, float, 0><<<dim3(4, 4, 64), blk256, 0, stream>>>(
        S0, S1, nullptr, wSelf, kDK, kD, kD, kT,
        kH, kTD, (long)kDK, kTD, (long)kDK, kHTT, kTT, 0.125f, 0);
    softmax_kernel<<<dim3(kB * kH * kT / 4), blk256, 0, stream>>>(wSelf, 1);
    // attn = P @ V -> S3 (B,T,D)
    gemm_kernel<128, 64, float, u16, 0><<<dim3(1, 4, 64), blk256, 0, stream>>>(
        wSelf, vt, nullptr, S3, kT, kT, kT, kD,
        kH, kHTT, kTT, (long)kH * kDK * kT, (long)kDK * kT, kTD, (long)kDK, 1.0f, 0);
    wgemm(S3, Wo_s + wOff, bo_s + (long)i * kD, S0);
    add_ln_kernel<<<dim3(kM), blk256, 0, stream>>>(x, S0, ln1g + (long)i * kD, ln1b + (long)i * kD);

    // ---------------- cross attention ----------------
    wgemm(x,   Wq_c + wOff, bq_c + (long)i * kD, S0);
    wgemm(enc, Wk_c + wOff, bk_c + (long)i * kD, S1);
    wgemm(enc, Wv_c + wOff, bv_c + (long)i * kD, S2);
    transpose_v_kernel<<<dim3(16, 2, 64), blkT, 0, stream>>>(S2, vt);
    gemm_kernel<128, 128, float, float, 0><<<dim3(4, 4, 64), blk256, 0, stream>>>(
        S0, S1, nullptr, wCross, kDK, kD, kD, kT,
        kH, kTD, (long)kDK, kTD, (long)kDK, kHTT, kTT, 0.125f, 0);
    softmax_kernel<<<dim3(kB * kH * kT / 4), blk256, 0, stream>>>(wCross, 0);
    gemm_kernel<128, 64, float, u16, 0><<<dim3(1, 4, 64), blk256, 0, stream>>>(
        wCross, vt, nullptr, S3, kT, kT, kT, kD,
        kH, kHTT, kTT, (long)kH * kDK * kT, (long)kDK * kT, kTD, (long)kDK, 1.0f, 0);
    wgemm(S3, Wo_c + wOff, bo_c + (long)i * kD, S0);
    add_ln_kernel<<<dim3(kM), blk256, 0, stream>>>(x, S0, ln2g + (long)i * kD, ln2b + (long)i * kD);

    // ---------------- FFN ----------------
    gemm_kernel<128, 128, float, float, 1><<<dim3(kF / 128, kM / 128, 1), blk256, 0, stream>>>(
        x, W1 + (long)i * kD * kF, b1 + (long)i * kF, S0, kD, kD, kF, kF,
        1, 0, 0, 0, 0, 0, 0, 1.0f, 1);
    gemm_kernel<128, 128, float, float, 1><<<dim3(kD / 128, kM / 128, 1), blk256, 0, stream>>>(
        S0, W2 + (long)i * kF * kD, b2 + (long)i * kD, S4, kF, kF, kD, kD,
        1, 0, 0, 0, 0, 0, 0, 1.0f, 0);
    add_ln_kernel<<<dim3(kM), blk256, 0, stream>>>(x, S4, ln3g + (long)i * kD, ln3b + (long)i * kD);
  }

  // ---------------- logits (overwrites scratch region; reads only x/Wout) ----
  gemm_kernel<128, 128, float, float, 1><<<dim3(kV / 128, kM / 128, 1), blk256, 0, stream>>>(
      x, Wout, bout, out, kD, kD, kV, kV,
      1, 0, 0, 0, 0, 0, 0, 1.0f, 0);
}

// Round 5
// 2149.817 us; speedup vs baseline: 1.6195x; 1.6195x over previous
//
#include <hip/hip_runtime.h>

// TransformerDecoder on MI355X. Round 4: bf16 end-to-end GEMM path.
// - Weights pre-transposed once per launch to bf16 (N,K) in d_ws (~196 MiB).
// - Activations kept in bf16 shadow buffers (written in GEMM/LN epilogues).
// - GEMM: m97-style 128x128 tile, linear LDS, global_load_lds width-16.
// - Fallback to the proven Round-3 f32-staging path if ws_size is small.

typedef unsigned short u16;
typedef __bf16 v8bf __attribute__((ext_vector_type(8)));
typedef float v4f __attribute__((ext_vector_type(4)));

namespace {
constexpr int kB = 4, kT = 512, kD = 1024, kH = 16, kDK = 64, kF = 4096, kV = 32000, kL = 4;
constexpr int kM = kB * kT;                       // 2048 rows
constexpr long kTD = (long)kT * kD;               // 524288
constexpr long kTT = (long)kT * kT;               // 262144
constexpr long kHTT = (long)kH * kTT;             // 4194304 (per batch b)
constexpr long kBHTT = (long)kB * kHTT;           // 16777216 (per layer)
constexpr long kLOG = (long)kM * kV;              // 65536000 logits elems
}

__device__ __forceinline__ u16 f2bf(float f) {
  union { float f; unsigned u; } v; v.f = f;
  unsigned r = v.u + 0x7FFFu + ((v.u >> 16) & 1u);
  return (u16)(r >> 16);
}
__device__ __forceinline__ float bf2f(u16 h) {
  union { unsigned u; float f; } v; v.u = ((unsigned)h) << 16;
  return v.f;
}

// ===========================================================================
// NEW FAST PATH
// ===========================================================================
typedef __attribute__((address_space(3))) void lds_void;
typedef const __attribute__((address_space(1))) void glob_void;

__device__ __forceinline__ void gl2lds16(const void* g, void* l) {
  __builtin_amdgcn_global_load_lds((glob_void*)g, (lds_void*)l, 16, 0, 0);
}

// ---------------------------------------------------------------------------
// bf16 GEMM: C[m][n] = scale * sum_k A[m][k]*B[n][k] + bias[n] (opt relu)
// A (M,K) bf16 lda; B (N,K) bf16 ldb; C f32 (OUTBF=0) or bf16 (OUTBF=1).
// Batched via blockIdx.z, (b,h)=(z/nH, z%nH). Staging: global_load_lds x16B,
// linear LDS [*][32] (m97 structure). 4 waves, per-wave (BM/2)x(BN/2).
// ---------------------------------------------------------------------------
template <int BM, int BN, int OUTBF>
__global__ __launch_bounds__(256)
void gemm_bf(const u16* __restrict__ A0, const u16* __restrict__ B0,
             const float* __restrict__ bias, void* __restrict__ Cv,
             const int K, const int lda, const int ldb, const int ldc,
             const int nH, const long sAb, const long sAh,
             const long sBb, const long sBh, const long sCb, const long sCh,
             const float scale, const int relu) {
  static_assert(BM % 64 == 0 && BN % 64 == 0, "tiles");
  __shared__ u16 As[BM][32];
  __shared__ u16 Bs[BN][32];
  const int tid = threadIdx.x;
  const int lane = tid & 63;
  const int w = tid >> 6;
  const int z = blockIdx.z;
  const int zb = z / nH, zh = z - zb * nH;
  const u16* A = A0 + zb * sAb + zh * sAh + (long)blockIdx.y * BM * lda;
  const u16* B = B0 + zb * sBb + zh * sBh + (long)blockIdx.x * BN * ldb;
  const long offC = zb * sCb + zh * sCh;
  const int wm = w >> 1, wn = w & 1;
  constexpr int FM = BM / 32, FN = BN / 32;
  v4f acc[FM][FN];
  const v4f zero = {0.f, 0.f, 0.f, 0.f};
#pragma unroll
  for (int i = 0; i < FM; ++i)
#pragma unroll
    for (int j = 0; j < FN; ++j) acc[i][j] = zero;
  const int l15 = lane & 15, lk = lane >> 4;
  const int lr = lane >> 2;          // 0..15 row within 16-row stripe
  const int lc = (lane & 3) * 8;     // elem col: 0,8,16,24

  for (int k0 = 0; k0 < K; k0 += 32) {
    __syncthreads();
    // wave w stages 16-row stripes; LDS dest = wave-uniform base + lane*16B
#pragma unroll
    for (int rd = 0; rd < BM / 64; ++rd)
      gl2lds16(A + (long)(rd * 64 + w * 16 + lr) * lda + k0 + lc,
               &As[rd * 64 + w * 16][0]);
#pragma unroll
    for (int rd = 0; rd < BN / 64; ++rd)
      gl2lds16(B + (long)(rd * 64 + w * 16 + lr) * ldb + k0 + lc,
               &Bs[rd * 64 + w * 16][0]);
    __syncthreads();   // compiler drains vmcnt here (m97 semantics)
    v8bf af[FM], bfr[FN];
#pragma unroll
    for (int i = 0; i < FM; ++i)
      af[i] = *(const v8bf*)&As[wm * (BM / 2) + i * 16 + l15][lk * 8];
#pragma unroll
    for (int j = 0; j < FN; ++j)
      bfr[j] = *(const v8bf*)&Bs[wn * (BN / 2) + j * 16 + l15][lk * 8];
#pragma unroll
    for (int i = 0; i < FM; ++i)
#pragma unroll
      for (int j = 0; j < FN; ++j)
        acc[i][j] = __builtin_amdgcn_mfma_f32_16x16x32_bf16(af[i], bfr[j], acc[i][j], 0, 0, 0);
  }

  // epilogue: C/D layout col=lane&15, row=(lane>>4)*4+r
  const long m0 = (long)blockIdx.y * BM + wm * (BM / 2);
  const int n0 = blockIdx.x * BN + wn * (BN / 2);
#pragma unroll
  for (int j = 0; j < FN; ++j) {
    const int col = n0 + j * 16 + l15;
    const float bv = bias ? bias[col] : 0.0f;
#pragma unroll
    for (int i = 0; i < FM; ++i) {
      const long row = m0 + i * 16 + lk * 4;
#pragma unroll
      for (int r = 0; r < 4; ++r) {
        float v = acc[i][j][r] * scale + bv;
        if (relu) v = fmaxf(v, 0.0f);
        const long idx = offC + (row + r) * ldc + col;
        if (OUTBF) ((u16*)Cv)[idx] = f2bf(v);
        else       ((float*)Cv)[idx] = v;
      }
    }
  }
}

// Weight transpose-convert: out(N,K) bf16 = in(K,N)^T f32; batched ptr pairs.
struct TPtrs { const float* in[8]; u16* out[8]; };

__global__ void transpose_wt_v2(TPtrs ps, int K, int N) {
  __shared__ float tile[32][33];
  const float* in = ps.in[blockIdx.z];
  u16* o = ps.out[blockIdx.z];
  const int n0 = blockIdx.x * 32, k0 = blockIdx.y * 32;
  const int tx = threadIdx.x, ty = threadIdx.y;
#pragma unroll
  for (int i = 0; i < 4; ++i)
    tile[ty + 8 * i][tx] = in[(long)(k0 + ty + 8 * i) * N + n0 + tx];
  __syncthreads();
#pragma unroll
  for (int i = 0; i < 4; ++i)
    o[(long)(n0 + ty + 8 * i) * K + k0 + tx] = f2bf(tile[tx][ty + 8 * i]);
}

// bias concat: dst[l*nsrc*1024 + s*1024 + j] = src_s[l*1024 + j]
__global__ void concat_bias(float* __restrict__ dst, const float* __restrict__ s0,
                            const float* __restrict__ s1, const float* __restrict__ s2,
                            const int nsrc) {
  const int idx = blockIdx.x * 256 + threadIdx.x;
  const int per = nsrc << 10;
  const int l = idx / per, rem = idx - l * per, s = rem >> 10, j = rem & 1023;
  const float* src = (s == 0) ? s0 : (s == 1 ? s1 : s2);
  dst[idx] = src[l * 1024 + j];
}

// f32 -> bf16 bulk convert (float4 per thread)
__global__ void cvt_bf16_v2(const float* __restrict__ in, u16* __restrict__ o) {
  const long i = ((long)blockIdx.x * 256 + threadIdx.x) * 4;
  float4 v = *(const float4*)(in + i);
  u16 h[4] = {f2bf(v.x), f2bf(v.y), f2bf(v.z), f2bf(v.w)};
  *(uint2*)(o + i) = *(const uint2*)h;
}

// embed: x f32 + xb bf16
__global__ void embed_v2(const int* __restrict__ tgt, const float* __restrict__ emb,
                         float* __restrict__ x, u16* __restrict__ xb) {
  const int row = blockIdx.x;
  const int t = row & (kT - 1);
  const int tok = tgt[row];
  const int c = threadIdx.x * 4;
  float4 e = *(const float4*)(emb + (long)tok * kD + c);
  const float nl = -9.210340371976184f / (float)kD;
  const float a0 = (float)t * expf((float)c * nl);
  const float a1 = (float)t * expf((float)(c + 2) * nl);
  float4 o;
  o.x = e.x * 32.0f + sinf(a0);
  o.y = e.y * 32.0f + cosf(a0);
  o.z = e.z * 32.0f + sinf(a1);
  o.w = e.w * 32.0f + cosf(a1);
  *(float4*)(x + (long)row * kD + c) = o;
  u16 h[4] = {f2bf(o.x), f2bf(o.y), f2bf(o.z), f2bf(o.w)};
  *(uint2*)(xb + (long)row * kD + c) = *(const uint2*)h;
}

// V slice of Sqkv (2048,3072) -> vt (B*H, dk, T) bf16
__global__ void transpose_v_v2(const u16* __restrict__ Sqkv, u16* __restrict__ vt) {
  __shared__ u16 tile[32][33];
  const int z = blockIdx.z, b = z >> 4, h = z & 15;
  const int t0 = blockIdx.x * 32, d0 = blockIdx.y * 32;
  const int tx = threadIdx.x, ty = threadIdx.y;
  const u16* in = Sqkv + (long)b * kT * 3072 + 2048 + h * kDK;
#pragma unroll
  for (int i = 0; i < 4; ++i)
    tile[ty + 8 * i][tx] = in[(long)(t0 + ty + 8 * i) * 3072 + d0 + tx];
  __syncthreads();
  u16* o = vt + (long)z * kDK * kT;
#pragma unroll
  for (int i = 0; i < 4; ++i)
    o[(long)(d0 + ty + 8 * i) * kT + t0 + tx] = tile[tx][ty + 8 * i];
}

// softmax in place on f32 rows of 512, plus bf16 copy for PV A-operand.
__global__ void softmax_v2(float* __restrict__ w, u16* __restrict__ pb, const int causal) {
  const int rowg = blockIdx.x * 4 + (threadIdx.x >> 6);
  const int lane = threadIdx.x & 63;
  const int q = rowg & (kT - 1);
  float* p = w + (long)rowg * kT + lane * 8;
  float4 v0 = *(const float4*)p;
  float4 v1 = *(const float4*)(p + 4);
  float f[8] = {v0.x, v0.y, v0.z, v0.w, v1.x, v1.y, v1.z, v1.w};
  const int base = lane * 8;
  float mx = -3.0e38f;
#pragma unroll
  for (int j = 0; j < 8; ++j)
    if (!causal || base + j <= q) mx = fmaxf(mx, f[j]);
#pragma unroll
  for (int o = 32; o > 0; o >>= 1) mx = fmaxf(mx, __shfl_xor(mx, o));
  float s = 0.0f;
#pragma unroll
  for (int j = 0; j < 8; ++j) {
    float e = (!causal || base + j <= q) ? __expf(f[j] - mx) : 0.0f;
    f[j] = e; s += e;
  }
#pragma unroll
  for (int o = 32; o > 0; o >>= 1) s += __shfl_xor(s, o);
  const float inv = 1.0f / s;
  float4 o0 = {f[0] * inv, f[1] * inv, f[2] * inv, f[3] * inv};
  float4 o1 = {f[4] * inv, f[5] * inv, f[6] * inv, f[7] * inv};
  *(float4*)p = o0;
  *(float4*)(p + 4) = o1;
  u16 hb[8] = {f2bf(o0.x), f2bf(o0.y), f2bf(o0.z), f2bf(o0.w),
               f2bf(o1.x), f2bf(o1.y), f2bf(o1.z), f2bf(o1.w)};
  *(uint4*)(pb + (long)rowg * kT + lane * 8) = *(const uint4*)hb;
}

// x = LN(x + res); writes x f32 and xb bf16
__global__ void add_ln_v2(float* __restrict__ x, u16* __restrict__ xb,
                          const float* __restrict__ res,
                          const float* __restrict__ g, const float* __restrict__ b) {
  const int row = blockIdx.x;
  const int c = threadIdx.x * 4;
  float4 xv = *(const float4*)(x + (long)row * kD + c);
  float4 rv = *(const float4*)(res + (long)row * kD + c);
  const float v0 = xv.x + rv.x, v1 = xv.y + rv.y, v2 = xv.z + rv.z, v3 = xv.w + rv.w;
  float s = v0 + v1 + v2 + v3;
  float ss = v0 * v0 + v1 * v1 + v2 * v2 + v3 * v3;
#pragma unroll
  for (int o = 32; o > 0; o >>= 1) { s += __shfl_xor(s, o); ss += __shfl_xor(ss, o); }
  __shared__ float red[4][2];
  const int wv = threadIdx.x >> 6;
  if ((threadIdx.x & 63) == 0) { red[wv][0] = s; red[wv][1] = ss; }
  __syncthreads();
  s  = red[0][0] + red[1][0] + red[2][0] + red[3][0];
  ss = red[0][1] + red[1][1] + red[2][1] + red[3][1];
  const float mean = s * (1.0f / kD);
  const float var = ss * (1.0f / kD) - mean * mean;
  const float rs = rsqrtf(var + 1e-5f);
  float4 gv = *(const float4*)(g + c);
  float4 bv = *(const float4*)(b + c);
  float4 o;
  o.x = gv.x * (v0 - mean) * rs + bv.x;
  o.y = gv.y * (v1 - mean) * rs + bv.y;
  o.z = gv.z * (v2 - mean) * rs + bv.z;
  o.w = gv.w * (v3 - mean) * rs + bv.w;
  *(float4*)(x + (long)row * kD + c) = o;
  u16 h[4] = {f2bf(o.x), f2bf(o.y), f2bf(o.z), f2bf(o.w)};
  *(uint2*)(xb + (long)row * kD + c) = *(const uint2*)h;
}

// ===========================================================================
// FALLBACK PATH (Round-3, proven): f32-staging MFMA GEMM, scratch in d_out
// ===========================================================================
template <int BM, int BN, typename TA, typename TB, int BKN>
__global__ __launch_bounds__(256)
void gemm_kernel(const void* __restrict__ Av, const void* __restrict__ Bv,
                 const float* __restrict__ bias, float* __restrict__ Cv,
                 const int K, const int lda, const int ldb, const int ldc,
                 const int nH, const long sAb, const long sAh,
                 const long sBb, const long sBh, const long sCb, const long sCh,
                 const float scale, const int relu) {
  constexpr int LP = 40;
  __shared__ u16 As[BM][LP];
  __shared__ u16 Bs[BN][LP];
  const int tid = threadIdx.x;
  const int z = blockIdx.z;
  const int zb = z / nH, zh = z - zb * nH;
  const TA* A = (const TA*)Av + zb * sAb + zh * sAh + (long)blockIdx.y * BM * lda;
  const TB* Bp;
  if constexpr (BKN)
    Bp = (const TB*)Bv + zb * sBb + zh * sBh + (long)blockIdx.x * BN;
  else
    Bp = (const TB*)Bv + zb * sBb + zh * sBh + (long)blockIdx.x * BN * ldb;
  const long offC = zb * sCb + zh * sCh;
  const int lane = tid & 63;
  const int wm = (tid >> 7) & 1, wn = (tid >> 6) & 1;
  constexpr int FM = BM / 32, FN = BN / 32;
  v4f acc[FM][FN];
  const v4f zero = {0.f, 0.f, 0.f, 0.f};
#pragma unroll
  for (int i = 0; i < FM; ++i)
#pragma unroll
    for (int j = 0; j < FN; ++j) acc[i][j] = zero;
  const int l15 = lane & 15, lk = lane >> 4;

  for (int k0 = 0; k0 < K; k0 += 32) {
    __syncthreads();
    if constexpr (sizeof(TA) == 4) {
      const int r = tid >> 3, c = (tid & 7) * 4;
#pragma unroll
      for (int rr = 0; rr < BM; rr += 32) {
        float4 vv = *(const float4*)((const float*)A + (long)(rr + r) * lda + k0 + c);
        unsigned lo = (unsigned)f2bf(vv.x) | ((unsigned)f2bf(vv.y) << 16);
        unsigned hi = (unsigned)f2bf(vv.z) | ((unsigned)f2bf(vv.w) << 16);
        *(uint2*)&As[rr + r][c] = make_uint2(lo, hi);
      }
    } else {
      const int r = tid >> 2, c = (tid & 3) * 8;
#pragma unroll
      for (int rr = 0; rr < BM; rr += 64) {
        uint4 vv = *(const uint4*)((const u16*)A + (long)(rr + r) * lda + k0 + c);
        *(uint4*)&As[rr + r][c] = vv;
      }
    }
    if constexpr (BKN) {
      const int r = tid >> 3, c = (tid & 7) * 4;
#pragma unroll
      for (int nn = 0; nn < BN; nn += 32) {
        float4 vv = *(const float4*)((const float*)Bp + (long)(k0 + r) * ldb + nn + c);
        Bs[nn + c + 0][r] = f2bf(vv.x);
        Bs[nn + c + 1][r] = f2bf(vv.y);
        Bs[nn + c + 2][r] = f2bf(vv.z);
        Bs[nn + c + 3][r] = f2bf(vv.w);
      }
    } else if constexpr (sizeof(TB) == 4) {
      const int r = tid >> 3, c = (tid & 7) * 4;
#pragma unroll
      for (int rr = 0; rr < BN; rr += 32) {
        float4 vv = *(const float4*)((const float*)Bp + (long)(rr + r) * ldb + k0 + c);
        unsigned lo = (unsigned)f2bf(vv.x) | ((unsigned)f2bf(vv.y) << 16);
        unsigned hi = (unsigned)f2bf(vv.z) | ((unsigned)f2bf(vv.w) << 16);
        *(uint2*)&Bs[rr + r][c] = make_uint2(lo, hi);
      }
    } else {
      const int r = tid >> 2, c = (tid & 3) * 8;
#pragma unroll
      for (int rr = 0; rr < BN; rr += 64) {
        uint4 vv = *(const uint4*)((const u16*)Bp + (long)(rr + r) * ldb + k0 + c);
        *(uint4*)&Bs[rr + r][c] = vv;
      }
    }
    __syncthreads();
    v8bf af[FM], bfr[FN];
#pragma unroll
    for (int i = 0; i < FM; ++i)
      af[i] = *(const v8bf*)&As[wm * (BM / 2) + i * 16 + l15][lk * 8];
#pragma unroll
    for (int j = 0; j < FN; ++j)
      bfr[j] = *(const v8bf*)&Bs[wn * (BN / 2) + j * 16 + l15][lk * 8];
#pragma unroll
    for (int i = 0; i < FM; ++i)
#pragma unroll
      for (int j = 0; j < FN; ++j)
        acc[i][j] = __builtin_amdgcn_mfma_f32_16x16x32_bf16(af[i], bfr[j], acc[i][j], 0, 0, 0);
  }

  const long m0 = (long)blockIdx.y * BM + wm * (BM / 2);
  const int n0 = blockIdx.x * BN + wn * (BN / 2);
#pragma unroll
  for (int j = 0; j < FN; ++j) {
    const int col = n0 + j * 16 + l15;
    const float bv = bias ? bias[col] : 0.0f;
#pragma unroll
    for (int i = 0; i < FM; ++i) {
      const long row = m0 + i * 16 + lk * 4;
#pragma unroll
      for (int r = 0; r < 4; ++r) {
        float v = acc[i][j][r] * scale + bv;
        if (relu) v = fmaxf(v, 0.0f);
        Cv[offC + (row + r) * ldc + col] = v;
      }
    }
  }
}

__global__ void embed_kernel(const int* __restrict__ tgt, const float* __restrict__ emb,
                             float* __restrict__ x) {
  const int row = blockIdx.x;
  const int t = row & (kT - 1);
  const int tok = tgt[row];
  const int c = threadIdx.x * 4;
  float4 e = *(const float4*)(emb + (long)tok * kD + c);
  const float nl = -9.210340371976184f / (float)kD;
  const float a0 = (float)t * expf((float)c * nl);
  const float a1 = (float)t * expf((float)(c + 2) * nl);
  float4 o;
  o.x = e.x * 32.0f + sinf(a0);
  o.y = e.y * 32.0f + cosf(a0);
  o.z = e.z * 32.0f + sinf(a1);
  o.w = e.w * 32.0f + cosf(a1);
  *(float4*)(x + (long)row * kD + c) = o;
}

__global__ void transpose_v_kernel(const float* __restrict__ v, u16* __restrict__ vt) {
  __shared__ float tile[32][33];
  const int z = blockIdx.z;
  const int b = z >> 4, h = z & 15;
  const int t0 = blockIdx.x * 32, d0 = blockIdx.y * 32;
  const int tx = threadIdx.x, ty = threadIdx.y;
  const float* in = v + (long)b * kTD + (long)h * kDK;
#pragma unroll
  for (int i = 0; i < 4; ++i)
    tile[ty + 8 * i][tx] = in[(long)(t0 + ty + 8 * i) * kD + d0 + tx];
  __syncthreads();
  u16* o = vt + (long)z * kDK * kT;
#pragma unroll
  for (int i = 0; i < 4; ++i)
    o[(long)(d0 + ty + 8 * i) * kT + t0 + tx] = f2bf(tile[tx][ty + 8 * i]);
}

__global__ void softmax_kernel(float* __restrict__ w, const int causal) {
  const int rowg = blockIdx.x * 4 + (threadIdx.x >> 6);
  const int lane = threadIdx.x & 63;
  const int q = rowg & (kT - 1);
  float* p = w + (long)rowg * kT + lane * 8;
  float4 v0 = *(const float4*)p;
  float4 v1 = *(const float4*)(p + 4);
  float f[8] = {v0.x, v0.y, v0.z, v0.w, v1.x, v1.y, v1.z, v1.w};
  const int base = lane * 8;
  float mx = -3.0e38f;
#pragma unroll
  for (int j = 0; j < 8; ++j)
    if (!causal || base + j <= q) mx = fmaxf(mx, f[j]);
#pragma unroll
  for (int o = 32; o > 0; o >>= 1) mx = fmaxf(mx, __shfl_xor(mx, o));
  float s = 0.0f;
#pragma unroll
  for (int j = 0; j < 8; ++j) {
    float e = (!causal || base + j <= q) ? __expf(f[j] - mx) : 0.0f;
    f[j] = e; s += e;
  }
#pragma unroll
  for (int o = 32; o > 0; o >>= 1) s += __shfl_xor(s, o);
  const float inv = 1.0f / s;
  float4 o0 = {f[0] * inv, f[1] * inv, f[2] * inv, f[3] * inv};
  float4 o1 = {f[4] * inv, f[5] * inv, f[6] * inv, f[7] * inv};
  *(float4*)p = o0;
  *(float4*)(p + 4) = o1;
}

__global__ void add_ln_kernel(float* __restrict__ x, const float* __restrict__ res,
                              const float* __restrict__ g, const float* __restrict__ b) {
  const int row = blockIdx.x;
  const int c = threadIdx.x * 4;
  float4 xv = *(const float4*)(x + (long)row * kD + c);
  float4 rv = *(const float4*)(res + (long)row * kD + c);
  const float v0 = xv.x + rv.x, v1 = xv.y + rv.y, v2 = xv.z + rv.z, v3 = xv.w + rv.w;
  float s = v0 + v1 + v2 + v3;
  float ss = v0 * v0 + v1 * v1 + v2 * v2 + v3 * v3;
#pragma unroll
  for (int o = 32; o > 0; o >>= 1) { s += __shfl_xor(s, o); ss += __shfl_xor(ss, o); }
  __shared__ float red[4][2];
  const int wv = threadIdx.x >> 6;
  if ((threadIdx.x & 63) == 0) { red[wv][0] = s; red[wv][1] = ss; }
  __syncthreads();
  s  = red[0][0] + red[1][0] + red[2][0] + red[3][0];
  ss = red[0][1] + red[1][1] + red[2][1] + red[3][1];
  const float mean = s * (1.0f / kD);
  const float var = ss * (1.0f / kD) - mean * mean;
  const float rs = rsqrtf(var + 1e-5f);
  float4 gv = *(const float4*)(g + c);
  float4 bv = *(const float4*)(b + c);
  float4 o;
  o.x = gv.x * (v0 - mean) * rs + bv.x;
  o.y = gv.y * (v1 - mean) * rs + bv.y;
  o.z = gv.z * (v2 - mean) * rs + bv.z;
  o.w = gv.w * (v3 - mean) * rs + bv.w;
  *(float4*)(x + (long)row * kD + c) = o;
}

// ===========================================================================
extern "C" void kernel_launch(void* const* d_in, const int* in_sizes, int n_in,
                              void* d_out, int out_size, void* d_ws, size_t ws_size,
                              hipStream_t stream) {
  const int*   tgt  = (const int*)d_in[0];
  const float* enc  = (const float*)d_in[1];
  const float* emb  = (const float*)d_in[3];
  const float* Wout = (const float*)d_in[4];
  const float* bout = (const float*)d_in[5];
  const float* Wq_s = (const float*)d_in[6];
  const float* bq_s = (const float*)d_in[7];
  const float* Wk_s = (const float*)d_in[8];
  const float* bk_s = (const float*)d_in[9];
  const float* Wv_s = (const float*)d_in[10];
  const float* bv_s = (const float*)d_in[11];
  const float* Wo_s = (const float*)d_in[12];
  const float* bo_s = (const float*)d_in[13];
  const float* Wq_c = (const float*)d_in[14];
  const float* bq_c = (const float*)d_in[15];
  const float* Wk_c = (const float*)d_in[16];
  const float* bk_c = (const float*)d_in[17];
  const float* Wv_c = (const float*)d_in[18];
  const float* bv_c = (const float*)d_in[19];
  const float* Wo_c = (const float*)d_in[20];
  const float* bo_c = (const float*)d_in[21];
  const float* W1   = (const float*)d_in[22];
  const float* b1   = (const float*)d_in[23];
  const float* W2   = (const float*)d_in[24];
  const float* b2   = (const float*)d_in[25];
  const float* ln1g = (const float*)d_in[26];
  const float* ln1b = (const float*)d_in[27];
  const float* ln2g = (const float*)d_in[28];
  const float* ln2b = (const float*)d_in[29];
  const float* ln3g = (const float*)d_in[30];
  const float* ln3b = (const float*)d_in[31];

  float* out = (float*)d_out;
  const long DD = (long)kD * kD;
  const dim3 blk256(256), blkT(32, 8);

  if (ws_size >= (300ll << 20)) {
    // =================== FAST PATH ===================
    char* ws = (char*)d_ws;
    float* x   = (float*)ws;                      // 8 MiB
    u16* xb    = (u16*)(ws + (8l << 20));         // 4 MiB
    u16* encb  = (u16*)(ws + (12l << 20));        // 4 MiB
    u16* Sqkv  = (u16*)(ws + (16l << 20));        // 12 MiB (2048x3072)
    u16* vt    = (u16*)(ws + (28l << 20));        // 4 MiB
    u16* S3b   = (u16*)(ws + (32l << 20));        // 4 MiB
    u16* Hb    = (u16*)(ws + (36l << 20));        // 16 MiB (2048x4096)
    float* S0  = (float*)(ws + (52l << 20));      // 8 MiB
    u16* Pb    = (u16*)(ws + (60l << 20));        // 32 MiB (B,H,T,T)
    u16* wbase = (u16*)(ws + (92l << 20));        // 128 MiB (4x32)
    u16* woutT = (u16*)(ws + (220l << 20));       // 62.5 MiB
    float* bqkvS = (float*)(ws + (283l << 20));   // 48 KiB
    float* bkvC  = (float*)(ws + (283l << 20) + (64l << 10));  // 32 KiB
    const long WLAY = (32l << 20) / 2;            // u16 elems per layer block

    // ---- one-time prep ----
    for (int i = 0; i < kL; ++i) {
      u16* wqkvS = wbase + i * WLAY;
      u16* woS   = wqkvS + 3072 * 1024;
      u16* wqC   = woS + 1024 * 1024;
      u16* wkvC  = wqC + 1024 * 1024;
      u16* woC   = wkvC + 2048 * 1024;
      u16* w1t   = woC + 1024 * 1024;
      u16* w2t   = w1t + (long)4096 * 1024;
      TPtrs p{};
      p.in[0] = Wq_s + i * DD; p.out[0] = wqkvS;
      p.in[1] = Wk_s + i * DD; p.out[1] = wqkvS + 1024 * 1024;
      p.in[2] = Wv_s + i * DD; p.out[2] = wqkvS + 2048 * 1024;
      p.in[3] = Wo_s + i * DD; p.out[3] = woS;
      p.in[4] = Wq_c + i * DD; p.out[4] = wqC;
      p.in[5] = Wk_c + i * DD; p.out[5] = wkvC;
      p.in[6] = Wv_c + i * DD; p.out[6] = wkvC + 1024 * 1024;
      p.in[7] = Wo_c + i * DD; p.out[7] = woC;
      transpose_wt_v2<<<dim3(32, 32, 8), blkT, 0, stream>>>(p, 1024, 1024);
      TPtrs p1{}; p1.in[0] = W1 + (long)i * kD * kF; p1.out[0] = w1t;
      transpose_wt_v2<<<dim3(128, 32, 1), blkT, 0, stream>>>(p1, 1024, 4096);
      TPtrs p2{}; p2.in[0] = W2 + (long)i * kF * kD; p2.out[0] = w2t;
      transpose_wt_v2<<<dim3(32, 128, 1), blkT, 0, stream>>>(p2, 4096, 1024);
    }
    TPtrs po{}; po.in[0] = Wout; po.out[0] = woutT;
    transpose_wt_v2<<<dim3(1000, 32, 1), blkT, 0, stream>>>(po, 1024, 32000);
    concat_bias<<<dim3(48), blk256, 0, stream>>>(bqkvS, bq_s, bk_s, bv_s, 3);
    concat_bias<<<dim3(32), blk256, 0, stream>>>(bkvC, bk_c, bv_c, nullptr, 2);
    cvt_bf16_v2<<<dim3(2048), blk256, 0, stream>>>(enc, encb);
    embed_v2<<<dim3(kM), blk256, 0, stream>>>(tgt, emb, x, xb);

    for (int i = 0; i < kL; ++i) {
      u16* wqkvS = wbase + i * WLAY;
      u16* woS   = wqkvS + 3072 * 1024;
      u16* wqC   = woS + 1024 * 1024;
      u16* wkvC  = wqC + 1024 * 1024;
      u16* woC   = wkvC + 2048 * 1024;
      u16* w1t   = woC + 1024 * 1024;
      u16* w2t   = w1t + (long)4096 * 1024;
      float* wSelf  = out + kLOG + (long)i * kBHTT;
      float* wCross = out + kLOG + (long)kL * kBHTT + (long)i * kBHTT;

      // -------- self attention --------
      gemm_bf<128, 128, 1><<<dim3(24, 16, 1), blk256, 0, stream>>>(
          xb, wqkvS, bqkvS + i * 3072, Sqkv, 1024, 1024, 1024, 3072,
          1, 0, 0, 0, 0, 0, 0, 1.0f, 0);
      transpose_v_v2<<<dim3(16, 2, 64), blkT, 0, stream>>>(Sqkv, vt);
      gemm_bf<128, 128, 0><<<dim3(4, 4, 64), blk256, 0, stream>>>(
          Sqkv, Sqkv + 1024, nullptr, wSelf, 64, 3072, 3072, 512,
          16, 512l * 3072, 64, 512l * 3072, 64, kHTT, kTT, 0.125f, 0);
      softmax_v2<<<dim3(kB * kH * kT / 4), blk256, 0, stream>>>(wSelf, Pb, 1);
      gemm_bf<128, 64, 1><<<dim3(1, 4, 64), blk256, 0, stream>>>(
          Pb, vt, nullptr, S3b, 512, 512, 512, 1024,
          16, kHTT, kTT, 16l * 32768, 32768, 512l * 1024, 64, 1.0f, 0);
      gemm_bf<128, 128, 0><<<dim3(8, 16, 1), blk256, 0, stream>>>(
          S3b, woS, bo_s + (long)i * kD, S0, 1024, 1024, 1024, 1024,
          1, 0, 0, 0, 0, 0, 0, 1.0f, 0);
      add_ln_v2<<<dim3(kM), blk256, 0, stream>>>(x, xb, S0, ln1g + (long)i * kD, ln1b + (long)i * kD);

      // -------- cross attention --------
      gemm_bf<128, 128, 1><<<dim3(8, 16, 1), blk256, 0, stream>>>(
          xb, wqC, bq_c + (long)i * kD, Sqkv, 1024, 1024, 1024, 3072,
          1, 0, 0, 0, 0, 0, 0, 1.0f, 0);
      gemm_bf<128, 128, 1><<<dim3(16, 16, 1), blk256, 0, stream>>>(
          encb, wkvC, bkvC + i * 2048, Sqkv + 1024, 1024, 1024, 1024, 3072,
          1, 0, 0, 0, 0, 0, 0, 1.0f, 0);
      transpose_v_v2<<<dim3(16, 2, 64), blkT, 0, stream>>>(Sqkv, vt);
      gemm_bf<128, 128, 0><<<dim3(4, 4, 64), blk256, 0, stream>>>(
          Sqkv, Sqkv + 1024, nullptr, wCross, 64, 3072, 3072, 512,
          16, 512l * 3072, 64, 512l * 3072, 64, kHTT, kTT, 0.125f, 0);
      softmax_v2<<<dim3(kB * kH * kT / 4), blk256, 0, stream>>>(wCross, Pb, 0);
      gemm_bf<128, 64, 1><<<dim3(1, 4, 64), blk256, 0, stream>>>(
          Pb, vt, nullptr, S3b, 512, 512, 512, 1024,
          16, kHTT, kTT, 16l * 32768, 32768, 512l * 1024, 64, 1.0f, 0);
      gemm_bf<128, 128, 0><<<dim3(8, 16, 1), blk256, 0, stream>>>(
          S3b, woC, bo_c + (long)i * kD, S0, 1024, 1024, 1024, 1024,
          1, 0, 0, 0, 0, 0, 0, 1.0f, 0);
      add_ln_v2<<<dim3(kM), blk256, 0, stream>>>(x, xb, S0, ln2g + (long)i * kD, ln2b + (long)i * kD);

      // -------- FFN --------
      gemm_bf<128, 128, 1><<<dim3(32, 16, 1), blk256, 0, stream>>>(
          xb, w1t, b1 + (long)i * kF, Hb, 1024, 1024, 1024, 4096,
          1, 0, 0, 0, 0, 0, 0, 1.0f, 1);
      gemm_bf<128, 128, 0><<<dim3(8, 16, 1), blk256, 0, stream>>>(
          Hb, w2t, b2 + (long)i * kD, S0, 4096, 4096, 4096, 1024,
          1, 0, 0, 0, 0, 0, 0, 1.0f, 0);
      add_ln_v2<<<dim3(kM), blk256, 0, stream>>>(x, xb, S0, ln3g + (long)i * kD, ln3b + (long)i * kD);
    }

    gemm_bf<128, 128, 0><<<dim3(250, 16, 1), blk256, 0, stream>>>(
        xb, woutT, bout, out, 1024, 1024, 1024, 32000,
        1, 0, 0, 0, 0, 0, 0, 1.0f, 0);
    return;
  }

  // =================== FALLBACK (Round-3 verified) ===================
  float* x = (float*)d_ws;
  char* sc = (char*)d_out;
  float* S0 = (float*)sc;
  float* S1 = (float*)(sc + (8l  << 20));
  float* S2 = (float*)(sc + (16l << 20));
  float* S3 = (float*)(sc + (24l << 20));
  float* S4 = (float*)(sc + (32l << 20));
  u16*   vt = (u16*)  (sc + (40l << 20));

  embed_kernel<<<dim3(kM), blk256, 0, stream>>>(tgt, emb, x);
  auto wgemm = [&](const float* A, const float* W, const float* bias, float* C) {
    gemm_kernel<128, 128, float, float, 1><<<dim3(kD / 128, kM / 128, 1), blk256, 0, stream>>>(
        A, W, bias, C, kD, kD, kD, kD, 1, 0, 0, 0, 0, 0, 0, 1.0f, 0);
  };
  for (int i = 0; i < kL; ++i) {
    const long wOff = (long)i * DD;
    float* wSelf  = out + kLOG + (long)i * kBHTT;
    float* wCross = out + kLOG + (long)kL * kBHTT + (long)i * kBHTT;
    wgemm(x, Wq_s + wOff, bq_s + (long)i * kD, S0);
    wgemm(x, Wk_s + wOff, bk_s + (long)i * kD, S1);
    wgemm(x, Wv_s + wOff, bv_s + (long)i * kD, S2);
    transpose_v_kernel<<<dim3(16, 2, 64), blkT, 0, stream>>>(S2, vt);
    gemm_kernel<128, 128, float, float, 0><<<dim3(4, 4, 64), blk256, 0, stream>>>(
        S0, S1, nullptr, wSelf, kDK, kD, kD, kT,
        kH, kTD, (long)kDK, kTD, (long)kDK, kHTT, kTT, 0.125f, 0);
    softmax_kernel<<<dim3(kB * kH * kT / 4), blk256, 0, stream>>>(wSelf, 1);
    gemm_kernel<128, 64, float, u16, 0><<<dim3(1, 4, 64), blk256, 0, stream>>>(
        wSelf, vt, nullptr, S3, kT, kT, kT, kD,
        kH, kHTT, kTT, (long)kH * kDK * kT, (long)kDK * kT, kTD, (long)kDK, 1.0f, 0);
    wgemm(S3, Wo_s + wOff, bo_s + (long)i * kD, S0);
    add_ln_kernel<<<dim3(kM), blk256, 0, stream>>>(x, S0, ln1g + (long)i * kD, ln1b + (long)i * kD);
    wgemm(x,   Wq_c + wOff, bq_c + (long)i * kD, S0);
    wgemm(enc, Wk_c + wOff, bk_c + (long)i * kD, S1);
    wgemm(enc, Wv_c + wOff, bv_c + (long)i * kD, S2);
    transpose_v_kernel<<<dim3(16, 2, 64), blkT, 0, stream>>>(S2, vt);
    gemm_kernel<128, 128, float, float, 0><<<dim3(4, 4, 64), blk256, 0, stream>>>(
        S0, S1, nullptr, wCross, kDK, kD, kD, kT,
        kH, kTD, (long)kDK, kTD, (long)kDK, kHTT, kTT, 0.125f, 0);
    softmax_kernel<<<dim3(kB * kH * kT / 4), blk256, 0, stream>>>(wCross, 0);
    gemm_kernel<128, 64, float, u16, 0><<<dim3(1, 4, 64), blk256, 0, stream>>>(
        wCross, vt, nullptr, S3, kT, kT, kT, kD,
        kH, kHTT, kTT, (long)kH * kDK * kT, (long)kDK * kT, kTD, (long)kDK, 1.0f, 0);
    wgemm(S3, Wo_c + wOff, bo_c + (long)i * kD, S0);
    add_ln_kernel<<<dim3(kM), blk256, 0, stream>>>(x, S0, ln2g + (long)i * kD, ln2b + (long)i * kD);
    gemm_kernel<128, 128, float, float, 1><<<dim3(kF / 128, kM / 128, 1), blk256, 0, stream>>>(
        x, W1 + (long)i * kD * kF, b1 + (long)i * kF, S0, kD, kD, kF, kF,
        1, 0, 0, 0, 0, 0, 0, 1.0f, 1);
    gemm_kernel<128, 128, float, float, 1><<<dim3(kD / 128, kM / 128, 1), blk256, 0, stream>>>(
        S0, W2 + (long)i * kF * kD, b2 + (long)i * kD, S4, kF, kF, kD, kD,
        1, 0, 0, 0, 0, 0, 0, 1.0f, 0);
    add_ln_kernel<<<dim3(kM), blk256, 0, stream>>>(x, S4, ln3g + (long)i * kD, ln3b + (long)i * kD);
  }
  gemm_kernel<128, 128, float, float, 1><<<dim3(kV / 128, kM / 128, 1), blk256, 0, stream>>>(
      x, Wout, bout, out, kD, kD, kV, kV,
      1, 0, 0, 0, 0, 0, 0, 1.0f, 0);
}

// Round 6
// 1685.230 us; speedup vs baseline: 2.0659x; 1.2757x over previous
//
#include <hip/hip_runtime.h>

// TransformerDecoder on MI355X. Round 5: BK=64 GEMM, split-K for narrow GEMMs,
// fused scores+softmax kernel. Fallback (Round-3 proven) if ws too small.

typedef unsigned short u16;
typedef __bf16 v8bf __attribute__((ext_vector_type(8)));
typedef float v4f __attribute__((ext_vector_type(4)));

namespace {
constexpr int kB = 4, kT = 512, kD = 1024, kH = 16, kDK = 64, kF = 4096, kV = 32000, kL = 4;
constexpr int kM = kB * kT;                       // 2048 rows
constexpr long kTD = (long)kT * kD;               // 524288
constexpr long kTT = (long)kT * kT;               // 262144
constexpr long kHTT = (long)kH * kTT;             // 4194304 (per batch b)
constexpr long kBHTT = (long)kB * kHTT;           // 16777216 (per layer)
constexpr long kLOG = (long)kM * kV;              // 65536000 logits elems
constexpr long kPART = (long)kM * kD;             // 2097152 (one f32 partial)
}

__device__ __forceinline__ u16 f2bf(float f) {
  union { float f; unsigned u; } v; v.f = f;
  unsigned r = v.u + 0x7FFFu + ((v.u >> 16) & 1u);
  return (u16)(r >> 16);
}
__device__ __forceinline__ float bf2f(u16 h) {
  union { unsigned u; float f; } v; v.u = ((unsigned)h) << 16;
  return v.f;
}

typedef __attribute__((address_space(3))) void lds_void;
typedef const __attribute__((address_space(1))) void glob_void;
__device__ __forceinline__ void gl2lds16(const void* g, void* l) {
  __builtin_amdgcn_global_load_lds((glob_void*)g, (lds_void*)l, 16, 0, 0);
}

// ---------------------------------------------------------------------------
// bf16 GEMM, BK=64: C[m][n] = scale*sum_k A[m][k]*B[n][k] + bias[n] (opt relu)
// A (M,K) bf16 lda; B (N,K) bf16 ldb; C f32 or bf16. Batch/split-K via z:
// (zb,zh)=(z/nH,z%nH) with element offsets; bias applied only when zb==0.
// ---------------------------------------------------------------------------
template <int BM, int BN, int OUTBF>
__global__ __launch_bounds__(256)
void gemm_bf(const u16* __restrict__ A0, const u16* __restrict__ B0,
             const float* __restrict__ bias, void* __restrict__ Cv,
             const int K, const int lda, const int ldb, const int ldc,
             const int nH, const long sAb, const long sAh,
             const long sBb, const long sBh, const long sCb, const long sCh,
             const float scale, const int relu) {
  static_assert(BM % 32 == 0 && BN % 32 == 0, "tiles");
  __shared__ u16 As[BM][64];
  __shared__ u16 Bs[BN][64];
  const int tid = threadIdx.x;
  const int lane = tid & 63;
  const int w = tid >> 6;
  const int z = blockIdx.z;
  const int zb = z / nH, zh = z - zb * nH;
  const u16* A = A0 + zb * sAb + zh * sAh + (long)blockIdx.y * BM * lda;
  const u16* B = B0 + zb * sBb + zh * sBh + (long)blockIdx.x * BN * ldb;
  const long offC = zb * sCb + zh * sCh;
  const int wm = w >> 1, wn = w & 1;
  constexpr int FM = BM / 32, FN = BN / 32;
  v4f acc[FM][FN];
  const v4f zero = {0.f, 0.f, 0.f, 0.f};
#pragma unroll
  for (int i = 0; i < FM; ++i)
#pragma unroll
    for (int j = 0; j < FN; ++j) acc[i][j] = zero;
  const int l15 = lane & 15, lk = lane >> 4;
  const int lr8 = lane >> 3;          // 0..7 row within 8-row stripe
  const int lc8 = (lane & 7) * 8;     // elem col: 0..56

  for (int k0 = 0; k0 < K; k0 += 64) {
    __syncthreads();
#pragma unroll
    for (int s = 0; s < BM / 32; ++s)
      gl2lds16(A + (long)(w * (BM / 4) + s * 8 + lr8) * lda + k0 + lc8,
               &As[w * (BM / 4) + s * 8][0]);
#pragma unroll
    for (int s = 0; s < BN / 32; ++s)
      gl2lds16(B + (long)(w * (BN / 4) + s * 8 + lr8) * ldb + k0 + lc8,
               &Bs[w * (BN / 4) + s * 8][0]);
    __syncthreads();
#pragma unroll
    for (int t = 0; t < 2; ++t) {
      v8bf af[FM], bfr[FN];
#pragma unroll
      for (int i = 0; i < FM; ++i)
        af[i] = *(const v8bf*)&As[wm * (BM / 2) + i * 16 + l15][t * 32 + lk * 8];
#pragma unroll
      for (int j = 0; j < FN; ++j)
        bfr[j] = *(const v8bf*)&Bs[wn * (BN / 2) + j * 16 + l15][t * 32 + lk * 8];
#pragma unroll
      for (int i = 0; i < FM; ++i)
#pragma unroll
        for (int j = 0; j < FN; ++j)
          acc[i][j] = __builtin_amdgcn_mfma_f32_16x16x32_bf16(af[i], bfr[j], acc[i][j], 0, 0, 0);
    }
  }

  const long m0 = (long)blockIdx.y * BM + wm * (BM / 2);
  const int n0 = blockIdx.x * BN + wn * (BN / 2);
#pragma unroll
  for (int j = 0; j < FN; ++j) {
    const int col = n0 + j * 16 + l15;
    const float bv = (bias && zb == 0) ? bias[col] : 0.0f;
#pragma unroll
    for (int i = 0; i < FM; ++i) {
      const long row = m0 + i * 16 + lk * 4;
#pragma unroll
      for (int r = 0; r < 4; ++r) {
        float v = acc[i][j][r] * scale + bv;
        if (relu) v = fmaxf(v, 0.0f);
        const long idx = offC + (row + r) * ldc + col;
        if (OUTBF) ((u16*)Cv)[idx] = f2bf(v);
        else       ((float*)Cv)[idx] = v;
      }
    }
  }
}

// ---------------------------------------------------------------------------
// Fused scores+softmax: per block computes 128 q-rows x all 512 keys for one
// (b,h), does row softmax in-block, writes w (f32, d_out) and P (bf16).
// Q,K from Sqkv (ld 3072). 512 threads = 8 waves (2 wm x 4 wn).
// ---------------------------------------------------------------------------
template <int CAUSAL>
__global__ __launch_bounds__(512)
void attn_scores(const u16* __restrict__ Qb, const u16* __restrict__ Kb,
                 float* __restrict__ wout, u16* __restrict__ pb) {
  __shared__ u16 Qs[128][64];
  __shared__ u16 Ks[512][64];
  __shared__ float redM[128][4];
  __shared__ float redS[128][4];
  const int tid = threadIdx.x, lane = tid & 63, w = tid >> 6;
  const int wm = w >> 2, wn = w & 3;
  const int l15 = lane & 15, lk = lane >> 4;
  const int lr8 = lane >> 3, lc8 = (lane & 7) * 8;
  const int bx = blockIdx.x;                 // q tile 0..3
  const int z = blockIdx.y, zb = z >> 4, zh = z & 15;
  const u16* Q = Qb + (long)zb * 512 * 3072 + zh * 64 + (long)bx * 128 * 3072;
  const u16* Kp = Kb + (long)zb * 512 * 3072 + zh * 64;
  const long obase = (long)zb * kHTT + (long)zh * kTT;

#pragma unroll
  for (int s = 0; s < 2; ++s)
    gl2lds16(Q + (long)(w * 16 + s * 8 + lr8) * 3072 + lc8, &Qs[w * 16 + s * 8][0]);
#pragma unroll
  for (int s = 0; s < 8; ++s) {
    const int r0 = w * 64 + s * 8;
    if (!CAUSAL || r0 <= bx * 128 + 127)     // fully-masked K rows: skip staging
      gl2lds16(Kp + (long)(r0 + lr8) * 3072 + lc8, &Ks[r0][0]);
  }
  __syncthreads();

  v4f acc[4][8];
  const v4f zero = {0.f, 0.f, 0.f, 0.f};
#pragma unroll
  for (int i = 0; i < 4; ++i)
#pragma unroll
    for (int j = 0; j < 8; ++j) acc[i][j] = zero;

#pragma unroll
  for (int t = 0; t < 2; ++t) {
    v8bf aq[4], bk[8];
#pragma unroll
    for (int i = 0; i < 4; ++i)
      aq[i] = *(const v8bf*)&Qs[wm * 64 + i * 16 + l15][t * 32 + lk * 8];
#pragma unroll
    for (int j = 0; j < 8; ++j)
      bk[j] = *(const v8bf*)&Ks[wn * 128 + j * 16 + l15][t * 32 + lk * 8];
#pragma unroll
    for (int i = 0; i < 4; ++i)
#pragma unroll
      for (int j = 0; j < 8; ++j) {
        // skip frags where min_col > max_row (fully masked)
        if (!(CAUSAL && wn * 128 + j * 16 > bx * 128 + wm * 64 + i * 16 + 15))
          acc[i][j] = __builtin_amdgcn_mfma_f32_16x16x32_bf16(aq[i], bk[j], acc[i][j], 0, 0, 0);
      }
  }

  // ---- row max (in-lane over j, shfl over l15, LDS over wn) ----
  float gmax[4][4];
#pragma unroll
  for (int i = 0; i < 4; ++i)
#pragma unroll
    for (int r = 0; r < 4; ++r) {
      const int q = bx * 128 + wm * 64 + i * 16 + lk * 4 + r;
      float m = -3.0e38f;
#pragma unroll
      for (int j = 0; j < 8; ++j) {
        const int col = wn * 128 + j * 16 + l15;
        if (!CAUSAL || col <= q) m = fmaxf(m, acc[i][j][r] * 0.125f);
      }
#pragma unroll
      for (int off = 1; off < 16; off <<= 1) m = fmaxf(m, __shfl_xor(m, off));
      if (l15 == 0) redM[wm * 64 + i * 16 + lk * 4 + r][wn] = m;
    }
  __syncthreads();
#pragma unroll
  for (int i = 0; i < 4; ++i)
#pragma unroll
    for (int r = 0; r < 4; ++r) {
      v4f mv = *(const v4f*)&redM[wm * 64 + i * 16 + lk * 4 + r][0];
      gmax[i][r] = fmaxf(fmaxf(mv[0], mv[1]), fmaxf(mv[2], mv[3]));
    }
  // ---- exp + row sum ----
#pragma unroll
  for (int i = 0; i < 4; ++i)
#pragma unroll
    for (int r = 0; r < 4; ++r) {
      const int q = bx * 128 + wm * 64 + i * 16 + lk * 4 + r;
      float s = 0.0f;
#pragma unroll
      for (int j = 0; j < 8; ++j) {
        const int col = wn * 128 + j * 16 + l15;
        float e = (!CAUSAL || col <= q) ? __expf(acc[i][j][r] * 0.125f - gmax[i][r]) : 0.0f;
        acc[i][j][r] = e;
        s += e;
      }
#pragma unroll
      for (int off = 1; off < 16; off <<= 1) s += __shfl_xor(s, off);
      if (l15 == 0) redS[wm * 64 + i * 16 + lk * 4 + r][wn] = s;
    }
  __syncthreads();
  // ---- normalize + write w (f32) and P (bf16) ----
#pragma unroll
  for (int i = 0; i < 4; ++i)
#pragma unroll
    for (int r = 0; r < 4; ++r) {
      v4f sv = *(const v4f*)&redS[wm * 64 + i * 16 + lk * 4 + r][0];
      const float inv = 1.0f / (sv[0] + sv[1] + sv[2] + sv[3]);
      const int q = bx * 128 + wm * 64 + i * 16 + lk * 4 + r;
      const long rowoff = obase + (long)q * 512;
#pragma unroll
      for (int j = 0; j < 8; ++j) {
        const int col = wn * 128 + j * 16 + l15;
        const float v = acc[i][j][r] * inv;
        wout[rowoff + col] = v;
        pb[rowoff + col] = f2bf(v);
      }
    }
}

// Weight transpose-convert: out(N,K) bf16 = in(K,N)^T f32; batched ptr pairs.
struct TPtrs { const float* in[8]; u16* out[8]; };

__global__ void transpose_wt_v2(TPtrs ps, int K, int N) {
  __shared__ float tile[32][33];
  const float* in = ps.in[blockIdx.z];
  u16* o = ps.out[blockIdx.z];
  const int n0 = blockIdx.x * 32, k0 = blockIdx.y * 32;
  const int tx = threadIdx.x, ty = threadIdx.y;
#pragma unroll
  for (int i = 0; i < 4; ++i)
    tile[ty + 8 * i][tx] = in[(long)(k0 + ty + 8 * i) * N + n0 + tx];
  __syncthreads();
#pragma unroll
  for (int i = 0; i < 4; ++i)
    o[(long)(n0 + ty + 8 * i) * K + k0 + tx] = f2bf(tile[tx][ty + 8 * i]);
}

__global__ void concat_bias(float* __restrict__ dst, const float* __restrict__ s0,
                            const float* __restrict__ s1, const float* __restrict__ s2,
                            const int nsrc) {
  const int idx = blockIdx.x * 256 + threadIdx.x;
  const int per = nsrc << 10;
  const int l = idx / per, rem = idx - l * per, s = rem >> 10, j = rem & 1023;
  const float* src = (s == 0) ? s0 : (s == 1 ? s1 : s2);
  dst[idx] = src[l * 1024 + j];
}

__global__ void cvt_bf16_v2(const float* __restrict__ in, u16* __restrict__ o) {
  const long i = ((long)blockIdx.x * 256 + threadIdx.x) * 4;
  float4 v = *(const float4*)(in + i);
  u16 h[4] = {f2bf(v.x), f2bf(v.y), f2bf(v.z), f2bf(v.w)};
  *(uint2*)(o + i) = *(const uint2*)h;
}

__global__ void embed_v2(const int* __restrict__ tgt, const float* __restrict__ emb,
                         float* __restrict__ x, u16* __restrict__ xb) {
  const int row = blockIdx.x;
  const int t = row & (kT - 1);
  const int tok = tgt[row];
  const int c = threadIdx.x * 4;
  float4 e = *(const float4*)(emb + (long)tok * kD + c);
  const float nl = -9.210340371976184f / (float)kD;
  const float a0 = (float)t * expf((float)c * nl);
  const float a1 = (float)t * expf((float)(c + 2) * nl);
  float4 o;
  o.x = e.x * 32.0f + sinf(a0);
  o.y = e.y * 32.0f + cosf(a0);
  o.z = e.z * 32.0f + sinf(a1);
  o.w = e.w * 32.0f + cosf(a1);
  *(float4*)(x + (long)row * kD + c) = o;
  u16 h[4] = {f2bf(o.x), f2bf(o.y), f2bf(o.z), f2bf(o.w)};
  *(uint2*)(xb + (long)row * kD + c) = *(const uint2*)h;
}

// V slice of Sqkv (2048,3072) -> vt (B*H, dk, T) bf16
__global__ void transpose_v_v2(const u16* __restrict__ Sqkv, u16* __restrict__ vt) {
  __shared__ u16 tile[32][33];
  const int z = blockIdx.z, b = z >> 4, h = z & 15;
  const int t0 = blockIdx.x * 32, d0 = blockIdx.y * 32;
  const int tx = threadIdx.x, ty = threadIdx.y;
  const u16* in = Sqkv + (long)b * kT * 3072 + 2048 + h * kDK;
#pragma unroll
  for (int i = 0; i < 4; ++i)
    tile[ty + 8 * i][tx] = in[(long)(t0 + ty + 8 * i) * 3072 + d0 + tx];
  __syncthreads();
  u16* o = vt + (long)z * kDK * kT;
#pragma unroll
  for (int i = 0; i < 4; ++i)
    o[(long)(d0 + ty + 8 * i) * kT + t0 + tx] = tile[tx][ty + 8 * i];
}

// x = LN(x + sum_{p<nres} res[p]); writes x f32 and xb bf16
__global__ void add_ln_v3(float* __restrict__ x, u16* __restrict__ xb,
                          const float* __restrict__ res, const int nres,
                          const float* __restrict__ g, const float* __restrict__ b) {
  const int row = blockIdx.x;
  const int c = threadIdx.x * 4;
  float4 xv = *(const float4*)(x + (long)row * kD + c);
  float v0 = xv.x, v1 = xv.y, v2 = xv.z, v3 = xv.w;
  for (int p = 0; p < nres; ++p) {
    float4 rv = *(const float4*)(res + p * kPART + (long)row * kD + c);
    v0 += rv.x; v1 += rv.y; v2 += rv.z; v3 += rv.w;
  }
  float s = v0 + v1 + v2 + v3;
  float ss = v0 * v0 + v1 * v1 + v2 * v2 + v3 * v3;
#pragma unroll
  for (int o = 32; o > 0; o >>= 1) { s += __shfl_xor(s, o); ss += __shfl_xor(ss, o); }
  __shared__ float red[4][2];
  const int wv = threadIdx.x >> 6;
  if ((threadIdx.x & 63) == 0) { red[wv][0] = s; red[wv][1] = ss; }
  __syncthreads();
  s  = red[0][0] + red[1][0] + red[2][0] + red[3][0];
  ss = red[0][1] + red[1][1] + red[2][1] + red[3][1];
  const float mean = s * (1.0f / kD);
  const float var = ss * (1.0f / kD) - mean * mean;
  const float rs = rsqrtf(var + 1e-5f);
  float4 gv = *(const float4*)(g + c);
  float4 bv = *(const float4*)(b + c);
  float4 o;
  o.x = gv.x * (v0 - mean) * rs + bv.x;
  o.y = gv.y * (v1 - mean) * rs + bv.y;
  o.z = gv.z * (v2 - mean) * rs + bv.z;
  o.w = gv.w * (v3 - mean) * rs + bv.w;
  *(float4*)(x + (long)row * kD + c) = o;
  u16 h[4] = {f2bf(o.x), f2bf(o.y), f2bf(o.z), f2bf(o.w)};
  *(uint2*)(xb + (long)row * kD + c) = *(const uint2*)h;
}

// ===========================================================================
// FALLBACK PATH (Round-3 proven)
// ===========================================================================
template <int BM, int BN, typename TA, typename TB, int BKN>
__global__ __launch_bounds__(256)
void gemm_kernel(const void* __restrict__ Av, const void* __restrict__ Bv,
                 const float* __restrict__ bias, float* __restrict__ Cv,
                 const int K, const int lda, const int ldb, const int ldc,
                 const int nH, const long sAb, const long sAh,
                 const long sBb, const long sBh, const long sCb, const long sCh,
                 const float scale, const int relu) {
  constexpr int LP = 40;
  __shared__ u16 As[BM][LP];
  __shared__ u16 Bs[BN][LP];
  const int tid = threadIdx.x;
  const int z = blockIdx.z;
  const int zb = z / nH, zh = z - zb * nH;
  const TA* A = (const TA*)Av + zb * sAb + zh * sAh + (long)blockIdx.y * BM * lda;
  const TB* Bp;
  if constexpr (BKN)
    Bp = (const TB*)Bv + zb * sBb + zh * sBh + (long)blockIdx.x * BN;
  else
    Bp = (const TB*)Bv + zb * sBb + zh * sBh + (long)blockIdx.x * BN * ldb;
  const long offC = zb * sCb + zh * sCh;
  const int lane = tid & 63;
  const int wm = (tid >> 7) & 1, wn = (tid >> 6) & 1;
  constexpr int FM = BM / 32, FN = BN / 32;
  v4f acc[FM][FN];
  const v4f zero = {0.f, 0.f, 0.f, 0.f};
#pragma unroll
  for (int i = 0; i < FM; ++i)
#pragma unroll
    for (int j = 0; j < FN; ++j) acc[i][j] = zero;
  const int l15 = lane & 15, lk = lane >> 4;

  for (int k0 = 0; k0 < K; k0 += 32) {
    __syncthreads();
    if constexpr (sizeof(TA) == 4) {
      const int r = tid >> 3, c = (tid & 7) * 4;
#pragma unroll
      for (int rr = 0; rr < BM; rr += 32) {
        float4 vv = *(const float4*)((const float*)A + (long)(rr + r) * lda + k0 + c);
        unsigned lo = (unsigned)f2bf(vv.x) | ((unsigned)f2bf(vv.y) << 16);
        unsigned hi = (unsigned)f2bf(vv.z) | ((unsigned)f2bf(vv.w) << 16);
        *(uint2*)&As[rr + r][c] = make_uint2(lo, hi);
      }
    } else {
      const int r = tid >> 2, c = (tid & 3) * 8;
#pragma unroll
      for (int rr = 0; rr < BM; rr += 64) {
        uint4 vv = *(const uint4*)((const u16*)A + (long)(rr + r) * lda + k0 + c);
        *(uint4*)&As[rr + r][c] = vv;
      }
    }
    if constexpr (BKN) {
      const int r = tid >> 3, c = (tid & 7) * 4;
#pragma unroll
      for (int nn = 0; nn < BN; nn += 32) {
        float4 vv = *(const float4*)((const float*)Bp + (long)(k0 + r) * ldb + nn + c);
        Bs[nn + c + 0][r] = f2bf(vv.x);
        Bs[nn + c + 1][r] = f2bf(vv.y);
        Bs[nn + c + 2][r] = f2bf(vv.z);
        Bs[nn + c + 3][r] = f2bf(vv.w);
      }
    } else if constexpr (sizeof(TB) == 4) {
      const int r = tid >> 3, c = (tid & 7) * 4;
#pragma unroll
      for (int rr = 0; rr < BN; rr += 32) {
        float4 vv = *(const float4*)((const float*)Bp + (long)(rr + r) * ldb + k0 + c);
        unsigned lo = (unsigned)f2bf(vv.x) | ((unsigned)f2bf(vv.y) << 16);
        unsigned hi = (unsigned)f2bf(vv.z) | ((unsigned)f2bf(vv.w) << 16);
        *(uint2*)&Bs[rr + r][c] = make_uint2(lo, hi);
      }
    } else {
      const int r = tid >> 2, c = (tid & 3) * 8;
#pragma unroll
      for (int rr = 0; rr < BN; rr += 64) {
        uint4 vv = *(const uint4*)((const u16*)Bp + (long)(rr + r) * ldb + k0 + c);
        *(uint4*)&Bs[rr + r][c] = vv;
      }
    }
    __syncthreads();
    v8bf af[FM], bfr[FN];
#pragma unroll
    for (int i = 0; i < FM; ++i)
      af[i] = *(const v8bf*)&As[wm * (BM / 2) + i * 16 + l15][lk * 8];
#pragma unroll
    for (int j = 0; j < FN; ++j)
      bfr[j] = *(const v8bf*)&Bs[wn * (BN / 2) + j * 16 + l15][lk * 8];
#pragma unroll
    for (int i = 0; i < FM; ++i)
#pragma unroll
      for (int j = 0; j < FN; ++j)
        acc[i][j] = __builtin_amdgcn_mfma_f32_16x16x32_bf16(af[i], bfr[j], acc[i][j], 0, 0, 0);
  }

  const long m0 = (long)blockIdx.y * BM + wm * (BM / 2);
  const int n0 = blockIdx.x * BN + wn * (BN / 2);
#pragma unroll
  for (int j = 0; j < FN; ++j) {
    const int col = n0 + j * 16 + l15;
    const float bv = bias ? bias[col] : 0.0f;
#pragma unroll
    for (int i = 0; i < FM; ++i) {
      const long row = m0 + i * 16 + lk * 4;
#pragma unroll
      for (int r = 0; r < 4; ++r) {
        float v = acc[i][j][r] * scale + bv;
        if (relu) v = fmaxf(v, 0.0f);
        Cv[offC + (row + r) * ldc + col] = v;
      }
    }
  }
}

__global__ void embed_kernel(const int* __restrict__ tgt, const float* __restrict__ emb,
                             float* __restrict__ x) {
  const int row = blockIdx.x;
  const int t = row & (kT - 1);
  const int tok = tgt[row];
  const int c = threadIdx.x * 4;
  float4 e = *(const float4*)(emb + (long)tok * kD + c);
  const float nl = -9.210340371976184f / (float)kD;
  const float a0 = (float)t * expf((float)c * nl);
  const float a1 = (float)t * expf((float)(c + 2) * nl);
  float4 o;
  o.x = e.x * 32.0f + sinf(a0);
  o.y = e.y * 32.0f + cosf(a0);
  o.z = e.z * 32.0f + sinf(a1);
  o.w = e.w * 32.0f + cosf(a1);
  *(float4*)(x + (long)row * kD + c) = o;
}

__global__ void transpose_v_kernel(const float* __restrict__ v, u16* __restrict__ vt) {
  __shared__ float tile[32][33];
  const int z = blockIdx.z;
  const int b = z >> 4, h = z & 15;
  const int t0 = blockIdx.x * 32, d0 = blockIdx.y * 32;
  const int tx = threadIdx.x, ty = threadIdx.y;
  const float* in = v + (long)b * kTD + (long)h * kDK;
#pragma unroll
  for (int i = 0; i < 4; ++i)
    tile[ty + 8 * i][tx] = in[(long)(t0 + ty + 8 * i) * kD + d0 + tx];
  __syncthreads();
  u16* o = vt + (long)z * kDK * kT;
#pragma unroll
  for (int i = 0; i < 4; ++i)
    o[(long)(d0 + ty + 8 * i) * kT + t0 + tx] = f2bf(tile[tx][ty + 8 * i]);
}

__global__ void softmax_kernel(float* __restrict__ w, const int causal) {
  const int rowg = blockIdx.x * 4 + (threadIdx.x >> 6);
  const int lane = threadIdx.x & 63;
  const int q = rowg & (kT - 1);
  float* p = w + (long)rowg * kT + lane * 8;
  float4 v0 = *(const float4*)p;
  float4 v1 = *(const float4*)(p + 4);
  float f[8] = {v0.x, v0.y, v0.z, v0.w, v1.x, v1.y, v1.z, v1.w};
  const int base = lane * 8;
  float mx = -3.0e38f;
#pragma unroll
  for (int j = 0; j < 8; ++j)
    if (!causal || base + j <= q) mx = fmaxf(mx, f[j]);
#pragma unroll
  for (int o = 32; o > 0; o >>= 1) mx = fmaxf(mx, __shfl_xor(mx, o));
  float s = 0.0f;
#pragma unroll
  for (int j = 0; j < 8; ++j) {
    float e = (!causal || base + j <= q) ? __expf(f[j] - mx) : 0.0f;
    f[j] = e; s += e;
  }
#pragma unroll
  for (int o = 32; o > 0; o >>= 1) s += __shfl_xor(s, o);
  const float inv = 1.0f / s;
  float4 o0 = {f[0] * inv, f[1] * inv, f[2] * inv, f[3] * inv};
  float4 o1 = {f[4] * inv, f[5] * inv, f[6] * inv, f[7] * inv};
  *(float4*)p = o0;
  *(float4*)(p + 4) = o1;
}

__global__ void add_ln_kernel(float* __restrict__ x, const float* __restrict__ res,
                              const float* __restrict__ g, const float* __restrict__ b) {
  const int row = blockIdx.x;
  const int c = threadIdx.x * 4;
  float4 xv = *(const float4*)(x + (long)row * kD + c);
  float4 rv = *(const float4*)(res + (long)row * kD + c);
  const float v0 = xv.x + rv.x, v1 = xv.y + rv.y, v2 = xv.z + rv.z, v3 = xv.w + rv.w;
  float s = v0 + v1 + v2 + v3;
  float ss = v0 * v0 + v1 * v1 + v2 * v2 + v3 * v3;
#pragma unroll
  for (int o = 32; o > 0; o >>= 1) { s += __shfl_xor(s, o); ss += __shfl_xor(ss, o); }
  __shared__ float red[4][2];
  const int wv = threadIdx.x >> 6;
  if ((threadIdx.x & 63) == 0) { red[wv][0] = s; red[wv][1] = ss; }
  __syncthreads();
  s  = red[0][0] + red[1][0] + red[2][0] + red[3][0];
  ss = red[0][1] + red[1][1] + red[2][1] + red[3][1];
  const float mean = s * (1.0f / kD);
  const float var = ss * (1.0f / kD) - mean * mean;
  const float rs = rsqrtf(var + 1e-5f);
  float4 gv = *(const float4*)(g + c);
  float4 bv = *(const float4*)(b + c);
  float4 o;
  o.x = gv.x * (v0 - mean) * rs + bv.x;
  o.y = gv.y * (v1 - mean) * rs + bv.y;
  o.z = gv.z * (v2 - mean) * rs + bv.z;
  o.w = gv.w * (v3 - mean) * rs + bv.w;
  *(float4*)(x + (long)row * kD + c) = o;
}

// ===========================================================================
extern "C" void kernel_launch(void* const* d_in, const int* in_sizes, int n_in,
                              void* d_out, int out_size, void* d_ws, size_t ws_size,
                              hipStream_t stream) {
  const int*   tgt  = (const int*)d_in[0];
  const float* enc  = (const float*)d_in[1];
  const float* emb  = (const float*)d_in[3];
  const float* Wout = (const float*)d_in[4];
  const float* bout = (const float*)d_in[5];
  const float* Wq_s = (const float*)d_in[6];
  const float* bq_s = (const float*)d_in[7];
  const float* Wk_s = (const float*)d_in[8];
  const float* bk_s = (const float*)d_in[9];
  const float* Wv_s = (const float*)d_in[10];
  const float* bv_s = (const float*)d_in[11];
  const float* Wo_s = (const float*)d_in[12];
  const float* bo_s = (const float*)d_in[13];
  const float* Wq_c = (const float*)d_in[14];
  const float* bq_c = (const float*)d_in[15];
  const float* Wk_c = (const float*)d_in[16];
  const float* bk_c = (const float*)d_in[17];
  const float* Wv_c = (const float*)d_in[18];
  const float* bv_c = (const float*)d_in[19];
  const float* Wo_c = (const float*)d_in[20];
  const float* bo_c = (const float*)d_in[21];
  const float* W1   = (const float*)d_in[22];
  const float* b1   = (const float*)d_in[23];
  const float* W2   = (const float*)d_in[24];
  const float* b2   = (const float*)d_in[25];
  const float* ln1g = (const float*)d_in[26];
  const float* ln1b = (const float*)d_in[27];
  const float* ln2g = (const float*)d_in[28];
  const float* ln2b = (const float*)d_in[29];
  const float* ln3g = (const float*)d_in[30];
  const float* ln3b = (const float*)d_in[31];

  float* out = (float*)d_out;
  const long DD = (long)kD * kD;
  const dim3 blk256(256), blkT(32, 8);

  if (ws_size >= (320ll << 20)) {
    // =================== FAST PATH ===================
    char* ws = (char*)d_ws;
    float* x     = (float*)ws;                    // 8 MiB
    u16* xb      = (u16*)(ws + (8l << 20));       // 4 MiB
    u16* encb    = (u16*)(ws + (12l << 20));      // 4 MiB
    u16* Sqkv    = (u16*)(ws + (16l << 20));      // 12 MiB (2048x3072)
    u16* vt      = (u16*)(ws + (28l << 20));      // 4 MiB
    u16* S3b     = (u16*)(ws + (32l << 20));      // 4 MiB
    u16* Hb      = (u16*)(ws + (36l << 20));      // 16 MiB (2048x4096)
    float* Spart = (float*)(ws + (52l << 20));    // 32 MiB (4 f32 partials)
    u16* Pb      = (u16*)(ws + (84l << 20));      // 32 MiB (B,H,T,T)
    u16* wbase   = (u16*)(ws + (116l << 20));     // 128 MiB (4x32)
    u16* woutT   = (u16*)(ws + (244l << 20));     // 62.5 MiB
    float* bqkvS = (float*)(ws + (308l << 20));   // 48 KiB
    float* bkvC  = (float*)(ws + (308l << 20) + (64l << 10));  // 32 KiB
    const long WLAY = (32l << 20) / 2;            // u16 elems per layer block

    // ---- one-time prep ----
    for (int i = 0; i < kL; ++i) {
      u16* wqkvS = wbase + i * WLAY;
      u16* woS   = wqkvS + 3072 * 1024;
      u16* wqC   = woS + 1024 * 1024;
      u16* wkvC  = wqC + 1024 * 1024;
      u16* woC   = wkvC + 2048 * 1024;
      u16* w1t   = woC + 1024 * 1024;
      u16* w2t   = w1t + (long)4096 * 1024;
      TPtrs p{};
      p.in[0] = Wq_s + i * DD; p.out[0] = wqkvS;
      p.in[1] = Wk_s + i * DD; p.out[1] = wqkvS + 1024 * 1024;
      p.in[2] = Wv_s + i * DD; p.out[2] = wqkvS + 2048 * 1024;
      p.in[3] = Wo_s + i * DD; p.out[3] = woS;
      p.in[4] = Wq_c + i * DD; p.out[4] = wqC;
      p.in[5] = Wk_c + i * DD; p.out[5] = wkvC;
      p.in[6] = Wv_c + i * DD; p.out[6] = wkvC + 1024 * 1024;
      p.in[7] = Wo_c + i * DD; p.out[7] = woC;
      transpose_wt_v2<<<dim3(32, 32, 8), blkT, 0, stream>>>(p, 1024, 1024);
      TPtrs p1{}; p1.in[0] = W1 + (long)i * kD * kF; p1.out[0] = w1t;
      transpose_wt_v2<<<dim3(128, 32, 1), blkT, 0, stream>>>(p1, 1024, 4096);
      TPtrs p2{}; p2.in[0] = W2 + (long)i * kF * kD; p2.out[0] = w2t;
      transpose_wt_v2<<<dim3(32, 128, 1), blkT, 0, stream>>>(p2, 4096, 1024);
    }
    TPtrs po{}; po.in[0] = Wout; po.out[0] = woutT;
    transpose_wt_v2<<<dim3(1000, 32, 1), blkT, 0, stream>>>(po, 1024, 32000);
    concat_bias<<<dim3(48), blk256, 0, stream>>>(bqkvS, bq_s, bk_s, bv_s, 3);
    concat_bias<<<dim3(32), blk256, 0, stream>>>(bkvC, bk_c, bv_c, nullptr, 2);
    cvt_bf16_v2<<<dim3(2048), blk256, 0, stream>>>(enc, encb);
    embed_v2<<<dim3(kM), blk256, 0, stream>>>(tgt, emb, x, xb);

    for (int i = 0; i < kL; ++i) {
      u16* wqkvS = wbase + i * WLAY;
      u16* woS   = wqkvS + 3072 * 1024;
      u16* wqC   = woS + 1024 * 1024;
      u16* wkvC  = wqC + 1024 * 1024;
      u16* woC   = wkvC + 2048 * 1024;
      u16* w1t   = woC + 1024 * 1024;
      u16* w2t   = w1t + (long)4096 * 1024;
      float* wSelf  = out + kLOG + (long)i * kBHTT;
      float* wCross = out + kLOG + (long)kL * kBHTT + (long)i * kBHTT;

      // -------- self attention --------
      gemm_bf<128, 128, 1><<<dim3(24, 16, 1), blk256, 0, stream>>>(
          xb, wqkvS, bqkvS + i * 3072, Sqkv, 1024, 1024, 1024, 3072,
          1, 0, 0, 0, 0, 0, 0, 1.0f, 0);
      transpose_v_v2<<<dim3(16, 2, 64), blkT, 0, stream>>>(Sqkv, vt);
      attn_scores<1><<<dim3(4, 64), dim3(512), 0, stream>>>(Sqkv, Sqkv + 1024, wSelf, Pb);
      gemm_bf<128, 64, 1><<<dim3(1, 4, 64), blk256, 0, stream>>>(
          Pb, vt, nullptr, S3b, 512, 512, 512, 1024,
          16, kHTT, kTT, 16l * 32768, 32768, 512l * 1024, 64, 1.0f, 0);
      gemm_bf<128, 128, 0><<<dim3(8, 16, 2), blk256, 0, stream>>>(
          S3b, woS, bo_s + (long)i * kD, Spart, 512, 1024, 1024, 1024,
          1, 512, 0, 512, 0, kPART, 0, 1.0f, 0);
      add_ln_v3<<<dim3(kM), blk256, 0, stream>>>(x, xb, Spart, 2,
          ln1g + (long)i * kD, ln1b + (long)i * kD);

      // -------- cross attention --------
      gemm_bf<128, 128, 1><<<dim3(8, 16, 1), blk256, 0, stream>>>(
          xb, wqC, bq_c + (long)i * kD, Sqkv, 1024, 1024, 1024, 3072,
          1, 0, 0, 0, 0, 0, 0, 1.0f, 0);
      gemm_bf<128, 128, 1><<<dim3(16, 16, 1), blk256, 0, stream>>>(
          encb, wkvC, bkvC + i * 2048, Sqkv + 1024, 1024, 1024, 1024, 3072,
          1, 0, 0, 0, 0, 0, 0, 1.0f, 0);
      transpose_v_v2<<<dim3(16, 2, 64), blkT, 0, stream>>>(Sqkv, vt);
      attn_scores<0><<<dim3(4, 64), dim3(512), 0, stream>>>(Sqkv, Sqkv + 1024, wCross, Pb);
      gemm_bf<128, 64, 1><<<dim3(1, 4, 64), blk256, 0, stream>>>(
          Pb, vt, nullptr, S3b, 512, 512, 512, 1024,
          16, kHTT, kTT, 16l * 32768, 32768, 512l * 1024, 64, 1.0f, 0);
      gemm_bf<128, 128, 0><<<dim3(8, 16, 2), blk256, 0, stream>>>(
          S3b, woC, bo_c + (long)i * kD, Spart, 512, 1024, 1024, 1024,
          1, 512, 0, 512, 0, kPART, 0, 1.0f, 0);
      add_ln_v3<<<dim3(kM), blk256, 0, stream>>>(x, xb, Spart, 2,
          ln2g + (long)i * kD, ln2b + (long)i * kD);

      // -------- FFN --------
      gemm_bf<128, 128, 1><<<dim3(32, 16, 1), blk256, 0, stream>>>(
          xb, w1t, b1 + (long)i * kF, Hb, 1024, 1024, 1024, 4096,
          1, 0, 0, 0, 0, 0, 0, 1.0f, 1);
      gemm_bf<128, 128, 0><<<dim3(8, 16, 4), blk256, 0, stream>>>(
          Hb, w2t, b2 + (long)i * kD, Spart, 1024, 4096, 4096, 1024,
          1, 1024, 0, 1024, 0, kPART, 0, 1.0f, 0);
      add_ln_v3<<<dim3(kM), blk256, 0, stream>>>(x, xb, Spart, 4,
          ln3g + (long)i * kD, ln3b + (long)i * kD);
    }

    gemm_bf<128, 128, 0><<<dim3(250, 16, 1), blk256, 0, stream>>>(
        xb, woutT, bout, out, 1024, 1024, 1024, 32000,
        1, 0, 0, 0, 0, 0, 0, 1.0f, 0);
    return;
  }

  // =================== FALLBACK (Round-3 verified) ===================
  float* x = (float*)d_ws;
  char* sc = (char*)d_out;
  float* S0 = (float*)sc;
  float* S1 = (float*)(sc + (8l  << 20));
  float* S2 = (float*)(sc + (16l << 20));
  float* S3 = (float*)(sc + (24l << 20));
  float* S4 = (float*)(sc + (32l << 20));
  u16*   vt = (u16*)  (sc + (40l << 20));

  embed_kernel<<<dim3(kM), blk256, 0, stream>>>(tgt, emb, x);
  auto wgemm = [&](const float* A, const float* W, const float* bias, float* C) {
    gemm_kernel<128, 128, float, float, 1><<<dim3(kD / 128, kM / 128, 1), blk256, 0, stream>>>(
        A, W, bias, C, kD, kD, kD, kD, 1, 0, 0, 0, 0, 0, 0, 1.0f, 0);
  };
  for (int i = 0; i < kL; ++i) {
    const long wOff = (long)i * DD;
    float* wSelf  = out + kLOG + (long)i * kBHTT;
    float* wCross = out + kLOG + (long)kL * kBHTT + (long)i * kBHTT;
    wgemm(x, Wq_s + wOff, bq_s + (long)i * kD, S0);
    wgemm(x, Wk_s + wOff, bk_s + (long)i * kD, S1);
    wgemm(x, Wv_s + wOff, bv_s + (long)i * kD, S2);
    transpose_v_kernel<<<dim3(16, 2, 64), blkT, 0, stream>>>(S2, vt);
    gemm_kernel<128, 128, float, float, 0><<<dim3(4, 4, 64), blk256, 0, stream>>>(
        S0, S1, nullptr, wSelf, kDK, kD, kD, kT,
        kH, kTD, (long)kDK, kTD, (long)kDK, kHTT, kTT, 0.125f, 0);
    softmax_kernel<<<dim3(kB * kH * kT / 4), blk256, 0, stream>>>(wSelf, 1);
    gemm_kernel<128, 64, float, u16, 0><<<dim3(1, 4, 64), blk256, 0, stream>>>(
        wSelf, vt, nullptr, S3, kT, kT, kT, kD,
        kH, kHTT, kTT, (long)kH * kDK * kT, (long)kDK * kT, kTD, (long)kDK, 1.0f, 0);
    wgemm(S3, Wo_s + wOff, bo_s + (long)i * kD, S0);
    add_ln_kernel<<<dim3(kM), blk256, 0, stream>>>(x, S0, ln1g + (long)i * kD, ln1b + (long)i * kD);
    wgemm(x,   Wq_c + wOff, bq_c + (long)i * kD, S0);
    wgemm(enc, Wk_c + wOff, bk_c + (long)i * kD, S1);
    wgemm(enc, Wv_c + wOff, bv_c + (long)i * kD, S2);
    transpose_v_kernel<<<dim3(16, 2, 64), blkT, 0, stream>>>(S2, vt);
    gemm_kernel<128, 128, float, float, 0><<<dim3(4, 4, 64), blk256, 0, stream>>>(
        S0, S1, nullptr, wCross, kDK, kD, kD, kT,
        kH, kTD, (long)kDK, kTD, (long)kDK, kHTT, kTT, 0.125f, 0);
    softmax_kernel<<<dim3(kB * kH * kT / 4), blk256, 0, stream>>>(wCross, 0);
    gemm_kernel<128, 64, float, u16, 0><<<dim3(1, 4, 64), blk256, 0, stream>>>(
        wCross, vt, nullptr, S3, kT, kT, kT, kD,
        kH, kHTT, kTT, (long)kH * kDK * kT, (long)kDK * kT, kTD, (long)kDK, 1.0f, 0);
    wgemm(S3, Wo_c + wOff, bo_c + (long)i * kD, S0);
    add_ln_kernel<<<dim3(kM), blk256, 0, stream>>>(x, S0, ln2g + (long)i * kD, ln2b + (long)i * kD);
    gemm_kernel<128, 128, float, float, 1><<<dim3(kF / 128, kM / 128, 1), blk256, 0, stream>>>(
        x, W1 + (long)i * kD * kF, b1 + (long)i * kF, S0, kD, kD, kF, kF,
        1, 0, 0, 0, 0, 0, 0, 1.0f, 1);
    gemm_kernel<128, 128, float, float, 1><<<dim3(kD / 128, kM / 128, 1), blk256, 0, stream>>>(
        S0, W2 + (long)i * kF * kD, b2 + (long)i * kD, S4, kF, kF, kD, kD,
        1, 0, 0, 0, 0, 0, 0, 1.0f, 0);
    add_ln_kernel<<<dim3(kM), blk256, 0, stream>>>(x, S4, ln3g + (long)i * kD, ln3b + (long)i * kD);
  }
  gemm_kernel<128, 128, float, float, 1><<<dim3(kV / 128, kM / 128, 1), blk256, 0, stream>>>(
      x, Wout, bout, out, kD, kD, kV, kV,
      1, 0, 0, 0, 0, 0, 0, 1.0f, 0);
}

// Round 8
// 1585.058 us; speedup vs baseline: 2.1965x; 1.0632x over previous
//
#include <hip/hip_runtime.h>

// TransformerDecoder on MI355X. Round 7: Round-6 design, compile fix (a
// trailing backslash in a // comment line-spliced away the encb declaration).
// - T2 LDS xor-swizzle in GEMM (fixes 16-way bank conflict of BK=64 layout)
// - fused QK^T+softmax+PV attention kernel
// - merged cross Q/KV GEMM; V^T produced in QKV GEMM epilogue
// Fallback = Round-3 proven path.

typedef unsigned short u16;
typedef __bf16 v8bf __attribute__((ext_vector_type(8)));
typedef float v4f __attribute__((ext_vector_type(4)));

namespace {
constexpr int kB = 4, kT = 512, kD = 1024, kH = 16, kDK = 64, kF = 4096, kV = 32000, kL = 4;
constexpr int kM = kB * kT;
constexpr long kTD = (long)kT * kD;
constexpr long kTT = (long)kT * kT;
constexpr long kHTT = (long)kH * kTT;
constexpr long kBHTT = (long)kB * kHTT;
constexpr long kLOG = (long)kM * kV;
constexpr long kPART = (long)kM * kD;
}

__device__ __forceinline__ u16 f2bf(float f) {
  union { float f; unsigned u; } v; v.f = f;
  unsigned r = v.u + 0x7FFFu + ((v.u >> 16) & 1u);
  return (u16)(r >> 16);
}
__device__ __forceinline__ float bf2f(u16 h) {
  union { unsigned u; float f; } v; v.u = ((unsigned)h) << 16;
  return v.f;
}

typedef __attribute__((address_space(3))) void lds_void;
typedef const __attribute__((address_space(1))) void glob_void;
__device__ __forceinline__ void gl2lds16(const void* g, void* l) {
  __builtin_amdgcn_global_load_lds((glob_void*)g, (lds_void*)l, 16, 0, 0);
}

// ---------------------------------------------------------------------------
// bf16 GEMM, BK=64, swizzled LDS (rows of 64 u16 = 8 x 16B slots; physical
// slot p of row r holds logical chunk p^(r&7); staging pre-swizzles the
// global source, reads xor the chunk index). C[m][n] = scale*sum A[m][k]*B[n][k]
// + bias[zh*bstride + n] (zb==0 only). VTR: cols>=2048 also written transposed
// into vt (B,H,dk,T) — used by QKV GEMMs to produce V^T for attention.
// ---------------------------------------------------------------------------
template <int BM, int BN, int OUTBF, int VTR>
__global__ __launch_bounds__(256)
void gemm_bf(const u16* __restrict__ A0, const u16* __restrict__ B0,
             const float* __restrict__ bias, void* __restrict__ Cv,
             u16* __restrict__ vtw,
             const int K, const int lda, const int ldb, const int ldc,
             const int nH, const long sAb, const long sAh,
             const long sBb, const long sBh, const long sCb, const long sCh,
             const float scale, const int relu, const int bstride) {
  static_assert(BM % 32 == 0 && BN % 32 == 0, "tiles");
  __shared__ u16 As[BM][64];
  __shared__ u16 Bs[BN][64];
  const int tid = threadIdx.x;
  const int lane = tid & 63;
  const int w = tid >> 6;
  const int z = blockIdx.z;
  const int zb = z / nH, zh = z - zb * nH;
  const u16* A = A0 + zb * sAb + zh * sAh + (long)blockIdx.y * BM * lda;
  const u16* B = B0 + zb * sBb + zh * sBh + (long)blockIdx.x * BN * ldb;
  const long offC = zb * sCb + zh * sCh;
  const int wm = w >> 1, wn = w & 1;
  constexpr int FM = BM / 32, FN = BN / 32;
  v4f acc[FM][FN];
  const v4f zero = {0.f, 0.f, 0.f, 0.f};
#pragma unroll
  for (int i = 0; i < FM; ++i)
#pragma unroll
    for (int j = 0; j < FN; ++j) acc[i][j] = zero;
  const int l15 = lane & 15, lk = lane >> 4;
  const int lr8 = lane >> 3;                       // row within 8-row stripe
  const int swz = ((lane & 7) ^ lr8) * 8;          // pre-swizzled source col
  const int l7 = l15 & 7;

  for (int k0 = 0; k0 < K; k0 += 64) {
    __syncthreads();
#pragma unroll
    for (int s = 0; s < BM / 32; ++s)
      gl2lds16(A + (long)(w * (BM / 4) + s * 8 + lr8) * lda + k0 + swz,
               &As[w * (BM / 4) + s * 8][0]);
#pragma unroll
    for (int s = 0; s < BN / 32; ++s)
      gl2lds16(B + (long)(w * (BN / 4) + s * 8 + lr8) * ldb + k0 + swz,
               &Bs[w * (BN / 4) + s * 8][0]);
    __syncthreads();
#pragma unroll
    for (int t = 0; t < 2; ++t) {
      const int c0 = t * 4;
      v8bf af[FM], bfr[FN];
#pragma unroll
      for (int i = 0; i < FM; ++i)
        af[i] = *(const v8bf*)&As[wm * (BM / 2) + i * 16 + l15][((c0 + lk) ^ l7) * 8];
#pragma unroll
      for (int j = 0; j < FN; ++j)
        bfr[j] = *(const v8bf*)&Bs[wn * (BN / 2) + j * 16 + l15][((c0 + lk) ^ l7) * 8];
#pragma unroll
      for (int i = 0; i < FM; ++i)
#pragma unroll
        for (int j = 0; j < FN; ++j)
          acc[i][j] = __builtin_amdgcn_mfma_f32_16x16x32_bf16(af[i], bfr[j], acc[i][j], 0, 0, 0);
    }
  }

  const long m0 = (long)blockIdx.y * BM + wm * (BM / 2);
  const int n0 = blockIdx.x * BN + wn * (BN / 2);
#pragma unroll
  for (int j = 0; j < FN; ++j) {
    const int col = n0 + j * 16 + l15;
    const float bv = (bias && zb == 0) ? bias[zh * bstride + col] : 0.0f;
#pragma unroll
    for (int i = 0; i < FM; ++i) {
      const long row = m0 + i * 16 + lk * 4;
#pragma unroll
      for (int r = 0; r < 4; ++r) {
        float v = acc[i][j][r] * scale + bv;
        if (relu) v = fmaxf(v, 0.0f);
        const long idx = offC + (row + r) * ldc + col;
        if (OUTBF) ((u16*)Cv)[idx] = f2bf(v);
        else       ((float*)Cv)[idx] = v;
        if (VTR) {
          const int colS = (int)(offC % 3072) + col;   // column within (.,3072)
          if (colS >= 2048) {
            const int hh = (colS - 2048) >> 6, dd = (colS - 2048) & 63;
            const int rowg = (int)(row + r);
            vtw[((long)((rowg >> 9) * 16 + hh)) * 32768 + dd * 512 + (rowg & 511)] = f2bf(v);
          }
        }
      }
    }
  }
}

// ---------------------------------------------------------------------------
// Fused attention: per block 128 q-rows x one (b,h): QK^T (swizzled LDS),
// softmax (writes w f32 to d_out), then PV via padded-LDS P/V^T chunks,
// writes O bf16 into S3b (2048,1024). 512 threads = 8 waves (2 wm x 4 wn).
// ---------------------------------------------------------------------------
template <int CAUSAL>
__global__ __launch_bounds__(512)
void attn_fused(const u16* __restrict__ Qb, const u16* __restrict__ Kb,
                const u16* __restrict__ vtp, float* __restrict__ wout,
                u16* __restrict__ oout) {
  __shared__ __align__(16) char lds[81920];
  u16 (*Qs)[64] = (u16 (*)[64])lds;                 // [128][64]
  u16 (*Ks)[64] = (u16 (*)[64])(lds + 16384);       // [512][64]
  u16 (*Pl)[136] = (u16 (*)[136])lds;               // [128][136] 34816 B
  u16 (*Vt)[136] = (u16 (*)[136])(lds + 34816);     // [64][136]  17408 B
  __shared__ float redM[128][4];
  __shared__ float redS[128][4];
  const int tid = threadIdx.x, lane = tid & 63, w = tid >> 6;
  const int wm = w >> 2, wn = w & 3;
  const int l15 = lane & 15, lk = lane >> 4;
  const int lr8 = lane >> 3;
  const int swz = ((lane & 7) ^ lr8) * 8;
  const int l7 = l15 & 7;
  const int bx = blockIdx.x;
  const int z = blockIdx.y, zb = z >> 4, zh = z & 15;
  const u16* Q = Qb + (long)zb * 512 * 3072 + zh * 64 + (long)bx * 128 * 3072;
  const u16* Kp = Kb + (long)zb * 512 * 3072 + zh * 64;
  const u16* vtz = vtp + (long)((zb << 4) + zh) * 32768;
  const long obase = (long)zb * kHTT + (long)zh * kTT;

#pragma unroll
  for (int s = 0; s < 2; ++s)
    gl2lds16(Q + (long)(w * 16 + s * 8 + lr8) * 3072 + swz, &Qs[w * 16 + s * 8][0]);
#pragma unroll
  for (int s = 0; s < 8; ++s) {
    const int r0 = w * 64 + s * 8;
    if (!CAUSAL || r0 <= bx * 128 + 127)
      gl2lds16(Kp + (long)(r0 + lr8) * 3072 + swz, &Ks[r0][0]);
  }
  __syncthreads();

  v4f acc[4][8];
  const v4f zero = {0.f, 0.f, 0.f, 0.f};
#pragma unroll
  for (int i = 0; i < 4; ++i)
#pragma unroll
    for (int j = 0; j < 8; ++j) acc[i][j] = zero;

#pragma unroll
  for (int t = 0; t < 2; ++t) {
    const int c0 = t * 4;
    v8bf aq[4], bk[8];
#pragma unroll
    for (int i = 0; i < 4; ++i)
      aq[i] = *(const v8bf*)&Qs[wm * 64 + i * 16 + l15][((c0 + lk) ^ l7) * 8];
#pragma unroll
    for (int j = 0; j < 8; ++j)
      bk[j] = *(const v8bf*)&Ks[wn * 128 + j * 16 + l15][((c0 + lk) ^ l7) * 8];
#pragma unroll
    for (int i = 0; i < 4; ++i)
#pragma unroll
      for (int j = 0; j < 8; ++j)
        if (!(CAUSAL && wn * 128 + j * 16 > bx * 128 + wm * 64 + i * 16 + 15))
          acc[i][j] = __builtin_amdgcn_mfma_f32_16x16x32_bf16(aq[i], bk[j], acc[i][j], 0, 0, 0);
  }

  // row max
  float gmax[4][4];
#pragma unroll
  for (int i = 0; i < 4; ++i)
#pragma unroll
    for (int r = 0; r < 4; ++r) {
      const int q = bx * 128 + wm * 64 + i * 16 + lk * 4 + r;
      float m = -3.0e38f;
#pragma unroll
      for (int j = 0; j < 8; ++j) {
        const int col = wn * 128 + j * 16 + l15;
        if (!CAUSAL || col <= q) m = fmaxf(m, acc[i][j][r] * 0.125f);
      }
#pragma unroll
      for (int off = 1; off < 16; off <<= 1) m = fmaxf(m, __shfl_xor(m, off));
      if (l15 == 0) redM[wm * 64 + i * 16 + lk * 4 + r][wn] = m;
    }
  __syncthreads();
#pragma unroll
  for (int i = 0; i < 4; ++i)
#pragma unroll
    for (int r = 0; r < 4; ++r) {
      v4f mv = *(const v4f*)&redM[wm * 64 + i * 16 + lk * 4 + r][0];
      gmax[i][r] = fmaxf(fmaxf(mv[0], mv[1]), fmaxf(mv[2], mv[3]));
    }
  // exp + row sum
#pragma unroll
  for (int i = 0; i < 4; ++i)
#pragma unroll
    for (int r = 0; r < 4; ++r) {
      const int q = bx * 128 + wm * 64 + i * 16 + lk * 4 + r;
      float s = 0.0f;
#pragma unroll
      for (int j = 0; j < 8; ++j) {
        const int col = wn * 128 + j * 16 + l15;
        float e = (!CAUSAL || col <= q) ? __expf(acc[i][j][r] * 0.125f - gmax[i][r]) : 0.0f;
        acc[i][j][r] = e;
        s += e;
      }
#pragma unroll
      for (int off = 1; off < 16; off <<= 1) s += __shfl_xor(s, off);
      if (l15 == 0) redS[wm * 64 + i * 16 + lk * 4 + r][wn] = s;
    }
  __syncthreads();
  // normalize, write w (f32), keep normalized P in acc
#pragma unroll
  for (int i = 0; i < 4; ++i)
#pragma unroll
    for (int r = 0; r < 4; ++r) {
      v4f sv = *(const v4f*)&redS[wm * 64 + i * 16 + lk * 4 + r][0];
      const float inv = 1.0f / (sv[0] + sv[1] + sv[2] + sv[3]);
      const int q = bx * 128 + wm * 64 + i * 16 + lk * 4 + r;
      const long rowoff = obase + (long)q * 512;
#pragma unroll
      for (int j = 0; j < 8; ++j) {
        const int col = wn * 128 + j * 16 + l15;
        const float v = acc[i][j][r] * inv;
        acc[i][j][r] = v;
        wout[rowoff + col] = v;
      }
    }

  // ---- PV: O[128 q][64 d] = P @ V, chunked over k (128 per chunk) ----
  v4f acco[4];
#pragma unroll
  for (int i = 0; i < 4; ++i) acco[i] = zero;
  const int kcMax = CAUSAL ? bx : 3;
  for (int kc = 0; kc <= kcMax; ++kc) {
    __syncthreads();
    if (wn == kc) {       // this wave-group owns P cols [kc*128, kc*128+128)
#pragma unroll
      for (int i = 0; i < 4; ++i)
#pragma unroll
        for (int j = 0; j < 8; ++j) {
          const int colk = j * 16 + l15;
#pragma unroll
          for (int r = 0; r < 4; ++r)
            Pl[wm * 64 + i * 16 + lk * 4 + r][colk] = f2bf(acc[i][j][r]);
        }
    }
    // stage V^T chunk [64 d][128 k] into padded Vt
#pragma unroll
    for (int s = 0; s < 2; ++s) {
      const int c = tid * 2 + s;            // 0..1023 chunks of 16B
      const int d = c >> 4, off = (c & 15) * 8;
      uint4 vv = *(const uint4*)(vtz + (long)d * 512 + kc * 128 + off);
      *(uint4*)&Vt[d][off] = vv;
    }
    __syncthreads();
#pragma unroll
    for (int t = 0; t < 4; ++t) {
      v8bf bv = *(const v8bf*)&Vt[wn * 16 + l15][t * 32 + lk * 8];
#pragma unroll
      for (int i = 0; i < 4; ++i) {
        v8bf ap = *(const v8bf*)&Pl[wm * 64 + i * 16 + l15][t * 32 + lk * 8];
        acco[i] = __builtin_amdgcn_mfma_f32_16x16x32_bf16(ap, bv, acco[i], 0, 0, 0);
      }
    }
  }
  // write O bf16 into S3b (2048,1024) at column zh*64
#pragma unroll
  for (int i = 0; i < 4; ++i)
#pragma unroll
    for (int r = 0; r < 4; ++r) {
      const int row = bx * 128 + wm * 64 + i * 16 + lk * 4 + r;
      oout[(long)(zb * 512 + row) * 1024 + zh * 64 + wn * 16 + l15] = f2bf(acco[i][r]);
    }
}

// Weight transpose-convert: out(N,K) bf16 = in(K,N)^T f32; batched ptr pairs.
struct TPtrs { const float* in[8]; u16* out[8]; };

__global__ void transpose_wt_v2(TPtrs ps, int K, int N) {
  __shared__ float tile[32][33];
  const float* in = ps.in[blockIdx.z];
  u16* o = ps.out[blockIdx.z];
  const int n0 = blockIdx.x * 32, k0 = blockIdx.y * 32;
  const int tx = threadIdx.x, ty = threadIdx.y;
#pragma unroll
  for (int i = 0; i < 4; ++i)
    tile[ty + 8 * i][tx] = in[(long)(k0 + ty + 8 * i) * N + n0 + tx];
  __syncthreads();
#pragma unroll
  for (int i = 0; i < 4; ++i)
    o[(long)(n0 + ty + 8 * i) * K + k0 + tx] = f2bf(tile[tx][ty + 8 * i]);
}

__global__ void concat_bias(float* __restrict__ dst, const float* __restrict__ s0,
                            const float* __restrict__ s1, const float* __restrict__ s2,
                            const int nsrc) {
  const int idx = blockIdx.x * 256 + threadIdx.x;
  const int per = nsrc << 10;
  const int l = idx / per, rem = idx - l * per, s = rem >> 10, j = rem & 1023;
  const float* src = (s == 0) ? s0 : (s == 1 ? s1 : s2);
  dst[idx] = src[l * 1024 + j];
}

__global__ void cvt_bf16_v3(const float* __restrict__ in, u16* __restrict__ o1,
                            u16* __restrict__ o2) {
  const long i = ((long)blockIdx.x * 256 + threadIdx.x) * 4;
  float4 v = *(const float4*)(in + i);
  u16 h[4] = {f2bf(v.x), f2bf(v.y), f2bf(v.z), f2bf(v.w)};
  *(uint2*)(o1 + i) = *(const uint2*)h;
  *(uint2*)(o2 + i) = *(const uint2*)h;
}

__global__ void embed_v2(const int* __restrict__ tgt, const float* __restrict__ emb,
                         float* __restrict__ x, u16* __restrict__ xb) {
  const int row = blockIdx.x;
  const int t = row & (kT - 1);
  const int tok = tgt[row];
  const int c = threadIdx.x * 4;
  float4 e = *(const float4*)(emb + (long)tok * kD + c);
  const float nl = -9.210340371976184f / (float)kD;
  const float a0 = (float)t * expf((float)c * nl);
  const float a1 = (float)t * expf((float)(c + 2) * nl);
  float4 o;
  o.x = e.x * 32.0f + sinf(a0);
  o.y = e.y * 32.0f + cosf(a0);
  o.z = e.z * 32.0f + sinf(a1);
  o.w = e.w * 32.0f + cosf(a1);
  *(float4*)(x + (long)row * kD + c) = o;
  u16 h[4] = {f2bf(o.x), f2bf(o.y), f2bf(o.z), f2bf(o.w)};
  *(uint2*)(xb + (long)row * kD + c) = *(const uint2*)h;
}

// x = LN(x + sum_{p<nres} res[p]); writes x f32 and xb bf16
__global__ void add_ln_v3(float* __restrict__ x, u16* __restrict__ xb,
                          const float* __restrict__ res, const int nres,
                          const float* __restrict__ g, const float* __restrict__ b) {
  const int row = blockIdx.x;
  const int c = threadIdx.x * 4;
  float4 xv = *(const float4*)(x + (long)row * kD + c);
  float v0 = xv.x, v1 = xv.y, v2 = xv.z, v3 = xv.w;
  for (int p = 0; p < nres; ++p) {
    float4 rv = *(const float4*)(res + p * kPART + (long)row * kD + c);
    v0 += rv.x; v1 += rv.y; v2 += rv.z; v3 += rv.w;
  }
  float s = v0 + v1 + v2 + v3;
  float ss = v0 * v0 + v1 * v1 + v2 * v2 + v3 * v3;
#pragma unroll
  for (int o = 32; o > 0; o >>= 1) { s += __shfl_xor(s, o); ss += __shfl_xor(ss, o); }
  __shared__ float red[4][2];
  const int wv = threadIdx.x >> 6;
  if ((threadIdx.x & 63) == 0) { red[wv][0] = s; red[wv][1] = ss; }
  __syncthreads();
  s  = red[0][0] + red[1][0] + red[2][0] + red[3][0];
  ss = red[0][1] + red[1][1] + red[2][1] + red[3][1];
  const float mean = s * (1.0f / kD);
  const float var = ss * (1.0f / kD) - mean * mean;
  const float rs = rsqrtf(var + 1e-5f);
  float4 gv = *(const float4*)(g + c);
  float4 bv = *(const float4*)(b + c);
  float4 o;
  o.x = gv.x * (v0 - mean) * rs + bv.x;
  o.y = gv.y * (v1 - mean) * rs + bv.y;
  o.z = gv.z * (v2 - mean) * rs + bv.z;
  o.w = gv.w * (v3 - mean) * rs + bv.w;
  *(float4*)(x + (long)row * kD + c) = o;
  u16 h[4] = {f2bf(o.x), f2bf(o.y), f2bf(o.z), f2bf(o.w)};
  *(uint2*)(xb + (long)row * kD + c) = *(const uint2*)h;
}

// ===========================================================================
// FALLBACK PATH (Round-3 proven)
// ===========================================================================
template <int BM, int BN, typename TA, typename TB, int BKN>
__global__ __launch_bounds__(256)
void gemm_kernel(const void* __restrict__ Av, const void* __restrict__ Bv,
                 const float* __restrict__ bias, float* __restrict__ Cv,
                 const int K, const int lda, const int ldb, const int ldc,
                 const int nH, const long sAb, const long sAh,
                 const long sBb, const long sBh, const long sCb, const long sCh,
                 const float scale, const int relu) {
  constexpr int LP = 40;
  __shared__ u16 As[BM][LP];
  __shared__ u16 Bs[BN][LP];
  const int tid = threadIdx.x;
  const int z = blockIdx.z;
  const int zb = z / nH, zh = z - zb * nH;
  const TA* A = (const TA*)Av + zb * sAb + zh * sAh + (long)blockIdx.y * BM * lda;
  const TB* Bp;
  if constexpr (BKN)
    Bp = (const TB*)Bv + zb * sBb + zh * sBh + (long)blockIdx.x * BN;
  else
    Bp = (const TB*)Bv + zb * sBb + zh * sBh + (long)blockIdx.x * BN * ldb;
  const long offC = zb * sCb + zh * sCh;
  const int lane = tid & 63;
  const int wm = (tid >> 7) & 1, wn = (tid >> 6) & 1;
  constexpr int FM = BM / 32, FN = BN / 32;
  v4f acc[FM][FN];
  const v4f zero = {0.f, 0.f, 0.f, 0.f};
#pragma unroll
  for (int i = 0; i < FM; ++i)
#pragma unroll
    for (int j = 0; j < FN; ++j) acc[i][j] = zero;
  const int l15 = lane & 15, lk = lane >> 4;

  for (int k0 = 0; k0 < K; k0 += 32) {
    __syncthreads();
    if constexpr (sizeof(TA) == 4) {
      const int r = tid >> 3, c = (tid & 7) * 4;
#pragma unroll
      for (int rr = 0; rr < BM; rr += 32) {
        float4 vv = *(const float4*)((const float*)A + (long)(rr + r) * lda + k0 + c);
        unsigned lo = (unsigned)f2bf(vv.x) | ((unsigned)f2bf(vv.y) << 16);
        unsigned hi = (unsigned)f2bf(vv.z) | ((unsigned)f2bf(vv.w) << 16);
        *(uint2*)&As[rr + r][c] = make_uint2(lo, hi);
      }
    } else {
      const int r = tid >> 2, c = (tid & 3) * 8;
#pragma unroll
      for (int rr = 0; rr < BM; rr += 64) {
        uint4 vv = *(const uint4*)((const u16*)A + (long)(rr + r) * lda + k0 + c);
        *(uint4*)&As[rr + r][c] = vv;
      }
    }
    if constexpr (BKN) {
      const int r = tid >> 3, c = (tid & 7) * 4;
#pragma unroll
      for (int nn = 0; nn < BN; nn += 32) {
        float4 vv = *(const float4*)((const float*)Bp + (long)(k0 + r) * ldb + nn + c);
        Bs[nn + c + 0][r] = f2bf(vv.x);
        Bs[nn + c + 1][r] = f2bf(vv.y);
        Bs[nn + c + 2][r] = f2bf(vv.z);
        Bs[nn + c + 3][r] = f2bf(vv.w);
      }
    } else if constexpr (sizeof(TB) == 4) {
      const int r = tid >> 3, c = (tid & 7) * 4;
#pragma unroll
      for (int rr = 0; rr < BN; rr += 32) {
        float4 vv = *(const float4*)((const float*)Bp + (long)(rr + r) * ldb + k0 + c);
        unsigned lo = (unsigned)f2bf(vv.x) | ((unsigned)f2bf(vv.y) << 16);
        unsigned hi = (unsigned)f2bf(vv.z) | ((unsigned)f2bf(vv.w) << 16);
        *(uint2*)&Bs[rr + r][c] = make_uint2(lo, hi);
      }
    } else {
      const int r = tid >> 2, c = (tid & 3) * 8;
#pragma unroll
      for (int rr = 0; rr < BN; rr += 64) {
        uint4 vv = *(const uint4*)((const u16*)Bp + (long)(rr + r) * ldb + k0 + c);
        *(uint4*)&Bs[rr + r][c] = vv;
      }
    }
    __syncthreads();
    v8bf af[FM], bfr[FN];
#pragma unroll
    for (int i = 0; i < FM; ++i)
      af[i] = *(const v8bf*)&As[wm * (BM / 2) + i * 16 + l15][lk * 8];
#pragma unroll
    for (int j = 0; j < FN; ++j)
      bfr[j] = *(const v8bf*)&Bs[wn * (BN / 2) + j * 16 + l15][lk * 8];
#pragma unroll
    for (int i = 0; i < FM; ++i)
#pragma unroll
      for (int j = 0; j < FN; ++j)
        acc[i][j] = __builtin_amdgcn_mfma_f32_16x16x32_bf16(af[i], bfr[j], acc[i][j], 0, 0, 0);
  }

  const long m0 = (long)blockIdx.y * BM + wm * (BM / 2);
  const int n0 = blockIdx.x * BN + wn * (BN / 2);
#pragma unroll
  for (int j = 0; j < FN; ++j) {
    const int col = n0 + j * 16 + l15;
    const float bv = bias ? bias[col] : 0.0f;
#pragma unroll
    for (int i = 0; i < FM; ++i) {
      const long row = m0 + i * 16 + lk * 4;
#pragma unroll
      for (int r = 0; r < 4; ++r) {
        float v = acc[i][j][r] * scale + bv;
        if (relu) v = fmaxf(v, 0.0f);
        Cv[offC + (row + r) * ldc + col] = v;
      }
    }
  }
}

__global__ void embed_kernel(const int* __restrict__ tgt, const float* __restrict__ emb,
                             float* __restrict__ x) {
  const int row = blockIdx.x;
  const int t = row & (kT - 1);
  const int tok = tgt[row];
  const int c = threadIdx.x * 4;
  float4 e = *(const float4*)(emb + (long)tok * kD + c);
  const float nl = -9.210340371976184f / (float)kD;
  const float a0 = (float)t * expf((float)c * nl);
  const float a1 = (float)t * expf((float)(c + 2) * nl);
  float4 o;
  o.x = e.x * 32.0f + sinf(a0);
  o.y = e.y * 32.0f + cosf(a0);
  o.z = e.z * 32.0f + sinf(a1);
  o.w = e.w * 32.0f + cosf(a1);
  *(float4*)(x + (long)row * kD + c) = o;
}

__global__ void transpose_v_kernel(const float* __restrict__ v, u16* __restrict__ vt) {
  __shared__ float tile[32][33];
  const int z = blockIdx.z;
  const int b = z >> 4, h = z & 15;
  const int t0 = blockIdx.x * 32, d0 = blockIdx.y * 32;
  const int tx = threadIdx.x, ty = threadIdx.y;
  const float* in = v + (long)b * kTD + (long)h * kDK;
#pragma unroll
  for (int i = 0; i < 4; ++i)
    tile[ty + 8 * i][tx] = in[(long)(t0 + ty + 8 * i) * kD + d0 + tx];
  __syncthreads();
  u16* o = vt + (long)z * kDK * kT;
#pragma unroll
  for (int i = 0; i < 4; ++i)
    o[(long)(d0 + ty + 8 * i) * kT + t0 + tx] = f2bf(tile[tx][ty + 8 * i]);
}

__global__ void softmax_kernel(float* __restrict__ w, const int causal) {
  const int rowg = blockIdx.x * 4 + (threadIdx.x >> 6);
  const int lane = threadIdx.x & 63;
  const int q = rowg & (kT - 1);
  float* p = w + (long)rowg * kT + lane * 8;
  float4 v0 = *(const float4*)p;
  float4 v1 = *(const float4*)(p + 4);
  float f[8] = {v0.x, v0.y, v0.z, v0.w, v1.x, v1.y, v1.z, v1.w};
  const int base = lane * 8;
  float mx = -3.0e38f;
#pragma unroll
  for (int j = 0; j < 8; ++j)
    if (!causal || base + j <= q) mx = fmaxf(mx, f[j]);
#pragma unroll
  for (int o = 32; o > 0; o >>= 1) mx = fmaxf(mx, __shfl_xor(mx, o));
  float s = 0.0f;
#pragma unroll
  for (int j = 0; j < 8; ++j) {
    float e = (!causal || base + j <= q) ? __expf(f[j] - mx) : 0.0f;
    f[j] = e; s += e;
  }
#pragma unroll
  for (int o = 32; o > 0; o >>= 1) s += __shfl_xor(s, o);
  const float inv = 1.0f / s;
  float4 o0 = {f[0] * inv, f[1] * inv, f[2] * inv, f[3] * inv};
  float4 o1 = {f[4] * inv, f[5] * inv, f[6] * inv, f[7] * inv};
  *(float4*)p = o0;
  *(float4*)(p + 4) = o1;
}

__global__ void add_ln_kernel(float* __restrict__ x, const float* __restrict__ res,
                              const float* __restrict__ g, const float* __restrict__ b) {
  const int row = blockIdx.x;
  const int c = threadIdx.x * 4;
  float4 xv = *(const float4*)(x + (long)row * kD + c);
  float4 rv = *(const float4*)(res + (long)row * kD + c);
  const float v0 = xv.x + rv.x, v1 = xv.y + rv.y, v2 = xv.z + rv.z, v3 = xv.w + rv.w;
  float s = v0 + v1 + v2 + v3;
  float ss = v0 * v0 + v1 * v1 + v2 * v2 + v3 * v3;
#pragma unroll
  for (int o = 32; o > 0; o >>= 1) { s += __shfl_xor(s, o); ss += __shfl_xor(ss, o); }
  __shared__ float red[4][2];
  const int wv = threadIdx.x >> 6;
  if ((threadIdx.x & 63) == 0) { red[wv][0] = s; red[wv][1] = ss; }
  __syncthreads();
  s  = red[0][0] + red[1][0] + red[2][0] + red[3][0];
  ss = red[0][1] + red[1][1] + red[2][1] + red[3][1];
  const float mean = s * (1.0f / kD);
  const float var = ss * (1.0f / kD) - mean * mean;
  const float rs = rsqrtf(var + 1e-5f);
  float4 gv = *(const float4*)(g + c);
  float4 bv = *(const float4*)(b + c);
  float4 o;
  o.x = gv.x * (v0 - mean) * rs + bv.x;
  o.y = gv.y * (v1 - mean) * rs + bv.y;
  o.z = gv.z * (v2 - mean) * rs + bv.z;
  o.w = gv.w * (v3 - mean) * rs + bv.w;
  *(float4*)(x + (long)row * kD + c) = o;
}

// ===========================================================================
extern "C" void kernel_launch(void* const* d_in, const int* in_sizes, int n_in,
                              void* d_out, int out_size, void* d_ws, size_t ws_size,
                              hipStream_t stream) {
  const int*   tgt  = (const int*)d_in[0];
  const float* enc  = (const float*)d_in[1];
  const float* emb  = (const float*)d_in[3];
  const float* Wout = (const float*)d_in[4];
  const float* bout = (const float*)d_in[5];
  const float* Wq_s = (const float*)d_in[6];
  const float* bq_s = (const float*)d_in[7];
  const float* Wk_s = (const float*)d_in[8];
  const float* bk_s = (const float*)d_in[9];
  const float* Wv_s = (const float*)d_in[10];
  const float* bv_s = (const float*)d_in[11];
  const float* Wo_s = (const float*)d_in[12];
  const float* bo_s = (const float*)d_in[13];
  const float* Wq_c = (const float*)d_in[14];
  const float* bq_c = (const float*)d_in[15];
  const float* Wk_c = (const float*)d_in[16];
  const float* bk_c = (const float*)d_in[17];
  const float* Wv_c = (const float*)d_in[18];
  const float* bv_c = (const float*)d_in[19];
  const float* Wo_c = (const float*)d_in[20];
  const float* bo_c = (const float*)d_in[21];
  const float* W1   = (const float*)d_in[22];
  const float* b1   = (const float*)d_in[23];
  const float* W2   = (const float*)d_in[24];
  const float* b2   = (const float*)d_in[25];
  const float* ln1g = (const float*)d_in[26];
  const float* ln1b = (const float*)d_in[27];
  const float* ln2g = (const float*)d_in[28];
  const float* ln2b = (const float*)d_in[29];
  const float* ln3g = (const float*)d_in[30];
  const float* ln3b = (const float*)d_in[31];

  float* out = (float*)d_out;
  const long DD = (long)kD * kD;
  const dim3 blk256(256), blkT(32, 8);

  if (ws_size >= (272ll << 20)) {
    // =================== FAST PATH ===================
    char* ws = (char*)d_ws;
    float* x     = (float*)ws;                    // 8 MiB
    u16* xb      = (u16*)(ws + (8l << 20));       // 4 MiB (contiguous with encb)
    u16* encb    = (u16*)(ws + (12l << 20));      // 4 MiB (A source, merged cross)
    u16* encb2   = (u16*)(ws + (16l << 20));      // 4 MiB (second copy for V slice)
    u16* Sqkv    = (u16*)(ws + (20l << 20));      // 12 MiB (2048x3072)
    u16* vt      = (u16*)(ws + (32l << 20));      // 4 MiB (B,H,dk,T)
    u16* S3b     = (u16*)(ws + (36l << 20));      // 4 MiB
    u16* Hb      = (u16*)(ws + (40l << 20));      // 16 MiB (2048x4096)
    float* Spart = (float*)(ws + (56l << 20));    // 16 MiB (2 f32 partials)
    u16* wbase   = (u16*)(ws + (72l << 20));      // 128 MiB
    u16* woutT   = (u16*)(ws + (200l << 20));     // 62.5 MiB
    float* bqkvS = (float*)(ws + (263l << 20));   // 48 KiB
    float* bqkvC = (float*)(ws + (263l << 20) + (64l << 10));  // 48 KiB
    const long WLAY = 16l * 1024 * 1024;          // u16 elems per layer block

    // ---- one-time prep ----
    for (int i = 0; i < kL; ++i) {
      u16* wqkvS = wbase + i * WLAY;
      u16* woS   = wqkvS + 3072 * 1024;
      u16* wqkvC = woS + 1024 * 1024;
      u16* woC   = wqkvC + 3072 * 1024;
      u16* w1t   = woC + 1024 * 1024;
      u16* w2t   = w1t + (long)4096 * 1024;
      TPtrs p{};
      p.in[0] = Wq_s + i * DD; p.out[0] = wqkvS;
      p.in[1] = Wk_s + i * DD; p.out[1] = wqkvS + 1024 * 1024;
      p.in[2] = Wv_s + i * DD; p.out[2] = wqkvS + 2048 * 1024;
      p.in[3] = Wo_s + i * DD; p.out[3] = woS;
      p.in[4] = Wq_c + i * DD; p.out[4] = wqkvC;
      p.in[5] = Wk_c + i * DD; p.out[5] = wqkvC + 1024 * 1024;
      p.in[6] = Wv_c + i * DD; p.out[6] = wqkvC + 2048 * 1024;
      p.in[7] = Wo_c + i * DD; p.out[7] = woC;
      transpose_wt_v2<<<dim3(32, 32, 8), blkT, 0, stream>>>(p, 1024, 1024);
      TPtrs p1{}; p1.in[0] = W1 + (long)i * kD * kF; p1.out[0] = w1t;
      transpose_wt_v2<<<dim3(128, 32, 1), blkT, 0, stream>>>(p1, 1024, 4096);
      TPtrs p2{}; p2.in[0] = W2 + (long)i * kF * kD; p2.out[0] = w2t;
      transpose_wt_v2<<<dim3(32, 128, 1), blkT, 0, stream>>>(p2, 4096, 1024);
    }
    TPtrs po{}; po.in[0] = Wout; po.out[0] = woutT;
    transpose_wt_v2<<<dim3(1000, 32, 1), blkT, 0, stream>>>(po, 1024, 32000);
    concat_bias<<<dim3(48), blk256, 0, stream>>>(bqkvS, bq_s, bk_s, bv_s, 3);
    concat_bias<<<dim3(48), blk256, 0, stream>>>(bqkvC, bq_c, bk_c, bv_c, 3);
    cvt_bf16_v3<<<dim3(2048), blk256, 0, stream>>>(enc, encb, encb2);
    embed_v2<<<dim3(kM), blk256, 0, stream>>>(tgt, emb, x, xb);

    for (int i = 0; i < kL; ++i) {
      u16* wqkvS = wbase + i * WLAY;
      u16* woS   = wqkvS + 3072 * 1024;
      u16* wqkvC = woS + 1024 * 1024;
      u16* woC   = wqkvC + 3072 * 1024;
      u16* w1t   = woC + 1024 * 1024;
      u16* w2t   = w1t + (long)4096 * 1024;
      float* wSelf  = out + kLOG + (long)i * kBHTT;
      float* wCross = out + kLOG + (long)kL * kBHTT + (long)i * kBHTT;

      // -------- self attention --------
      gemm_bf<128, 128, 1, 1><<<dim3(24, 16, 1), blk256, 0, stream>>>(
          xb, wqkvS, bqkvS + i * 3072, Sqkv, vt, 1024, 1024, 1024, 3072,
          1, 0, 0, 0, 0, 0, 0, 1.0f, 0, 0);
      attn_fused<1><<<dim3(4, 64), dim3(512), 0, stream>>>(Sqkv, Sqkv + 1024, vt, wSelf, S3b);
      gemm_bf<128, 128, 0, 0><<<dim3(8, 16, 2), blk256, 0, stream>>>(
          S3b, woS, bo_s + (long)i * kD, Spart, nullptr, 512, 1024, 1024, 1024,
          1, 512, 0, 512, 0, kPART, 0, 1.0f, 0, 0);
      add_ln_v3<<<dim3(kM), blk256, 0, stream>>>(x, xb, Spart, 2,
          ln1g + (long)i * kD, ln1b + (long)i * kD);

      // -------- cross attention (merged Q/K/V via z: xb|encb|encb2) --------
      gemm_bf<128, 128, 1, 1><<<dim3(8, 16, 3), blk256, 0, stream>>>(
          xb, wqkvC, bqkvC + i * 3072, Sqkv, vt, 1024, 1024, 1024, 3072,
          3, 0, (long)2048 * 1024, 0, (long)1024 * 1024, 0, 1024, 1.0f, 0, 1024);
      attn_fused<0><<<dim3(4, 64), dim3(512), 0, stream>>>(Sqkv, Sqkv + 1024, vt, wCross, S3b);
      gemm_bf<128, 128, 0, 0><<<dim3(8, 16, 2), blk256, 0, stream>>>(
          S3b, woC, bo_c + (long)i * kD, Spart, nullptr, 512, 1024, 1024, 1024,
          1, 512, 0, 512, 0, kPART, 0, 1.0f, 0, 0);
      add_ln_v3<<<dim3(kM), blk256, 0, stream>>>(x, xb, Spart, 2,
          ln2g + (long)i * kD, ln2b + (long)i * kD);

      // -------- FFN --------
      gemm_bf<128, 128, 1, 0><<<dim3(32, 16, 1), blk256, 0, stream>>>(
          xb, w1t, b1 + (long)i * kF, Hb, nullptr, 1024, 1024, 1024, 4096,
          1, 0, 0, 0, 0, 0, 0, 1.0f, 1, 0);
      gemm_bf<128, 128, 0, 0><<<dim3(8, 16, 2), blk256, 0, stream>>>(
          Hb, w2t, b2 + (long)i * kD, Spart, nullptr, 2048, 4096, 4096, 1024,
          1, 2048, 0, 2048, 0, kPART, 0, 1.0f, 0, 0);
      add_ln_v3<<<dim3(kM), blk256, 0, stream>>>(x, xb, Spart, 2,
          ln3g + (long)i * kD, ln3b + (long)i * kD);
    }

    gemm_bf<128, 128, 0, 0><<<dim3(250, 16, 1), blk256, 0, stream>>>(
        xb, woutT, bout, out, nullptr, 1024, 1024, 1024, 32000,
        1, 0, 0, 0, 0, 0, 0, 1.0f, 0, 0);
    return;
  }

  // =================== FALLBACK (Round-3 verified) ===================
  float* x = (float*)d_ws;
  char* sc = (char*)d_out;
  float* S0 = (float*)sc;
  float* S1 = (float*)(sc + (8l  << 20));
  float* S2 = (float*)(sc + (16l << 20));
  float* S3 = (float*)(sc + (24l << 20));
  float* S4 = (float*)(sc + (32l << 20));
  u16*   vt = (u16*)  (sc + (40l << 20));

  embed_kernel<<<dim3(kM), blk256, 0, stream>>>(tgt, emb, x);
  auto wgemm = [&](const float* A, const float* W, const float* bias, float* C) {
    gemm_kernel<128, 128, float, float, 1><<<dim3(kD / 128, kM / 128, 1), blk256, 0, stream>>>(
        A, W, bias, C, kD, kD, kD, kD, 1, 0, 0, 0, 0, 0, 0, 1.0f, 0);
  };
  for (int i = 0; i < kL; ++i) {
    const long wOff = (long)i * DD;
    float* wSelf  = out + kLOG + (long)i * kBHTT;
    float* wCross = out + kLOG + (long)kL * kBHTT + (long)i * kBHTT;
    wgemm(x, Wq_s + wOff, bq_s + (long)i * kD, S0);
    wgemm(x, Wk_s + wOff, bk_s + (long)i * kD, S1);
    wgemm(x, Wv_s + wOff, bv_s + (long)i * kD, S2);
    transpose_v_kernel<<<dim3(16, 2, 64), blkT, 0, stream>>>(S2, vt);
    gemm_kernel<128, 128, float, float, 0><<<dim3(4, 4, 64), blk256, 0, stream>>>(
        S0, S1, nullptr, wSelf, kDK, kD, kD, kT,
        kH, kTD, (long)kDK, kTD, (long)kDK, kHTT, kTT, 0.125f, 0);
    softmax_kernel<<<dim3(kB * kH * kT / 4), blk256, 0, stream>>>(wSelf, 1);
    gemm_kernel<128, 64, float, u16, 0><<<dim3(1, 4, 64), blk256, 0, stream>>>(
        wSelf, vt, nullptr, S3, kT, kT, kT, kD,
        kH, kHTT, kTT, (long)kH * kDK * kT, (long)kDK * kT, kTD, (long)kDK, 1.0f, 0);
    wgemm(S3, Wo_s + wOff, bo_s + (long)i * kD, S0);
    add_ln_kernel<<<dim3(kM), blk256, 0, stream>>>(x, S0, ln1g + (long)i * kD, ln1b + (long)i * kD);
    wgemm(x,   Wq_c + wOff, bq_c + (long)i * kD, S0);
    wgemm(enc, Wk_c + wOff, bk_c + (long)i * kD, S1);
    wgemm(enc, Wv_c + wOff, bv_c + (long)i * kD, S2);
    transpose_v_kernel<<<dim3(16, 2, 64), blkT, 0, stream>>>(S2, vt);
    gemm_kernel<128, 128, float, float, 0><<<dim3(4, 4, 64), blk256, 0, stream>>>(
        S0, S1, nullptr, wCross, kDK, kD, kD, kT,
        kH, kTD, (long)kDK, kTD, (long)kDK, kHTT, kTT, 0.125f, 0);
    softmax_kernel<<<dim3(kB * kH * kT / 4), blk256, 0, stream>>>(wCross, 0);
    gemm_kernel<128, 64, float, u16, 0><<<dim3(1, 4, 64), blk256, 0, stream>>>(
        wCross, vt, nullptr, S3, kT, kT, kT, kD,
        kH, kHTT, kTT, (long)kH * kDK * kT, (long)kDK * kT, kTD, (long)kDK, 1.0f, 0);
    wgemm(S3, Wo_c + wOff, bo_c + (long)i * kD, S0);
    add_ln_kernel<<<dim3(kM), blk256, 0, stream>>>(x, S0, ln2g + (long)i * kD, ln2b + (long)i * kD);
    gemm_kernel<128, 128, float, float, 1><<<dim3(kF / 128, kM / 128, 1), blk256, 0, stream>>>(
        x, W1 + (long)i * kD * kF, b1 + (long)i * kF, S0, kD, kD, kF, kF,
        1, 0, 0, 0, 0, 0, 0, 1.0f, 1);
    gemm_kernel<128, 128, float, float, 1><<<dim3(kD / 128, kM / 128, 1), blk256, 0, stream>>>(
        S0, W2 + (long)i * kF * kD, b2 + (long)i * kD, S4, kF, kF, kD, kD,
        1, 0, 0, 0, 0, 0, 0, 1.0f, 0);
    add_ln_kernel<<<dim3(kM), blk256, 0, stream>>>(x, S4, ln3g + (long)i * kD, ln3b + (long)i * kD);
  }
  gemm_kernel<128, 128, float, float, 1><<<dim3(kV / 128, kM / 128, 1), blk256, 0, stream>>>(
      x, Wout, bout, out, kD, kD, kV, kV,
      1, 0, 0, 0, 0, 0, 0, 1.0f, 0);
}

// Round 9
// 1533.836 us; speedup vs baseline: 2.2698x; 1.0334x over previous
//
#include <hip/hip_runtime.h>

// TransformerDecoder on MI355X. Round 8: double-buffered GEMM K-loop
// (2-phase pipeline: stage next tile before computing current, ONE barrier
// per K-step). Rationale: projection GEMMs run at 1-2 blocks/CU, so global
// latency must be hidden by ILP, not TLP. Everything else = Round-8 passing.

typedef unsigned short u16;
typedef __bf16 v8bf __attribute__((ext_vector_type(8)));
typedef float v4f __attribute__((ext_vector_type(4)));

namespace {
constexpr int kB = 4, kT = 512, kD = 1024, kH = 16, kDK = 64, kF = 4096, kV = 32000, kL = 4;
constexpr int kM = kB * kT;
constexpr long kTD = (long)kT * kD;
constexpr long kTT = (long)kT * kT;
constexpr long kHTT = (long)kH * kTT;
constexpr long kBHTT = (long)kB * kHTT;
constexpr long kLOG = (long)kM * kV;
constexpr long kPART = (long)kM * kD;
}

__device__ __forceinline__ u16 f2bf(float f) {
  union { float f; unsigned u; } v; v.f = f;
  unsigned r = v.u + 0x7FFFu + ((v.u >> 16) & 1u);
  return (u16)(r >> 16);
}
__device__ __forceinline__ float bf2f(u16 h) {
  union { unsigned u; float f; } v; v.u = ((unsigned)h) << 16;
  return v.f;
}

typedef __attribute__((address_space(3))) void lds_void;
typedef const __attribute__((address_space(1))) void glob_void;
__device__ __forceinline__ void gl2lds16(const void* g, void* l) {
  __builtin_amdgcn_global_load_lds((glob_void*)g, (lds_void*)l, 16, 0, 0);
}

// ---------------------------------------------------------------------------
// bf16 GEMM, BK=64, swizzled LDS, DOUBLE-BUFFERED K-loop (one barrier/step).
// C[m][n] = scale*sum A[m][k]*B[n][k] + bias[zh*bstride+n] (zb==0 only).
// VTR: cols>=2048 of a (.,3072) C also written transposed into vt (B,H,dk,T).
// ---------------------------------------------------------------------------
template <int BM, int BN, int OUTBF, int VTR>
__global__ __launch_bounds__(256)
void gemm_bf(const u16* __restrict__ A0, const u16* __restrict__ B0,
             const float* __restrict__ bias, void* __restrict__ Cv,
             u16* __restrict__ vtw,
             const int K, const int lda, const int ldb, const int ldc,
             const int nH, const long sAb, const long sAh,
             const long sBb, const long sBh, const long sCb, const long sCh,
             const float scale, const int relu, const int bstride) {
  static_assert(BM % 32 == 0 && BN % 32 == 0, "tiles");
  __shared__ u16 As[2][BM][64];
  __shared__ u16 Bs[2][BN][64];
  const int tid = threadIdx.x;
  const int lane = tid & 63;
  const int w = tid >> 6;
  const int z = blockIdx.z;
  const int zb = z / nH, zh = z - zb * nH;
  const u16* A = A0 + zb * sAb + zh * sAh + (long)blockIdx.y * BM * lda;
  const u16* B = B0 + zb * sBb + zh * sBh + (long)blockIdx.x * BN * ldb;
  const long offC = zb * sCb + zh * sCh;
  const int wm = w >> 1, wn = w & 1;
  constexpr int FM = BM / 32, FN = BN / 32;
  v4f acc[FM][FN];
  const v4f zero = {0.f, 0.f, 0.f, 0.f};
#pragma unroll
  for (int i = 0; i < FM; ++i)
#pragma unroll
    for (int j = 0; j < FN; ++j) acc[i][j] = zero;
  const int l15 = lane & 15, lk = lane >> 4;
  const int lr8 = lane >> 3;                       // row within 8-row stripe
  const int swz = ((lane & 7) ^ lr8) * 8;          // pre-swizzled source col
  const int l7 = l15 & 7;

  // prologue: stage tile 0 into buffer 0
#pragma unroll
  for (int s = 0; s < BM / 32; ++s)
    gl2lds16(A + (long)(w * (BM / 4) + s * 8 + lr8) * lda + swz,
             &As[0][w * (BM / 4) + s * 8][0]);
#pragma unroll
  for (int s = 0; s < BN / 32; ++s)
    gl2lds16(B + (long)(w * (BN / 4) + s * 8 + lr8) * ldb + swz,
             &Bs[0][w * (BN / 4) + s * 8][0]);

  const int NT = K >> 6;
  for (int kt = 0; kt < NT; ++kt) {
    const int cur = kt & 1;
    __syncthreads();   // drains prev stage (vmcnt) + prev reads (lgkmcnt)
    if (kt + 1 < NT) { // issue next tile's stage into the other buffer
      const int k0 = (kt + 1) << 6;
#pragma unroll
      for (int s = 0; s < BM / 32; ++s)
        gl2lds16(A + (long)(w * (BM / 4) + s * 8 + lr8) * lda + k0 + swz,
                 &As[cur ^ 1][w * (BM / 4) + s * 8][0]);
#pragma unroll
      for (int s = 0; s < BN / 32; ++s)
        gl2lds16(B + (long)(w * (BN / 4) + s * 8 + lr8) * ldb + k0 + swz,
                 &Bs[cur ^ 1][w * (BN / 4) + s * 8][0]);
    }
#pragma unroll
    for (int t = 0; t < 2; ++t) {
      const int c0 = t * 4;
      v8bf af[FM], bfr[FN];
#pragma unroll
      for (int i = 0; i < FM; ++i)
        af[i] = *(const v8bf*)&As[cur][wm * (BM / 2) + i * 16 + l15][((c0 + lk) ^ l7) * 8];
#pragma unroll
      for (int j = 0; j < FN; ++j)
        bfr[j] = *(const v8bf*)&Bs[cur][wn * (BN / 2) + j * 16 + l15][((c0 + lk) ^ l7) * 8];
#pragma unroll
      for (int i = 0; i < FM; ++i)
#pragma unroll
        for (int j = 0; j < FN; ++j)
          acc[i][j] = __builtin_amdgcn_mfma_f32_16x16x32_bf16(af[i], bfr[j], acc[i][j], 0, 0, 0);
    }
  }

  const long m0 = (long)blockIdx.y * BM + wm * (BM / 2);
  const int n0 = blockIdx.x * BN + wn * (BN / 2);
#pragma unroll
  for (int j = 0; j < FN; ++j) {
    const int col = n0 + j * 16 + l15;
    const float bv = (bias && zb == 0) ? bias[zh * bstride + col] : 0.0f;
#pragma unroll
    for (int i = 0; i < FM; ++i) {
      const long row = m0 + i * 16 + lk * 4;
#pragma unroll
      for (int r = 0; r < 4; ++r) {
        float v = acc[i][j][r] * scale + bv;
        if (relu) v = fmaxf(v, 0.0f);
        const long idx = offC + (row + r) * ldc + col;
        if (OUTBF) ((u16*)Cv)[idx] = f2bf(v);
        else       ((float*)Cv)[idx] = v;
        if (VTR) {
          const int colS = (int)(offC % 3072) + col;   // column within (.,3072)
          if (colS >= 2048) {
            const int hh = (colS - 2048) >> 6, dd = (colS - 2048) & 63;
            const int rowg = (int)(row + r);
            vtw[((long)((rowg >> 9) * 16 + hh)) * 32768 + dd * 512 + (rowg & 511)] = f2bf(v);
          }
        }
      }
    }
  }
}

// ---------------------------------------------------------------------------
// Fused attention: per block 128 q-rows x one (b,h): QK^T (swizzled LDS),
// softmax (writes w f32 to d_out), then PV via padded-LDS P/V^T chunks,
// writes O bf16 into S3b (2048,1024). 512 threads = 8 waves (2 wm x 4 wn).
// ---------------------------------------------------------------------------
template <int CAUSAL>
__global__ __launch_bounds__(512)
void attn_fused(const u16* __restrict__ Qb, const u16* __restrict__ Kb,
                const u16* __restrict__ vtp, float* __restrict__ wout,
                u16* __restrict__ oout) {
  __shared__ __align__(16) char lds[81920];
  u16 (*Qs)[64] = (u16 (*)[64])lds;                 // [128][64]
  u16 (*Ks)[64] = (u16 (*)[64])(lds + 16384);       // [512][64]
  u16 (*Pl)[136] = (u16 (*)[136])lds;               // [128][136] 34816 B
  u16 (*Vt)[136] = (u16 (*)[136])(lds + 34816);     // [64][136]  17408 B
  __shared__ float redM[128][4];
  __shared__ float redS[128][4];
  const int tid = threadIdx.x, lane = tid & 63, w = tid >> 6;
  const int wm = w >> 2, wn = w & 3;
  const int l15 = lane & 15, lk = lane >> 4;
  const int lr8 = lane >> 3;
  const int swz = ((lane & 7) ^ lr8) * 8;
  const int l7 = l15 & 7;
  const int bx = blockIdx.x;
  const int z = blockIdx.y, zb = z >> 4, zh = z & 15;
  const u16* Q = Qb + (long)zb * 512 * 3072 + zh * 64 + (long)bx * 128 * 3072;
  const u16* Kp = Kb + (long)zb * 512 * 3072 + zh * 64;
  const u16* vtz = vtp + (long)((zb << 4) + zh) * 32768;
  const long obase = (long)zb * kHTT + (long)zh * kTT;

#pragma unroll
  for (int s = 0; s < 2; ++s)
    gl2lds16(Q + (long)(w * 16 + s * 8 + lr8) * 3072 + swz, &Qs[w * 16 + s * 8][0]);
#pragma unroll
  for (int s = 0; s < 8; ++s) {
    const int r0 = w * 64 + s * 8;
    if (!CAUSAL || r0 <= bx * 128 + 127)
      gl2lds16(Kp + (long)(r0 + lr8) * 3072 + swz, &Ks[r0][0]);
  }
  __syncthreads();

  v4f acc[4][8];
  const v4f zero = {0.f, 0.f, 0.f, 0.f};
#pragma unroll
  for (int i = 0; i < 4; ++i)
#pragma unroll
    for (int j = 0; j < 8; ++j) acc[i][j] = zero;

#pragma unroll
  for (int t = 0; t < 2; ++t) {
    const int c0 = t * 4;
    v8bf aq[4], bk[8];
#pragma unroll
    for (int i = 0; i < 4; ++i)
      aq[i] = *(const v8bf*)&Qs[wm * 64 + i * 16 + l15][((c0 + lk) ^ l7) * 8];
#pragma unroll
    for (int j = 0; j < 8; ++j)
      bk[j] = *(const v8bf*)&Ks[wn * 128 + j * 16 + l15][((c0 + lk) ^ l7) * 8];
#pragma unroll
    for (int i = 0; i < 4; ++i)
#pragma unroll
      for (int j = 0; j < 8; ++j)
        if (!(CAUSAL && wn * 128 + j * 16 > bx * 128 + wm * 64 + i * 16 + 15))
          acc[i][j] = __builtin_amdgcn_mfma_f32_16x16x32_bf16(aq[i], bk[j], acc[i][j], 0, 0, 0);
  }

  // row max
  float gmax[4][4];
#pragma unroll
  for (int i = 0; i < 4; ++i)
#pragma unroll
    for (int r = 0; r < 4; ++r) {
      const int q = bx * 128 + wm * 64 + i * 16 + lk * 4 + r;
      float m = -3.0e38f;
#pragma unroll
      for (int j = 0; j < 8; ++j) {
        const int col = wn * 128 + j * 16 + l15;
        if (!CAUSAL || col <= q) m = fmaxf(m, acc[i][j][r] * 0.125f);
      }
#pragma unroll
      for (int off = 1; off < 16; off <<= 1) m = fmaxf(m, __shfl_xor(m, off));
      if (l15 == 0) redM[wm * 64 + i * 16 + lk * 4 + r][wn] = m;
    }
  __syncthreads();
#pragma unroll
  for (int i = 0; i < 4; ++i)
#pragma unroll
    for (int r = 0; r < 4; ++r) {
      v4f mv = *(const v4f*)&redM[wm * 64 + i * 16 + lk * 4 + r][0];
      gmax[i][r] = fmaxf(fmaxf(mv[0], mv[1]), fmaxf(mv[2], mv[3]));
    }
  // exp + row sum
#pragma unroll
  for (int i = 0; i < 4; ++i)
#pragma unroll
    for (int r = 0; r < 4; ++r) {
      const int q = bx * 128 + wm * 64 + i * 16 + lk * 4 + r;
      float s = 0.0f;
#pragma unroll
      for (int j = 0; j < 8; ++j) {
        const int col = wn * 128 + j * 16 + l15;
        float e = (!CAUSAL || col <= q) ? __expf(acc[i][j][r] * 0.125f - gmax[i][r]) : 0.0f;
        acc[i][j][r] = e;
        s += e;
      }
#pragma unroll
      for (int off = 1; off < 16; off <<= 1) s += __shfl_xor(s, off);
      if (l15 == 0) redS[wm * 64 + i * 16 + lk * 4 + r][wn] = s;
    }
  __syncthreads();
  // normalize, write w (f32), keep normalized P in acc
#pragma unroll
  for (int i = 0; i < 4; ++i)
#pragma unroll
    for (int r = 0; r < 4; ++r) {
      v4f sv = *(const v4f*)&redS[wm * 64 + i * 16 + lk * 4 + r][0];
      const float inv = 1.0f / (sv[0] + sv[1] + sv[2] + sv[3]);
      const int q = bx * 128 + wm * 64 + i * 16 + lk * 4 + r;
      const long rowoff = obase + (long)q * 512;
#pragma unroll
      for (int j = 0; j < 8; ++j) {
        const int col = wn * 128 + j * 16 + l15;
        const float v = acc[i][j][r] * inv;
        acc[i][j][r] = v;
        wout[rowoff + col] = v;
      }
    }

  // ---- PV: O[128 q][64 d] = P @ V, chunked over k (128 per chunk) ----
  v4f acco[4];
#pragma unroll
  for (int i = 0; i < 4; ++i) acco[i] = zero;
  const int kcMax = CAUSAL ? bx : 3;
  for (int kc = 0; kc <= kcMax; ++kc) {
    __syncthreads();
    if (wn == kc) {       // this wave-group owns P cols [kc*128, kc*128+128)
#pragma unroll
      for (int i = 0; i < 4; ++i)
#pragma unroll
        for (int j = 0; j < 8; ++j) {
          const int colk = j * 16 + l15;
#pragma unroll
          for (int r = 0; r < 4; ++r)
            Pl[wm * 64 + i * 16 + lk * 4 + r][colk] = f2bf(acc[i][j][r]);
        }
    }
    // stage V^T chunk [64 d][128 k] into padded Vt
#pragma unroll
    for (int s = 0; s < 2; ++s) {
      const int c = tid * 2 + s;            // 0..1023 chunks of 16B
      const int d = c >> 4, off = (c & 15) * 8;
      uint4 vv = *(const uint4*)(vtz + (long)d * 512 + kc * 128 + off);
      *(uint4*)&Vt[d][off] = vv;
    }
    __syncthreads();
#pragma unroll
    for (int t = 0; t < 4; ++t) {
      v8bf bv = *(const v8bf*)&Vt[wn * 16 + l15][t * 32 + lk * 8];
#pragma unroll
      for (int i = 0; i < 4; ++i) {
        v8bf ap = *(const v8bf*)&Pl[wm * 64 + i * 16 + l15][t * 32 + lk * 8];
        acco[i] = __builtin_amdgcn_mfma_f32_16x16x32_bf16(ap, bv, acco[i], 0, 0, 0);
      }
    }
  }
  // write O bf16 into S3b (2048,1024) at column zh*64
#pragma unroll
  for (int i = 0; i < 4; ++i)
#pragma unroll
    for (int r = 0; r < 4; ++r) {
      const int row = bx * 128 + wm * 64 + i * 16 + lk * 4 + r;
      oout[(long)(zb * 512 + row) * 1024 + zh * 64 + wn * 16 + l15] = f2bf(acco[i][r]);
    }
}

// Weight transpose-convert: out(N,K) bf16 = in(K,N)^T f32; batched ptr pairs.
struct TPtrs { const float* in[8]; u16* out[8]; };

__global__ void transpose_wt_v2(TPtrs ps, int K, int N) {
  __shared__ float tile[32][33];
  const float* in = ps.in[blockIdx.z];
  u16* o = ps.out[blockIdx.z];
  const int n0 = blockIdx.x * 32, k0 = blockIdx.y * 32;
  const int tx = threadIdx.x, ty = threadIdx.y;
#pragma unroll
  for (int i = 0; i < 4; ++i)
    tile[ty + 8 * i][tx] = in[(long)(k0 + ty + 8 * i) * N + n0 + tx];
  __syncthreads();
#pragma unroll
  for (int i = 0; i < 4; ++i)
    o[(long)(n0 + ty + 8 * i) * K + k0 + tx] = f2bf(tile[tx][ty + 8 * i]);
}

__global__ void concat_bias(float* __restrict__ dst, const float* __restrict__ s0,
                            const float* __restrict__ s1, const float* __restrict__ s2,
                            const int nsrc) {
  const int idx = blockIdx.x * 256 + threadIdx.x;
  const int per = nsrc << 10;
  const int l = idx / per, rem = idx - l * per, s = rem >> 10, j = rem & 1023;
  const float* src = (s == 0) ? s0 : (s == 1 ? s1 : s2);
  dst[idx] = src[l * 1024 + j];
}

__global__ void cvt_bf16_v3(const float* __restrict__ in, u16* __restrict__ o1,
                            u16* __restrict__ o2) {
  const long i = ((long)blockIdx.x * 256 + threadIdx.x) * 4;
  float4 v = *(const float4*)(in + i);
  u16 h[4] = {f2bf(v.x), f2bf(v.y), f2bf(v.z), f2bf(v.w)};
  *(uint2*)(o1 + i) = *(const uint2*)h;
  *(uint2*)(o2 + i) = *(const uint2*)h;
}

__global__ void embed_v2(const int* __restrict__ tgt, const float* __restrict__ emb,
                         float* __restrict__ x, u16* __restrict__ xb) {
  const int row = blockIdx.x;
  const int t = row & (kT - 1);
  const int tok = tgt[row];
  const int c = threadIdx.x * 4;
  float4 e = *(const float4*)(emb + (long)tok * kD + c);
  const float nl = -9.210340371976184f / (float)kD;
  const float a0 = (float)t * expf((float)c * nl);
  const float a1 = (float)t * expf((float)(c + 2) * nl);
  float4 o;
  o.x = e.x * 32.0f + sinf(a0);
  o.y = e.y * 32.0f + cosf(a0);
  o.z = e.z * 32.0f + sinf(a1);
  o.w = e.w * 32.0f + cosf(a1);
  *(float4*)(x + (long)row * kD + c) = o;
  u16 h[4] = {f2bf(o.x), f2bf(o.y), f2bf(o.z), f2bf(o.w)};
  *(uint2*)(xb + (long)row * kD + c) = *(const uint2*)h;
}

// x = LN(x + sum_{p<nres} res[p]); writes x f32 and xb bf16
__global__ void add_ln_v3(float* __restrict__ x, u16* __restrict__ xb,
                          const float* __restrict__ res, const int nres,
                          const float* __restrict__ g, const float* __restrict__ b) {
  const int row = blockIdx.x;
  const int c = threadIdx.x * 4;
  float4 xv = *(const float4*)(x + (long)row * kD + c);
  float v0 = xv.x, v1 = xv.y, v2 = xv.z, v3 = xv.w;
  for (int p = 0; p < nres; ++p) {
    float4 rv = *(const float4*)(res + p * kPART + (long)row * kD + c);
    v0 += rv.x; v1 += rv.y; v2 += rv.z; v3 += rv.w;
  }
  float s = v0 + v1 + v2 + v3;
  float ss = v0 * v0 + v1 * v1 + v2 * v2 + v3 * v3;
#pragma unroll
  for (int o = 32; o > 0; o >>= 1) { s += __shfl_xor(s, o); ss += __shfl_xor(ss, o); }
  __shared__ float red[4][2];
  const int wv = threadIdx.x >> 6;
  if ((threadIdx.x & 63) == 0) { red[wv][0] = s; red[wv][1] = ss; }
  __syncthreads();
  s  = red[0][0] + red[1][0] + red[2][0] + red[3][0];
  ss = red[0][1] + red[1][1] + red[2][1] + red[3][1];
  const float mean = s * (1.0f / kD);
  const float var = ss * (1.0f / kD) - mean * mean;
  const float rs = rsqrtf(var + 1e-5f);
  float4 gv = *(const float4*)(g + c);
  float4 bv = *(const float4*)(b + c);
  float4 o;
  o.x = gv.x * (v0 - mean) * rs + bv.x;
  o.y = gv.y * (v1 - mean) * rs + bv.y;
  o.z = gv.z * (v2 - mean) * rs + bv.z;
  o.w = gv.w * (v3 - mean) * rs + bv.w;
  *(float4*)(x + (long)row * kD + c) = o;
  u16 h[4] = {f2bf(o.x), f2bf(o.y), f2bf(o.z), f2bf(o.w)};
  *(uint2*)(xb + (long)row * kD + c) = *(const uint2*)h;
}

// ===========================================================================
// FALLBACK PATH (Round-3 proven)
// ===========================================================================
template <int BM, int BN, typename TA, typename TB, int BKN>
__global__ __launch_bounds__(256)
void gemm_kernel(const void* __restrict__ Av, const void* __restrict__ Bv,
                 const float* __restrict__ bias, float* __restrict__ Cv,
                 const int K, const int lda, const int ldb, const int ldc,
                 const int nH, const long sAb, const long sAh,
                 const long sBb, const long sBh, const long sCb, const long sCh,
                 const float scale, const int relu) {
  constexpr int LP = 40;
  __shared__ u16 As[BM][LP];
  __shared__ u16 Bs[BN][LP];
  const int tid = threadIdx.x;
  const int z = blockIdx.z;
  const int zb = z / nH, zh = z - zb * nH;
  const TA* A = (const TA*)Av + zb * sAb + zh * sAh + (long)blockIdx.y * BM * lda;
  const TB* Bp;
  if constexpr (BKN)
    Bp = (const TB*)Bv + zb * sBb + zh * sBh + (long)blockIdx.x * BN;
  else
    Bp = (const TB*)Bv + zb * sBb + zh * sBh + (long)blockIdx.x * BN * ldb;
  const long offC = zb * sCb + zh * sCh;
  const int lane = tid & 63;
  const int wm = (tid >> 7) & 1, wn = (tid >> 6) & 1;
  constexpr int FM = BM / 32, FN = BN / 32;
  v4f acc[FM][FN];
  const v4f zero = {0.f, 0.f, 0.f, 0.f};
#pragma unroll
  for (int i = 0; i < FM; ++i)
#pragma unroll
    for (int j = 0; j < FN; ++j) acc[i][j] = zero;
  const int l15 = lane & 15, lk = lane >> 4;

  for (int k0 = 0; k0 < K; k0 += 32) {
    __syncthreads();
    if constexpr (sizeof(TA) == 4) {
      const int r = tid >> 3, c = (tid & 7) * 4;
#pragma unroll
      for (int rr = 0; rr < BM; rr += 32) {
        float4 vv = *(const float4*)((const float*)A + (long)(rr + r) * lda + k0 + c);
        unsigned lo = (unsigned)f2bf(vv.x) | ((unsigned)f2bf(vv.y) << 16);
        unsigned hi = (unsigned)f2bf(vv.z) | ((unsigned)f2bf(vv.w) << 16);
        *(uint2*)&As[rr + r][c] = make_uint2(lo, hi);
      }
    } else {
      const int r = tid >> 2, c = (tid & 3) * 8;
#pragma unroll
      for (int rr = 0; rr < BM; rr += 64) {
        uint4 vv = *(const uint4*)((const u16*)A + (long)(rr + r) * lda + k0 + c);
        *(uint4*)&As[rr + r][c] = vv;
      }
    }
    if constexpr (BKN) {
      const int r = tid >> 3, c = (tid & 7) * 4;
#pragma unroll
      for (int nn = 0; nn < BN; nn += 32) {
        float4 vv = *(const float4*)((const float*)Bp + (long)(k0 + r) * ldb + nn + c);
        Bs[nn + c + 0][r] = f2bf(vv.x);
        Bs[nn + c + 1][r] = f2bf(vv.y);
        Bs[nn + c + 2][r] = f2bf(vv.z);
        Bs[nn + c + 3][r] = f2bf(vv.w);
      }
    } else if constexpr (sizeof(TB) == 4) {
      const int r = tid >> 3, c = (tid & 7) * 4;
#pragma unroll
      for (int rr = 0; rr < BN; rr += 32) {
        float4 vv = *(const float4*)((const float*)Bp + (long)(rr + r) * ldb + k0 + c);
        unsigned lo = (unsigned)f2bf(vv.x) | ((unsigned)f2bf(vv.y) << 16);
        unsigned hi = (unsigned)f2bf(vv.z) | ((unsigned)f2bf(vv.w) << 16);
        *(uint2*)&Bs[rr + r][c] = make_uint2(lo, hi);
      }
    } else {
      const int r = tid >> 2, c = (tid & 3) * 8;
#pragma unroll
      for (int rr = 0; rr < BN; rr += 64) {
        uint4 vv = *(const uint4*)((const u16*)Bp + (long)(rr + r) * ldb + k0 + c);
        *(uint4*)&Bs[rr + r][c] = vv;
      }
    }
    __syncthreads();
    v8bf af[FM], bfr[FN];
#pragma unroll
    for (int i = 0; i < FM; ++i)
      af[i] = *(const v8bf*)&As[wm * (BM / 2) + i * 16 + l15][lk * 8];
#pragma unroll
    for (int j = 0; j < FN; ++j)
      bfr[j] = *(const v8bf*)&Bs[wn * (BN / 2) + j * 16 + l15][lk * 8];
#pragma unroll
    for (int i = 0; i < FM; ++i)
#pragma unroll
      for (int j = 0; j < FN; ++j)
        acc[i][j] = __builtin_amdgcn_mfma_f32_16x16x32_bf16(af[i], bfr[j], acc[i][j], 0, 0, 0);
  }

  const long m0 = (long)blockIdx.y * BM + wm * (BM / 2);
  const int n0 = blockIdx.x * BN + wn * (BN / 2);
#pragma unroll
  for (int j = 0; j < FN; ++j) {
    const int col = n0 + j * 16 + l15;
    const float bv = bias ? bias[col] : 0.0f;
#pragma unroll
    for (int i = 0; i < FM; ++i) {
      const long row = m0 + i * 16 + lk * 4;
#pragma unroll
      for (int r = 0; r < 4; ++r) {
        float v = acc[i][j][r] * scale + bv;
        if (relu) v = fmaxf(v, 0.0f);
        Cv[offC + (row + r) * ldc + col] = v;
      }
    }
  }
}

__global__ void embed_kernel(const int* __restrict__ tgt, const float* __restrict__ emb,
                             float* __restrict__ x) {
  const int row = blockIdx.x;
  const int t = row & (kT - 1);
  const int tok = tgt[row];
  const int c = threadIdx.x * 4;
  float4 e = *(const float4*)(emb + (long)tok * kD + c);
  const float nl = -9.210340371976184f / (float)kD;
  const float a0 = (float)t * expf((float)c * nl);
  const float a1 = (float)t * expf((float)(c + 2) * nl);
  float4 o;
  o.x = e.x * 32.0f + sinf(a0);
  o.y = e.y * 32.0f + cosf(a0);
  o.z = e.z * 32.0f + sinf(a1);
  o.w = e.w * 32.0f + cosf(a1);
  *(float4*)(x + (long)row * kD + c) = o;
}

__global__ void transpose_v_kernel(const float* __restrict__ v, u16* __restrict__ vt) {
  __shared__ float tile[32][33];
  const int z = blockIdx.z;
  const int b = z >> 4, h = z & 15;
  const int t0 = blockIdx.x * 32, d0 = blockIdx.y * 32;
  const int tx = threadIdx.x, ty = threadIdx.y;
  const float* in = v + (long)b * kTD + (long)h * kDK;
#pragma unroll
  for (int i = 0; i < 4; ++i)
    tile[ty + 8 * i][tx] = in[(long)(t0 + ty + 8 * i) * kD + d0 + tx];
  __syncthreads();
  u16* o = vt + (long)z * kDK * kT;
#pragma unroll
  for (int i = 0; i < 4; ++i)
    o[(long)(d0 + ty + 8 * i) * kT + t0 + tx] = f2bf(tile[tx][ty + 8 * i]);
}

__global__ void softmax_kernel(float* __restrict__ w, const int causal) {
  const int rowg = blockIdx.x * 4 + (threadIdx.x >> 6);
  const int lane = threadIdx.x & 63;
  const int q = rowg & (kT - 1);
  float* p = w + (long)rowg * kT + lane * 8;
  float4 v0 = *(const float4*)p;
  float4 v1 = *(const float4*)(p + 4);
  float f[8] = {v0.x, v0.y, v0.z, v0.w, v1.x, v1.y, v1.z, v1.w};
  const int base = lane * 8;
  float mx = -3.0e38f;
#pragma unroll
  for (int j = 0; j < 8; ++j)
    if (!causal || base + j <= q) mx = fmaxf(mx, f[j]);
#pragma unroll
  for (int o = 32; o > 0; o >>= 1) mx = fmaxf(mx, __shfl_xor(mx, o));
  float s = 0.0f;
#pragma unroll
  for (int j = 0; j < 8; ++j) {
    float e = (!causal || base + j <= q) ? __expf(f[j] - mx) : 0.0f;
    f[j] = e; s += e;
  }
#pragma unroll
  for (int o = 32; o > 0; o >>= 1) s += __shfl_xor(s, o);
  const float inv = 1.0f / s;
  float4 o0 = {f[0] * inv, f[1] * inv, f[2] * inv, f[3] * inv};
  float4 o1 = {f[4] * inv, f[5] * inv, f[6] * inv, f[7] * inv};
  *(float4*)p = o0;
  *(float4*)(p + 4) = o1;
}

__global__ void add_ln_kernel(float* __restrict__ x, const float* __restrict__ res,
                              const float* __restrict__ g, const float* __restrict__ b) {
  const int row = blockIdx.x;
  const int c = threadIdx.x * 4;
  float4 xv = *(const float4*)(x + (long)row * kD + c);
  float4 rv = *(const float4*)(res + (long)row * kD + c);
  const float v0 = xv.x + rv.x, v1 = xv.y + rv.y, v2 = xv.z + rv.z, v3 = xv.w + rv.w;
  float s = v0 + v1 + v2 + v3;
  float ss = v0 * v0 + v1 * v1 + v2 * v2 + v3 * v3;
#pragma unroll
  for (int o = 32; o > 0; o >>= 1) { s += __shfl_xor(s, o); ss += __shfl_xor(ss, o); }
  __shared__ float red[4][2];
  const int wv = threadIdx.x >> 6;
  if ((threadIdx.x & 63) == 0) { red[wv][0] = s; red[wv][1] = ss; }
  __syncthreads();
  s  = red[0][0] + red[1][0] + red[2][0] + red[3][0];
  ss = red[0][1] + red[1][1] + red[2][1] + red[3][1];
  const float mean = s * (1.0f / kD);
  const float var = ss * (1.0f / kD) - mean * mean;
  const float rs = rsqrtf(var + 1e-5f);
  float4 gv = *(const float4*)(g + c);
  float4 bv = *(const float4*)(b + c);
  float4 o;
  o.x = gv.x * (v0 - mean) * rs + bv.x;
  o.y = gv.y * (v1 - mean) * rs + bv.y;
  o.z = gv.z * (v2 - mean) * rs + bv.z;
  o.w = gv.w * (v3 - mean) * rs + bv.w;
  *(float4*)(x + (long)row * kD + c) = o;
}

// ===========================================================================
extern "C" void kernel_launch(void* const* d_in, const int* in_sizes, int n_in,
                              void* d_out, int out_size, void* d_ws, size_t ws_size,
                              hipStream_t stream) {
  const int*   tgt  = (const int*)d_in[0];
  const float* enc  = (const float*)d_in[1];
  const float* emb  = (const float*)d_in[3];
  const float* Wout = (const float*)d_in[4];
  const float* bout = (const float*)d_in[5];
  const float* Wq_s = (const float*)d_in[6];
  const float* bq_s = (const float*)d_in[7];
  const float* Wk_s = (const float*)d_in[8];
  const float* bk_s = (const float*)d_in[9];
  const float* Wv_s = (const float*)d_in[10];
  const float* bv_s = (const float*)d_in[11];
  const float* Wo_s = (const float*)d_in[12];
  const float* bo_s = (const float*)d_in[13];
  const float* Wq_c = (const float*)d_in[14];
  const float* bq_c = (const float*)d_in[15];
  const float* Wk_c = (const float*)d_in[16];
  const float* bk_c = (const float*)d_in[17];
  const float* Wv_c = (const float*)d_in[18];
  const float* bv_c = (const float*)d_in[19];
  const float* Wo_c = (const float*)d_in[20];
  const float* bo_c = (const float*)d_in[21];
  const float* W1   = (const float*)d_in[22];
  const float* b1   = (const float*)d_in[23];
  const float* W2   = (const float*)d_in[24];
  const float* b2   = (const float*)d_in[25];
  const float* ln1g = (const float*)d_in[26];
  const float* ln1b = (const float*)d_in[27];
  const float* ln2g = (const float*)d_in[28];
  const float* ln2b = (const float*)d_in[29];
  const float* ln3g = (const float*)d_in[30];
  const float* ln3b = (const float*)d_in[31];

  float* out = (float*)d_out;
  const long DD = (long)kD * kD;
  const dim3 blk256(256), blkT(32, 8);

  if (ws_size >= (272ll << 20)) {
    // =================== FAST PATH ===================
    char* ws = (char*)d_ws;
    float* x     = (float*)ws;                    // 8 MiB
    u16* xb      = (u16*)(ws + (8l << 20));       // 4 MiB (contiguous with encb)
    u16* encb    = (u16*)(ws + (12l << 20));      // 4 MiB (A source, merged cross)
    u16* encb2   = (u16*)(ws + (16l << 20));      // 4 MiB (second copy for V slice)
    u16* Sqkv    = (u16*)(ws + (20l << 20));      // 12 MiB (2048x3072)
    u16* vt      = (u16*)(ws + (32l << 20));      // 4 MiB (B,H,dk,T)
    u16* S3b     = (u16*)(ws + (36l << 20));      // 4 MiB
    u16* Hb      = (u16*)(ws + (40l << 20));      // 16 MiB (2048x4096)
    float* Spart = (float*)(ws + (56l << 20));    // 16 MiB (2 f32 partials)
    u16* wbase   = (u16*)(ws + (72l << 20));      // 128 MiB
    u16* woutT   = (u16*)(ws + (200l << 20));     // 62.5 MiB
    float* bqkvS = (float*)(ws + (263l << 20));   // 48 KiB
    float* bqkvC = (float*)(ws + (263l << 20) + (64l << 10));  // 48 KiB
    const long WLAY = 16l * 1024 * 1024;          // u16 elems per layer block

    // ---- one-time prep ----
    for (int i = 0; i < kL; ++i) {
      u16* wqkvS = wbase + i * WLAY;
      u16* woS   = wqkvS + 3072 * 1024;
      u16* wqkvC = woS + 1024 * 1024;
      u16* woC   = wqkvC + 3072 * 1024;
      u16* w1t   = woC + 1024 * 1024;
      u16* w2t   = w1t + (long)4096 * 1024;
      TPtrs p{};
      p.in[0] = Wq_s + i * DD; p.out[0] = wqkvS;
      p.in[1] = Wk_s + i * DD; p.out[1] = wqkvS + 1024 * 1024;
      p.in[2] = Wv_s + i * DD; p.out[2] = wqkvS + 2048 * 1024;
      p.in[3] = Wo_s + i * DD; p.out[3] = woS;
      p.in[4] = Wq_c + i * DD; p.out[4] = wqkvC;
      p.in[5] = Wk_c + i * DD; p.out[5] = wqkvC + 1024 * 1024;
      p.in[6] = Wv_c + i * DD; p.out[6] = wqkvC + 2048 * 1024;
      p.in[7] = Wo_c + i * DD; p.out[7] = woC;
      transpose_wt_v2<<<dim3(32, 32, 8), blkT, 0, stream>>>(p, 1024, 1024);
      TPtrs p1{}; p1.in[0] = W1 + (long)i * kD * kF; p1.out[0] = w1t;
      transpose_wt_v2<<<dim3(128, 32, 1), blkT, 0, stream>>>(p1, 1024, 4096);
      TPtrs p2{}; p2.in[0] = W2 + (long)i * kF * kD; p2.out[0] = w2t;
      transpose_wt_v2<<<dim3(32, 128, 1), blkT, 0, stream>>>(p2, 4096, 1024);
    }
    TPtrs po{}; po.in[0] = Wout; po.out[0] = woutT;
    transpose_wt_v2<<<dim3(1000, 32, 1), blkT, 0, stream>>>(po, 1024, 32000);
    concat_bias<<<dim3(48), blk256, 0, stream>>>(bqkvS, bq_s, bk_s, bv_s, 3);
    concat_bias<<<dim3(48), blk256, 0, stream>>>(bqkvC, bq_c, bk_c, bv_c, 3);
    cvt_bf16_v3<<<dim3(2048), blk256, 0, stream>>>(enc, encb, encb2);
    embed_v2<<<dim3(kM), blk256, 0, stream>>>(tgt, emb, x, xb);

    for (int i = 0; i < kL; ++i) {
      u16* wqkvS = wbase + i * WLAY;
      u16* woS   = wqkvS + 3072 * 1024;
      u16* wqkvC = woS + 1024 * 1024;
      u16* woC   = wqkvC + 3072 * 1024;
      u16* w1t   = woC + 1024 * 1024;
      u16* w2t   = w1t + (long)4096 * 1024;
      float* wSelf  = out + kLOG + (long)i * kBHTT;
      float* wCross = out + kLOG + (long)kL * kBHTT + (long)i * kBHTT;

      // -------- self attention --------
      gemm_bf<128, 128, 1, 1><<<dim3(24, 16, 1), blk256, 0, stream>>>(
          xb, wqkvS, bqkvS + i * 3072, Sqkv, vt, 1024, 1024, 1024, 3072,
          1, 0, 0, 0, 0, 0, 0, 1.0f, 0, 0);
      attn_fused<1><<<dim3(4, 64), dim3(512), 0, stream>>>(Sqkv, Sqkv + 1024, vt, wSelf, S3b);
      gemm_bf<128, 128, 0, 0><<<dim3(8, 16, 2), blk256, 0, stream>>>(
          S3b, woS, bo_s + (long)i * kD, Spart, nullptr, 512, 1024, 1024, 1024,
          1, 512, 0, 512, 0, kPART, 0, 1.0f, 0, 0);
      add_ln_v3<<<dim3(kM), blk256, 0, stream>>>(x, xb, Spart, 2,
          ln1g + (long)i * kD, ln1b + (long)i * kD);

      // -------- cross attention (merged Q/K/V via z: xb|encb|encb2) --------
      gemm_bf<128, 128, 1, 1><<<dim3(8, 16, 3), blk256, 0, stream>>>(
          xb, wqkvC, bqkvC + i * 3072, Sqkv, vt, 1024, 1024, 1024, 3072,
          3, 0, (long)2048 * 1024, 0, (long)1024 * 1024, 0, 1024, 1.0f, 0, 1024);
      attn_fused<0><<<dim3(4, 64), dim3(512), 0, stream>>>(Sqkv, Sqkv + 1024, vt, wCross, S3b);
      gemm_bf<128, 128, 0, 0><<<dim3(8, 16, 2), blk256, 0, stream>>>(
          S3b, woC, bo_c + (long)i * kD, Spart, nullptr, 512, 1024, 1024, 1024,
          1, 512, 0, 512, 0, kPART, 0, 1.0f, 0, 0);
      add_ln_v3<<<dim3(kM), blk256, 0, stream>>>(x, xb, Spart, 2,
          ln2g + (long)i * kD, ln2b + (long)i * kD);

      // -------- FFN --------
      gemm_bf<128, 128, 1, 0><<<dim3(32, 16, 1), blk256, 0, stream>>>(
          xb, w1t, b1 + (long)i * kF, Hb, nullptr, 1024, 1024, 1024, 4096,
          1, 0, 0, 0, 0, 0, 0, 1.0f, 1, 0);
      gemm_bf<128, 128, 0, 0><<<dim3(8, 16, 2), blk256, 0, stream>>>(
          Hb, w2t, b2 + (long)i * kD, Spart, nullptr, 2048, 4096, 4096, 1024,
          1, 2048, 0, 2048, 0, kPART, 0, 1.0f, 0, 0);
      add_ln_v3<<<dim3(kM), blk256, 0, stream>>>(x, xb, Spart, 2,
          ln3g + (long)i * kD, ln3b + (long)i * kD);
    }

    gemm_bf<128, 128, 0, 0><<<dim3(250, 16, 1), blk256, 0, stream>>>(
        xb, woutT, bout, out, nullptr, 1024, 1024, 1024, 32000,
        1, 0, 0, 0, 0, 0, 0, 1.0f, 0, 0);
    return;
  }

  // =================== FALLBACK (Round-3 verified) ===================
  float* x = (float*)d_ws;
  char* sc = (char*)d_out;
  float* S0 = (float*)sc;
  float* S1 = (float*)(sc + (8l  << 20));
  float* S2 = (float*)(sc + (16l << 20));
  float* S3 = (float*)(sc + (24l << 20));
  float* S4 = (float*)(sc + (32l << 20));
  u16*   vt = (u16*)  (sc + (40l << 20));

  embed_kernel<<<dim3(kM), blk256, 0, stream>>>(tgt, emb, x);
  auto wgemm = [&](const float* A, const float* W, const float* bias, float* C) {
    gemm_kernel<128, 128, float, float, 1><<<dim3(kD / 128, kM / 128, 1), blk256, 0, stream>>>(
        A, W, bias, C, kD, kD, kD, kD, 1, 0, 0, 0, 0, 0, 0, 1.0f, 0);
  };
  for (int i = 0; i < kL; ++i) {
    const long wOff = (long)i * DD;
    float* wSelf  = out + kLOG + (long)i * kBHTT;
    float* wCross = out + kLOG + (long)kL * kBHTT + (long)i * kBHTT;
    wgemm(x, Wq_s + wOff, bq_s + (long)i * kD, S0);
    wgemm(x, Wk_s + wOff, bk_s + (long)i * kD, S1);
    wgemm(x, Wv_s + wOff, bv_s + (long)i * kD, S2);
    transpose_v_kernel<<<dim3(16, 2, 64), blkT, 0, stream>>>(S2, vt);
    gemm_kernel<128, 128, float, float, 0><<<dim3(4, 4, 64), blk256, 0, stream>>>(
        S0, S1, nullptr, wSelf, kDK, kD, kD, kT,
        kH, kTD, (long)kDK, kTD, (long)kDK, kHTT, kTT, 0.125f, 0);
    softmax_kernel<<<dim3(kB * kH * kT / 4), blk256, 0, stream>>>(wSelf, 1);
    gemm_kernel<128, 64, float, u16, 0><<<dim3(1, 4, 64), blk256, 0, stream>>>(
        wSelf, vt, nullptr, S3, kT, kT, kT, kD,
        kH, kHTT, kTT, (long)kH * kDK * kT, (long)kDK * kT, kTD, (long)kDK, 1.0f, 0);
    wgemm(S3, Wo_s + wOff, bo_s + (long)i * kD, S0);
    add_ln_kernel<<<dim3(kM), blk256, 0, stream>>>(x, S0, ln1g + (long)i * kD, ln1b + (long)i * kD);
    wgemm(x,   Wq_c + wOff, bq_c + (long)i * kD, S0);
    wgemm(enc, Wk_c + wOff, bk_c + (long)i * kD, S1);
    wgemm(enc, Wv_c + wOff, bv_c + (long)i * kD, S2);
    transpose_v_kernel<<<dim3(16, 2, 64), blkT, 0, stream>>>(S2, vt);
    gemm_kernel<128, 128, float, float, 0><<<dim3(4, 4, 64), blk256, 0, stream>>>(
        S0, S1, nullptr, wCross, kDK, kD, kD, kT,
        kH, kTD, (long)kDK, kTD, (long)kDK, kHTT, kTT, 0.125f, 0);
    softmax_kernel<<<dim3(kB * kH * kT / 4), blk256, 0, stream>>>(wCross, 0);
    gemm_kernel<128, 64, float, u16, 0><<<dim3(1, 4, 64), blk256, 0, stream>>>(
        wCross, vt, nullptr, S3, kT, kT, kT, kD,
        kH, kHTT, kTT, (long)kH * kDK * kT, (long)kDK * kT, kTD, (long)kDK, 1.0f, 0);
    wgemm(S3, Wo_c + wOff, bo_c + (long)i * kD, S0);
    add_ln_kernel<<<dim3(kM), blk256, 0, stream>>>(x, S0, ln2g + (long)i * kD, ln2b + (long)i * kD);
    gemm_kernel<128, 128, float, float, 1><<<dim3(kF / 128, kM / 128, 1), blk256, 0, stream>>>(
        x, W1 + (long)i * kD * kF, b1 + (long)i * kF, S0, kD, kD, kF, kF,
        1, 0, 0, 0, 0, 0, 0, 1.0f, 1);
    gemm_kernel<128, 128, float, float, 1><<<dim3(kD / 128, kM / 128, 1), blk256, 0, stream>>>(
        S0, W2 + (long)i * kF * kD, b2 + (long)i * kD, S4, kF, kF, kD, kD,
        1, 0, 0, 0, 0, 0, 0, 1.0f, 0);
    add_ln_kernel<<<dim3(kM), blk256, 0, stream>>>(x, S4, ln3g + (long)i * kD, ln3b + (long)i * kD);
  }
  gemm_kernel<128, 128, float, float, 1><<<dim3(kV / 128, kM / 128, 1), blk256, 0, stream>>>(
      x, Wout, bout, out, kD, kD, kV, kV,
      1, 0, 0, 0, 0, 0, 0, 1.0f, 0);
}

// Round 10
// 1512.451 us; speedup vs baseline: 2.3019x; 1.0141x over previous
//
#include <hip/hip_runtime.h>

// TransformerDecoder on MI355X. Round 10:
// - vectorized (float4) 64x64 weight transpose (prep was ~150us, scalar loads)
// - split-K x4 for O-proj and FFN2 with single-buffer GEMM variant (TLP: 512
//   blocks => 8 waves/CU vs 4) ; add_ln sums 4 partials
// - gemm_bf gains DBUF param: dbuf for QKV/FFN1/logits, single for split-K
// Attention + rest = Round-9 passing code. Fallback = Round-3 proven.

typedef unsigned short u16;
typedef __bf16 v8bf __attribute__((ext_vector_type(8)));
typedef float v4f __attribute__((ext_vector_type(4)));

namespace {
constexpr int kB = 4, kT = 512, kD = 1024, kH = 16, kDK = 64, kF = 4096, kV = 32000, kL = 4;
constexpr int kM = kB * kT;
constexpr long kTD = (long)kT * kD;
constexpr long kTT = (long)kT * kT;
constexpr long kHTT = (long)kH * kTT;
constexpr long kBHTT = (long)kB * kHTT;
constexpr long kLOG = (long)kM * kV;
constexpr long kPART = (long)kM * kD;
}

__device__ __forceinline__ u16 f2bf(float f) {
  union { float f; unsigned u; } v; v.f = f;
  unsigned r = v.u + 0x7FFFu + ((v.u >> 16) & 1u);
  return (u16)(r >> 16);
}
__device__ __forceinline__ float bf2f(u16 h) {
  union { unsigned u; float f; } v; v.u = ((unsigned)h) << 16;
  return v.f;
}

typedef __attribute__((address_space(3))) void lds_void;
typedef const __attribute__((address_space(1))) void glob_void;
__device__ __forceinline__ void gl2lds16(const void* g, void* l) {
  __builtin_amdgcn_global_load_lds((glob_void*)g, (lds_void*)l, 16, 0, 0);
}

// ---------------------------------------------------------------------------
// bf16 GEMM, BK=64, swizzled LDS. DBUF=1: double-buffered (1 barrier/step).
// DBUF=0: single buffer (2 barriers/step, 32KB LDS -> higher residency).
// C[m][n] = scale*sum A[m][k]*B[n][k] + bias[zh*bstride+n] (zb==0 only).
// VTR: cols>=2048 of a (.,3072) C also written transposed into vt (B,H,dk,T).
// ---------------------------------------------------------------------------
template <int BM, int BN, int OUTBF, int VTR, int DBUF>
__global__ __launch_bounds__(256)
void gemm_bf(const u16* __restrict__ A0, const u16* __restrict__ B0,
             const float* __restrict__ bias, void* __restrict__ Cv,
             u16* __restrict__ vtw,
             const int K, const int lda, const int ldb, const int ldc,
             const int nH, const long sAb, const long sAh,
             const long sBb, const long sBh, const long sCb, const long sCh,
             const float scale, const int relu, const int bstride) {
  static_assert(BM % 32 == 0 && BN % 32 == 0, "tiles");
  __shared__ u16 As[DBUF + 1][BM][64];
  __shared__ u16 Bs[DBUF + 1][BN][64];
  const int tid = threadIdx.x;
  const int lane = tid & 63;
  const int w = tid >> 6;
  const int z = blockIdx.z;
  const int zb = z / nH, zh = z - zb * nH;
  const u16* A = A0 + zb * sAb + zh * sAh + (long)blockIdx.y * BM * lda;
  const u16* B = B0 + zb * sBb + zh * sBh + (long)blockIdx.x * BN * ldb;
  const long offC = zb * sCb + zh * sCh;
  const int wm = w >> 1, wn = w & 1;
  constexpr int FM = BM / 32, FN = BN / 32;
  v4f acc[FM][FN];
  const v4f zero = {0.f, 0.f, 0.f, 0.f};
#pragma unroll
  for (int i = 0; i < FM; ++i)
#pragma unroll
    for (int j = 0; j < FN; ++j) acc[i][j] = zero;
  const int l15 = lane & 15, lk = lane >> 4;
  const int lr8 = lane >> 3;                       // row within 8-row stripe
  const int swz = ((lane & 7) ^ lr8) * 8;          // pre-swizzled source col
  const int l7 = l15 & 7;

  if constexpr (DBUF) {
    // prologue: stage tile 0 into buffer 0
#pragma unroll
    for (int s = 0; s < BM / 32; ++s)
      gl2lds16(A + (long)(w * (BM / 4) + s * 8 + lr8) * lda + swz,
               &As[0][w * (BM / 4) + s * 8][0]);
#pragma unroll
    for (int s = 0; s < BN / 32; ++s)
      gl2lds16(B + (long)(w * (BN / 4) + s * 8 + lr8) * ldb + swz,
               &Bs[0][w * (BN / 4) + s * 8][0]);

    const int NT = K >> 6;
    for (int kt = 0; kt < NT; ++kt) {
      const int cur = kt & 1;
      __syncthreads();   // drains prev stage + prev reads
      if (kt + 1 < NT) {
        const int k0 = (kt + 1) << 6;
#pragma unroll
        for (int s = 0; s < BM / 32; ++s)
          gl2lds16(A + (long)(w * (BM / 4) + s * 8 + lr8) * lda + k0 + swz,
                   &As[cur ^ 1][w * (BM / 4) + s * 8][0]);
#pragma unroll
        for (int s = 0; s < BN / 32; ++s)
          gl2lds16(B + (long)(w * (BN / 4) + s * 8 + lr8) * ldb + k0 + swz,
                   &Bs[cur ^ 1][w * (BN / 4) + s * 8][0]);
      }
#pragma unroll
      for (int t = 0; t < 2; ++t) {
        const int c0 = t * 4;
        v8bf af[FM], bfr[FN];
#pragma unroll
        for (int i = 0; i < FM; ++i)
          af[i] = *(const v8bf*)&As[cur][wm * (BM / 2) + i * 16 + l15][((c0 + lk) ^ l7) * 8];
#pragma unroll
        for (int j = 0; j < FN; ++j)
          bfr[j] = *(const v8bf*)&Bs[cur][wn * (BN / 2) + j * 16 + l15][((c0 + lk) ^ l7) * 8];
#pragma unroll
        for (int i = 0; i < FM; ++i)
#pragma unroll
          for (int j = 0; j < FN; ++j)
            acc[i][j] = __builtin_amdgcn_mfma_f32_16x16x32_bf16(af[i], bfr[j], acc[i][j], 0, 0, 0);
      }
    }
  } else {
    for (int k0 = 0; k0 < K; k0 += 64) {
      __syncthreads();
#pragma unroll
      for (int s = 0; s < BM / 32; ++s)
        gl2lds16(A + (long)(w * (BM / 4) + s * 8 + lr8) * lda + k0 + swz,
                 &As[0][w * (BM / 4) + s * 8][0]);
#pragma unroll
      for (int s = 0; s < BN / 32; ++s)
        gl2lds16(B + (long)(w * (BN / 4) + s * 8 + lr8) * ldb + k0 + swz,
                 &Bs[0][w * (BN / 4) + s * 8][0]);
      __syncthreads();
#pragma unroll
      for (int t = 0; t < 2; ++t) {
        const int c0 = t * 4;
        v8bf af[FM], bfr[FN];
#pragma unroll
        for (int i = 0; i < FM; ++i)
          af[i] = *(const v8bf*)&As[0][wm * (BM / 2) + i * 16 + l15][((c0 + lk) ^ l7) * 8];
#pragma unroll
        for (int j = 0; j < FN; ++j)
          bfr[j] = *(const v8bf*)&Bs[0][wn * (BN / 2) + j * 16 + l15][((c0 + lk) ^ l7) * 8];
#pragma unroll
        for (int i = 0; i < FM; ++i)
#pragma unroll
          for (int j = 0; j < FN; ++j)
            acc[i][j] = __builtin_amdgcn_mfma_f32_16x16x32_bf16(af[i], bfr[j], acc[i][j], 0, 0, 0);
      }
    }
  }

  const long m0 = (long)blockIdx.y * BM + wm * (BM / 2);
  const int n0 = blockIdx.x * BN + wn * (BN / 2);
#pragma unroll
  for (int j = 0; j < FN; ++j) {
    const int col = n0 + j * 16 + l15;
    const float bv = (bias && zb == 0) ? bias[zh * bstride + col] : 0.0f;
#pragma unroll
    for (int i = 0; i < FM; ++i) {
      const long row = m0 + i * 16 + lk * 4;
#pragma unroll
      for (int r = 0; r < 4; ++r) {
        float v = acc[i][j][r] * scale + bv;
        if (relu) v = fmaxf(v, 0.0f);
        const long idx = offC + (row + r) * ldc + col;
        if (OUTBF) ((u16*)Cv)[idx] = f2bf(v);
        else       ((float*)Cv)[idx] = v;
        if (VTR) {
          const int colS = (int)(offC % 3072) + col;   // column within (.,3072)
          if (colS >= 2048) {
            const int hh = (colS - 2048) >> 6, dd = (colS - 2048) & 63;
            const int rowg = (int)(row + r);
            vtw[((long)((rowg >> 9) * 16 + hh)) * 32768 + dd * 512 + (rowg & 511)] = f2bf(v);
          }
        }
      }
    }
  }
}

// ---------------------------------------------------------------------------
// Fused attention: per block 128 q-rows x one (b,h): QK^T (swizzled LDS),
// softmax (writes w f32 to d_out), then PV via padded-LDS P/V^T chunks,
// writes O bf16 into S3b (2048,1024). 512 threads = 8 waves (2 wm x 4 wn).
// ---------------------------------------------------------------------------
template <int CAUSAL>
__global__ __launch_bounds__(512)
void attn_fused(const u16* __restrict__ Qb, const u16* __restrict__ Kb,
                const u16* __restrict__ vtp, float* __restrict__ wout,
                u16* __restrict__ oout) {
  __shared__ __align__(16) char lds[81920];
  u16 (*Qs)[64] = (u16 (*)[64])lds;                 // [128][64]
  u16 (*Ks)[64] = (u16 (*)[64])(lds + 16384);       // [512][64]
  u16 (*Pl)[136] = (u16 (*)[136])lds;               // [128][136] 34816 B
  u16 (*Vt)[136] = (u16 (*)[136])(lds + 34816);     // [64][136]  17408 B
  __shared__ float redM[128][4];
  __shared__ float redS[128][4];
  const int tid = threadIdx.x, lane = tid & 63, w = tid >> 6;
  const int wm = w >> 2, wn = w & 3;
  const int l15 = lane & 15, lk = lane >> 4;
  const int lr8 = lane >> 3;
  const int swz = ((lane & 7) ^ lr8) * 8;
  const int l7 = l15 & 7;
  const int bx = blockIdx.x;
  const int z = blockIdx.y, zb = z >> 4, zh = z & 15;
  const u16* Q = Qb + (long)zb * 512 * 3072 + zh * 64 + (long)bx * 128 * 3072;
  const u16* Kp = Kb + (long)zb * 512 * 3072 + zh * 64;
  const u16* vtz = vtp + (long)((zb << 4) + zh) * 32768;
  const long obase = (long)zb * kHTT + (long)zh * kTT;

#pragma unroll
  for (int s = 0; s < 2; ++s)
    gl2lds16(Q + (long)(w * 16 + s * 8 + lr8) * 3072 + swz, &Qs[w * 16 + s * 8][0]);
#pragma unroll
  for (int s = 0; s < 8; ++s) {
    const int r0 = w * 64 + s * 8;
    if (!CAUSAL || r0 <= bx * 128 + 127)
      gl2lds16(Kp + (long)(r0 + lr8) * 3072 + swz, &Ks[r0][0]);
  }
  __syncthreads();

  v4f acc[4][8];
  const v4f zero = {0.f, 0.f, 0.f, 0.f};
#pragma unroll
  for (int i = 0; i < 4; ++i)
#pragma unroll
    for (int j = 0; j < 8; ++j) acc[i][j] = zero;

#pragma unroll
  for (int t = 0; t < 2; ++t) {
    const int c0 = t * 4;
    v8bf aq[4], bk[8];
#pragma unroll
    for (int i = 0; i < 4; ++i)
      aq[i] = *(const v8bf*)&Qs[wm * 64 + i * 16 + l15][((c0 + lk) ^ l7) * 8];
#pragma unroll
    for (int j = 0; j < 8; ++j)
      bk[j] = *(const v8bf*)&Ks[wn * 128 + j * 16 + l15][((c0 + lk) ^ l7) * 8];
#pragma unroll
    for (int i = 0; i < 4; ++i)
#pragma unroll
      for (int j = 0; j < 8; ++j)
        if (!(CAUSAL && wn * 128 + j * 16 > bx * 128 + wm * 64 + i * 16 + 15))
          acc[i][j] = __builtin_amdgcn_mfma_f32_16x16x32_bf16(aq[i], bk[j], acc[i][j], 0, 0, 0);
  }

  // row max
  float gmax[4][4];
#pragma unroll
  for (int i = 0; i < 4; ++i)
#pragma unroll
    for (int r = 0; r < 4; ++r) {
      const int q = bx * 128 + wm * 64 + i * 16 + lk * 4 + r;
      float m = -3.0e38f;
#pragma unroll
      for (int j = 0; j < 8; ++j) {
        const int col = wn * 128 + j * 16 + l15;
        if (!CAUSAL || col <= q) m = fmaxf(m, acc[i][j][r] * 0.125f);
      }
#pragma unroll
      for (int off = 1; off < 16; off <<= 1) m = fmaxf(m, __shfl_xor(m, off));
      if (l15 == 0) redM[wm * 64 + i * 16 + lk * 4 + r][wn] = m;
    }
  __syncthreads();
#pragma unroll
  for (int i = 0; i < 4; ++i)
#pragma unroll
    for (int r = 0; r < 4; ++r) {
      v4f mv = *(const v4f*)&redM[wm * 64 + i * 16 + lk * 4 + r][0];
      gmax[i][r] = fmaxf(fmaxf(mv[0], mv[1]), fmaxf(mv[2], mv[3]));
    }
  // exp + row sum
#pragma unroll
  for (int i = 0; i < 4; ++i)
#pragma unroll
    for (int r = 0; r < 4; ++r) {
      const int q = bx * 128 + wm * 64 + i * 16 + lk * 4 + r;
      float s = 0.0f;
#pragma unroll
      for (int j = 0; j < 8; ++j) {
        const int col = wn * 128 + j * 16 + l15;
        float e = (!CAUSAL || col <= q) ? __expf(acc[i][j][r] * 0.125f - gmax[i][r]) : 0.0f;
        acc[i][j][r] = e;
        s += e;
      }
#pragma unroll
      for (int off = 1; off < 16; off <<= 1) s += __shfl_xor(s, off);
      if (l15 == 0) redS[wm * 64 + i * 16 + lk * 4 + r][wn] = s;
    }
  __syncthreads();
  // normalize, write w (f32), keep normalized P in acc
#pragma unroll
  for (int i = 0; i < 4; ++i)
#pragma unroll
    for (int r = 0; r < 4; ++r) {
      v4f sv = *(const v4f*)&redS[wm * 64 + i * 16 + lk * 4 + r][0];
      const float inv = 1.0f / (sv[0] + sv[1] + sv[2] + sv[3]);
      const int q = bx * 128 + wm * 64 + i * 16 + lk * 4 + r;
      const long rowoff = obase + (long)q * 512;
#pragma unroll
      for (int j = 0; j < 8; ++j) {
        const int col = wn * 128 + j * 16 + l15;
        const float v = acc[i][j][r] * inv;
        acc[i][j][r] = v;
        wout[rowoff + col] = v;
      }
    }

  // ---- PV: O[128 q][64 d] = P @ V, chunked over k (128 per chunk) ----
  v4f acco[4];
#pragma unroll
  for (int i = 0; i < 4; ++i) acco[i] = zero;
  const int kcMax = CAUSAL ? bx : 3;
  for (int kc = 0; kc <= kcMax; ++kc) {
    __syncthreads();
    if (wn == kc) {       // this wave-group owns P cols [kc*128, kc*128+128)
#pragma unroll
      for (int i = 0; i < 4; ++i)
#pragma unroll
        for (int j = 0; j < 8; ++j) {
          const int colk = j * 16 + l15;
#pragma unroll
          for (int r = 0; r < 4; ++r)
            Pl[wm * 64 + i * 16 + lk * 4 + r][colk] = f2bf(acc[i][j][r]);
        }
    }
    // stage V^T chunk [64 d][128 k] into padded Vt
#pragma unroll
    for (int s = 0; s < 2; ++s) {
      const int c = tid * 2 + s;            // 0..1023 chunks of 16B
      const int d = c >> 4, off = (c & 15) * 8;
      uint4 vv = *(const uint4*)(vtz + (long)d * 512 + kc * 128 + off);
      *(uint4*)&Vt[d][off] = vv;
    }
    __syncthreads();
#pragma unroll
    for (int t = 0; t < 4; ++t) {
      v8bf bv = *(const v8bf*)&Vt[wn * 16 + l15][t * 32 + lk * 8];
#pragma unroll
      for (int i = 0; i < 4; ++i) {
        v8bf ap = *(const v8bf*)&Pl[wm * 64 + i * 16 + l15][t * 32 + lk * 8];
        acco[i] = __builtin_amdgcn_mfma_f32_16x16x32_bf16(ap, bv, acco[i], 0, 0, 0);
      }
    }
  }
  // write O bf16 into S3b (2048,1024) at column zh*64
#pragma unroll
  for (int i = 0; i < 4; ++i)
#pragma unroll
    for (int r = 0; r < 4; ++r) {
      const int row = bx * 128 + wm * 64 + i * 16 + lk * 4 + r;
      oout[(long)(zb * 512 + row) * 1024 + zh * 64 + wn * 16 + l15] = f2bf(acco[i][r]);
    }
}

// Weight transpose-convert: out(N,K) bf16 = in(K,N)^T f32; 64x64 tiles,
// float4 vectorized loads, uint2 vectorized stores. Batched ptr pairs.
struct TPtrs { const float* in[8]; u16* out[8]; };

__global__ void transpose_wt_v3(TPtrs ps, int K, int N) {
  __shared__ float tile[64][65];
  const float* in = ps.in[blockIdx.z];
  u16* o = ps.out[blockIdx.z];
  const int n0 = blockIdx.x * 64, k0 = blockIdx.y * 64;
  const int tr = threadIdx.x >> 4;          // 0..15
  const int tc = (threadIdx.x & 15) * 4;    // 0,4,..,60
#pragma unroll
  for (int i = 0; i < 4; ++i) {
    float4 v = *(const float4*)(in + (long)(k0 + tr + 16 * i) * N + n0 + tc);
    tile[tr + 16 * i][tc + 0] = v.x;
    tile[tr + 16 * i][tc + 1] = v.y;
    tile[tr + 16 * i][tc + 2] = v.z;
    tile[tr + 16 * i][tc + 3] = v.w;
  }
  __syncthreads();
#pragma unroll
  for (int i = 0; i < 4; ++i) {
    const int rr = tr + 16 * i;             // n within tile
    u16 h[4];
#pragma unroll
    for (int j = 0; j < 4; ++j) h[j] = f2bf(tile[tc + j][rr]);
    *(uint2*)(o + (long)(n0 + rr) * K + k0 + tc) = *(const uint2*)h;
  }
}

__global__ void concat_bias(float* __restrict__ dst, const float* __restrict__ s0,
                            const float* __restrict__ s1, const float* __restrict__ s2,
                            const int nsrc) {
  const int idx = blockIdx.x * 256 + threadIdx.x;
  const int per = nsrc << 10;
  const int l = idx / per, rem = idx - l * per, s = rem >> 10, j = rem & 1023;
  const float* src = (s == 0) ? s0 : (s == 1 ? s1 : s2);
  dst[idx] = src[l * 1024 + j];
}

__global__ void cvt_bf16_v3(const float* __restrict__ in, u16* __restrict__ o1,
                            u16* __restrict__ o2) {
  const long i = ((long)blockIdx.x * 256 + threadIdx.x) * 4;
  float4 v = *(const float4*)(in + i);
  u16 h[4] = {f2bf(v.x), f2bf(v.y), f2bf(v.z), f2bf(v.w)};
  *(uint2*)(o1 + i) = *(const uint2*)h;
  *(uint2*)(o2 + i) = *(const uint2*)h;
}

__global__ void embed_v2(const int* __restrict__ tgt, const float* __restrict__ emb,
                         float* __restrict__ x, u16* __restrict__ xb) {
  const int row = blockIdx.x;
  const int t = row & (kT - 1);
  const int tok = tgt[row];
  const int c = threadIdx.x * 4;
  float4 e = *(const float4*)(emb + (long)tok * kD + c);
  const float nl = -9.210340371976184f / (float)kD;
  const float a0 = (float)t * expf((float)c * nl);
  const float a1 = (float)t * expf((float)(c + 2) * nl);
  float4 o;
  o.x = e.x * 32.0f + sinf(a0);
  o.y = e.y * 32.0f + cosf(a0);
  o.z = e.z * 32.0f + sinf(a1);
  o.w = e.w * 32.0f + cosf(a1);
  *(float4*)(x + (long)row * kD + c) = o;
  u16 h[4] = {f2bf(o.x), f2bf(o.y), f2bf(o.z), f2bf(o.w)};
  *(uint2*)(xb + (long)row * kD + c) = *(const uint2*)h;
}

// x = LN(x + sum_{p<nres} res[p]); writes x f32 and xb bf16
__global__ void add_ln_v3(float* __restrict__ x, u16* __restrict__ xb,
                          const float* __restrict__ res, const int nres,
                          const float* __restrict__ g, const float* __restrict__ b) {
  const int row = blockIdx.x;
  const int c = threadIdx.x * 4;
  float4 xv = *(const float4*)(x + (long)row * kD + c);
  float v0 = xv.x, v1 = xv.y, v2 = xv.z, v3 = xv.w;
  for (int p = 0; p < nres; ++p) {
    float4 rv = *(const float4*)(res + p * kPART + (long)row * kD + c);
    v0 += rv.x; v1 += rv.y; v2 += rv.z; v3 += rv.w;
  }
  float s = v0 + v1 + v2 + v3;
  float ss = v0 * v0 + v1 * v1 + v2 * v2 + v3 * v3;
#pragma unroll
  for (int o = 32; o > 0; o >>= 1) { s += __shfl_xor(s, o); ss += __shfl_xor(ss, o); }
  __shared__ float red[4][2];
  const int wv = threadIdx.x >> 6;
  if ((threadIdx.x & 63) == 0) { red[wv][0] = s; red[wv][1] = ss; }
  __syncthreads();
  s  = red[0][0] + red[1][0] + red[2][0] + red[3][0];
  ss = red[0][1] + red[1][1] + red[2][1] + red[3][1];
  const float mean = s * (1.0f / kD);
  const float var = ss * (1.0f / kD) - mean * mean;
  const float rs = rsqrtf(var + 1e-5f);
  float4 gv = *(const float4*)(g + c);
  float4 bv = *(const float4*)(b + c);
  float4 o;
  o.x = gv.x * (v0 - mean) * rs + bv.x;
  o.y = gv.y * (v1 - mean) * rs + bv.y;
  o.z = gv.z * (v2 - mean) * rs + bv.z;
  o.w = gv.w * (v3 - mean) * rs + bv.w;
  *(float4*)(x + (long)row * kD + c) = o;
  u16 h[4] = {f2bf(o.x), f2bf(o.y), f2bf(o.z), f2bf(o.w)};
  *(uint2*)(xb + (long)row * kD + c) = *(const uint2*)h;
}

// ===========================================================================
// FALLBACK PATH (Round-3 proven)
// ===========================================================================
template <int BM, int BN, typename TA, typename TB, int BKN>
__global__ __launch_bounds__(256)
void gemm_kernel(const void* __restrict__ Av, const void* __restrict__ Bv,
                 const float* __restrict__ bias, float* __restrict__ Cv,
                 const int K, const int lda, const int ldb, const int ldc,
                 const int nH, const long sAb, const long sAh,
                 const long sBb, const long sBh, const long sCb, const long sCh,
                 const float scale, const int relu) {
  constexpr int LP = 40;
  __shared__ u16 As[BM][LP];
  __shared__ u16 Bs[BN][LP];
  const int tid = threadIdx.x;
  const int z = blockIdx.z;
  const int zb = z / nH, zh = z - zb * nH;
  const TA* A = (const TA*)Av + zb * sAb + zh * sAh + (long)blockIdx.y * BM * lda;
  const TB* Bp;
  if constexpr (BKN)
    Bp = (const TB*)Bv + zb * sBb + zh * sBh + (long)blockIdx.x * BN;
  else
    Bp = (const TB*)Bv + zb * sBb + zh * sBh + (long)blockIdx.x * BN * ldb;
  const long offC = zb * sCb + zh * sCh;
  const int lane = tid & 63;
  const int wm = (tid >> 7) & 1, wn = (tid >> 6) & 1;
  constexpr int FM = BM / 32, FN = BN / 32;
  v4f acc[FM][FN];
  const v4f zero = {0.f, 0.f, 0.f, 0.f};
#pragma unroll
  for (int i = 0; i < FM; ++i)
#pragma unroll
    for (int j = 0; j < FN; ++j) acc[i][j] = zero;
  const int l15 = lane & 15, lk = lane >> 4;

  for (int k0 = 0; k0 < K; k0 += 32) {
    __syncthreads();
    if constexpr (sizeof(TA) == 4) {
      const int r = tid >> 3, c = (tid & 7) * 4;
#pragma unroll
      for (int rr = 0; rr < BM; rr += 32) {
        float4 vv = *(const float4*)((const float*)A + (long)(rr + r) * lda + k0 + c);
        unsigned lo = (unsigned)f2bf(vv.x) | ((unsigned)f2bf(vv.y) << 16);
        unsigned hi = (unsigned)f2bf(vv.z) | ((unsigned)f2bf(vv.w) << 16);
        *(uint2*)&As[rr + r][c] = make_uint2(lo, hi);
      }
    } else {
      const int r = tid >> 2, c = (tid & 3) * 8;
#pragma unroll
      for (int rr = 0; rr < BM; rr += 64) {
        uint4 vv = *(const uint4*)((const u16*)A + (long)(rr + r) * lda + k0 + c);
        *(uint4*)&As[rr + r][c] = vv;
      }
    }
    if constexpr (BKN) {
      const int r = tid >> 3, c = (tid & 7) * 4;
#pragma unroll
      for (int nn = 0; nn < BN; nn += 32) {
        float4 vv = *(const float4*)((const float*)Bp + (long)(k0 + r) * ldb + nn + c);
        Bs[nn + c + 0][r] = f2bf(vv.x);
        Bs[nn + c + 1][r] = f2bf(vv.y);
        Bs[nn + c + 2][r] = f2bf(vv.z);
        Bs[nn + c + 3][r] = f2bf(vv.w);
      }
    } else if constexpr (sizeof(TB) == 4) {
      const int r = tid >> 3, c = (tid & 7) * 4;
#pragma unroll
      for (int rr = 0; rr < BN; rr += 32) {
        float4 vv = *(const float4*)((const float*)Bp + (long)(rr + r) * ldb + k0 + c);
        unsigned lo = (unsigned)f2bf(vv.x) | ((unsigned)f2bf(vv.y) << 16);
        unsigned hi = (unsigned)f2bf(vv.z) | ((unsigned)f2bf(vv.w) << 16);
        *(uint2*)&Bs[rr + r][c] = make_uint2(lo, hi);
      }
    } else {
      const int r = tid >> 2, c = (tid & 3) * 8;
#pragma unroll
      for (int rr = 0; rr < BN; rr += 64) {
        uint4 vv = *(const uint4*)((const u16*)Bp + (long)(rr + r) * ldb + k0 + c);
        *(uint4*)&Bs[rr + r][c] = vv;
      }
    }
    __syncthreads();
    v8bf af[FM], bfr[FN];
#pragma unroll
    for (int i = 0; i < FM; ++i)
      af[i] = *(const v8bf*)&As[wm * (BM / 2) + i * 16 + l15][lk * 8];
#pragma unroll
    for (int j = 0; j < FN; ++j)
      bfr[j] = *(const v8bf*)&Bs[wn * (BN / 2) + j * 16 + l15][lk * 8];
#pragma unroll
    for (int i = 0; i < FM; ++i)
#pragma unroll
      for (int j = 0; j < FN; ++j)
        acc[i][j] = __builtin_amdgcn_mfma_f32_16x16x32_bf16(af[i], bfr[j], acc[i][j], 0, 0, 0);
  }

  const long m0 = (long)blockIdx.y * BM + wm * (BM / 2);
  const int n0 = blockIdx.x * BN + wn * (BN / 2);
#pragma unroll
  for (int j = 0; j < FN; ++j) {
    const int col = n0 + j * 16 + l15;
    const float bv = bias ? bias[col] : 0.0f;
#pragma unroll
    for (int i = 0; i < FM; ++i) {
      const long row = m0 + i * 16 + lk * 4;
#pragma unroll
      for (int r = 0; r < 4; ++r) {
        float v = acc[i][j][r] * scale + bv;
        if (relu) v = fmaxf(v, 0.0f);
        Cv[offC + (row + r) * ldc + col] = v;
      }
    }
  }
}

__global__ void embed_kernel(const int* __restrict__ tgt, const float* __restrict__ emb,
                             float* __restrict__ x) {
  const int row = blockIdx.x;
  const int t = row & (kT - 1);
  const int tok = tgt[row];
  const int c = threadIdx.x * 4;
  float4 e = *(const float4*)(emb + (long)tok * kD + c);
  const float nl = -9.210340371976184f / (float)kD;
  const float a0 = (float)t * expf((float)c * nl);
  const float a1 = (float)t * expf((float)(c + 2) * nl);
  float4 o;
  o.x = e.x * 32.0f + sinf(a0);
  o.y = e.y * 32.0f + cosf(a0);
  o.z = e.z * 32.0f + sinf(a1);
  o.w = e.w * 32.0f + cosf(a1);
  *(float4*)(x + (long)row * kD + c) = o;
}

__global__ void transpose_v_kernel(const float* __restrict__ v, u16* __restrict__ vt) {
  __shared__ float tile[32][33];
  const int z = blockIdx.z;
  const int b = z >> 4, h = z & 15;
  const int t0 = blockIdx.x * 32, d0 = blockIdx.y * 32;
  const int tx = threadIdx.x, ty = threadIdx.y;
  const float* in = v + (long)b * kTD + (long)h * kDK;
#pragma unroll
  for (int i = 0; i < 4; ++i)
    tile[ty + 8 * i][tx] = in[(long)(t0 + ty + 8 * i) * kD + d0 + tx];
  __syncthreads();
  u16* o = vt + (long)z * kDK * kT;
#pragma unroll
  for (int i = 0; i < 4; ++i)
    o[(long)(d0 + ty + 8 * i) * kT + t0 + tx] = f2bf(tile[tx][ty + 8 * i]);
}

__global__ void softmax_kernel(float* __restrict__ w, const int causal) {
  const int rowg = blockIdx.x * 4 + (threadIdx.x >> 6);
  const int lane = threadIdx.x & 63;
  const int q = rowg & (kT - 1);
  float* p = w + (long)rowg * kT + lane * 8;
  float4 v0 = *(const float4*)p;
  float4 v1 = *(const float4*)(p + 4);
  float f[8] = {v0.x, v0.y, v0.z, v0.w, v1.x, v1.y, v1.z, v1.w};
  const int base = lane * 8;
  float mx = -3.0e38f;
#pragma unroll
  for (int j = 0; j < 8; ++j)
    if (!causal || base + j <= q) mx = fmaxf(mx, f[j]);
#pragma unroll
  for (int o = 32; o > 0; o >>= 1) mx = fmaxf(mx, __shfl_xor(mx, o));
  float s = 0.0f;
#pragma unroll
  for (int j = 0; j < 8; ++j) {
    float e = (!causal || base + j <= q) ? __expf(f[j] - mx) : 0.0f;
    f[j] = e; s += e;
  }
#pragma unroll
  for (int o = 32; o > 0; o >>= 1) s += __shfl_xor(s, o);
  const float inv = 1.0f / s;
  float4 o0 = {f[0] * inv, f[1] * inv, f[2] * inv, f[3] * inv};
  float4 o1 = {f[4] * inv, f[5] * inv, f[6] * inv, f[7] * inv};
  *(float4*)p = o0;
  *(float4*)(p + 4) = o1;
}

__global__ void add_ln_kernel(float* __restrict__ x, const float* __restrict__ res,
                              const float* __restrict__ g, const float* __restrict__ b) {
  const int row = blockIdx.x;
  const int c = threadIdx.x * 4;
  float4 xv = *(const float4*)(x + (long)row * kD + c);
  float4 rv = *(const float4*)(res + (long)row * kD + c);
  const float v0 = xv.x + rv.x, v1 = xv.y + rv.y, v2 = xv.z + rv.z, v3 = xv.w + rv.w;
  float s = v0 + v1 + v2 + v3;
  float ss = v0 * v0 + v1 * v1 + v2 * v2 + v3 * v3;
#pragma unroll
  for (int o = 32; o > 0; o >>= 1) { s += __shfl_xor(s, o); ss += __shfl_xor(ss, o); }
  __shared__ float red[4][2];
  const int wv = threadIdx.x >> 6;
  if ((threadIdx.x & 63) == 0) { red[wv][0] = s; red[wv][1] = ss; }
  __syncthreads();
  s  = red[0][0] + red[1][0] + red[2][0] + red[3][0];
  ss = red[0][1] + red[1][1] + red[2][1] + red[3][1];
  const float mean = s * (1.0f / kD);
  const float var = ss * (1.0f / kD) - mean * mean;
  const float rs = rsqrtf(var + 1e-5f);
  float4 gv = *(const float4*)(g + c);
  float4 bv = *(const float4*)(b + c);
  float4 o;
  o.x = gv.x * (v0 - mean) * rs + bv.x;
  o.y = gv.y * (v1 - mean) * rs + bv.y;
  o.z = gv.z * (v2 - mean) * rs + bv.z;
  o.w = gv.w * (v3 - mean) * rs + bv.w;
  *(float4*)(x + (long)row * kD + c) = o;
}

// ===========================================================================
extern "C" void kernel_launch(void* const* d_in, const int* in_sizes, int n_in,
                              void* d_out, int out_size, void* d_ws, size_t ws_size,
                              hipStream_t stream) {
  const int*   tgt  = (const int*)d_in[0];
  const float* enc  = (const float*)d_in[1];
  const float* emb  = (const float*)d_in[3];
  const float* Wout = (const float*)d_in[4];
  const float* bout = (const float*)d_in[5];
  const float* Wq_s = (const float*)d_in[6];
  const float* bq_s = (const float*)d_in[7];
  const float* Wk_s = (const float*)d_in[8];
  const float* bk_s = (const float*)d_in[9];
  const float* Wv_s = (const float*)d_in[10];
  const float* bv_s = (const float*)d_in[11];
  const float* Wo_s = (const float*)d_in[12];
  const float* bo_s = (const float*)d_in[13];
  const float* Wq_c = (const float*)d_in[14];
  const float* bq_c = (const float*)d_in[15];
  const float* Wk_c = (const float*)d_in[16];
  const float* bk_c = (const float*)d_in[17];
  const float* Wv_c = (const float*)d_in[18];
  const float* bv_c = (const float*)d_in[19];
  const float* Wo_c = (const float*)d_in[20];
  const float* bo_c = (const float*)d_in[21];
  const float* W1   = (const float*)d_in[22];
  const float* b1   = (const float*)d_in[23];
  const float* W2   = (const float*)d_in[24];
  const float* b2   = (const float*)d_in[25];
  const float* ln1g = (const float*)d_in[26];
  const float* ln1b = (const float*)d_in[27];
  const float* ln2g = (const float*)d_in[28];
  const float* ln2b = (const float*)d_in[29];
  const float* ln3g = (const float*)d_in[30];
  const float* ln3b = (const float*)d_in[31];

  float* out = (float*)d_out;
  const long DD = (long)kD * kD;
  const dim3 blk256(256), blkT(32, 8);

  if (ws_size >= (320ll << 20)) {
    // =================== FAST PATH ===================
    char* ws = (char*)d_ws;
    float* x     = (float*)ws;                    // 8 MiB
    u16* xb      = (u16*)(ws + (8l << 20));       // 4 MiB (contiguous with encb)
    u16* encb    = (u16*)(ws + (12l << 20));      // 4 MiB (A source, merged cross)
    u16* encb2   = (u16*)(ws + (16l << 20));      // 4 MiB (second copy for V slice)
    u16* Sqkv    = (u16*)(ws + (20l << 20));      // 12 MiB (2048x3072)
    u16* vt      = (u16*)(ws + (32l << 20));      // 4 MiB (B,H,dk,T)
    u16* S3b     = (u16*)(ws + (36l << 20));      // 4 MiB
    u16* Hb      = (u16*)(ws + (40l << 20));      // 16 MiB (2048x4096)
    float* Spart = (float*)(ws + (56l << 20));    // 32 MiB (4 f32 partials)
    u16* wbase   = (u16*)(ws + (88l << 20));      // 128 MiB
    u16* woutT   = (u16*)(ws + (216l << 20));     // 62.5 MiB
    float* bqkvS = (float*)(ws + (280l << 20));   // 48 KiB
    float* bqkvC = (float*)(ws + (280l << 20) + (64l << 10));  // 48 KiB
    const long WLAY = 16l * 1024 * 1024;          // u16 elems per layer block

    // ---- one-time prep ----
    for (int i = 0; i < kL; ++i) {
      u16* wqkvS = wbase + i * WLAY;
      u16* woS   = wqkvS + 3072 * 1024;
      u16* wqkvC = woS + 1024 * 1024;
      u16* woC   = wqkvC + 3072 * 1024;
      u16* w1t   = woC + 1024 * 1024;
      u16* w2t   = w1t + (long)4096 * 1024;
      TPtrs p{};
      p.in[0] = Wq_s + i * DD; p.out[0] = wqkvS;
      p.in[1] = Wk_s + i * DD; p.out[1] = wqkvS + 1024 * 1024;
      p.in[2] = Wv_s + i * DD; p.out[2] = wqkvS + 2048 * 1024;
      p.in[3] = Wo_s + i * DD; p.out[3] = woS;
      p.in[4] = Wq_c + i * DD; p.out[4] = wqkvC;
      p.in[5] = Wk_c + i * DD; p.out[5] = wqkvC + 1024 * 1024;
      p.in[6] = Wv_c + i * DD; p.out[6] = wqkvC + 2048 * 1024;
      p.in[7] = Wo_c + i * DD; p.out[7] = woC;
      transpose_wt_v3<<<dim3(16, 16, 8), blk256, 0, stream>>>(p, 1024, 1024);
      TPtrs p1{}; p1.in[0] = W1 + (long)i * kD * kF; p1.out[0] = w1t;
      transpose_wt_v3<<<dim3(64, 16, 1), blk256, 0, stream>>>(p1, 1024, 4096);
      TPtrs p2{}; p2.in[0] = W2 + (long)i * kF * kD; p2.out[0] = w2t;
      transpose_wt_v3<<<dim3(16, 64, 1), blk256, 0, stream>>>(p2, 4096, 1024);
    }
    TPtrs po{}; po.in[0] = Wout; po.out[0] = woutT;
    transpose_wt_v3<<<dim3(500, 16, 1), blk256, 0, stream>>>(po, 1024, 32000);
    concat_bias<<<dim3(48), blk256, 0, stream>>>(bqkvS, bq_s, bk_s, bv_s, 3);
    concat_bias<<<dim3(48), blk256, 0, stream>>>(bqkvC, bq_c, bk_c, bv_c, 3);
    cvt_bf16_v3<<<dim3(2048), blk256, 0, stream>>>(enc, encb, encb2);
    embed_v2<<<dim3(kM), blk256, 0, stream>>>(tgt, emb, x, xb);

    for (int i = 0; i < kL; ++i) {
      u16* wqkvS = wbase + i * WLAY;
      u16* woS   = wqkvS + 3072 * 1024;
      u16* wqkvC = woS + 1024 * 1024;
      u16* woC   = wqkvC + 3072 * 1024;
      u16* w1t   = woC + 1024 * 1024;
      u16* w2t   = w1t + (long)4096 * 1024;
      float* wSelf  = out + kLOG + (long)i * kBHTT;
      float* wCross = out + kLOG + (long)kL * kBHTT + (long)i * kBHTT;

      // -------- self attention --------
      gemm_bf<128, 128, 1, 1, 1><<<dim3(24, 16, 1), blk256, 0, stream>>>(
          xb, wqkvS, bqkvS + i * 3072, Sqkv, vt, 1024, 1024, 1024, 3072,
          1, 0, 0, 0, 0, 0, 0, 1.0f, 0, 0);
      attn_fused<1><<<dim3(4, 64), dim3(512), 0, stream>>>(Sqkv, Sqkv + 1024, vt, wSelf, S3b);
      // O-proj: split-K x4 (K=256 each), single-buffer GEMM, 512 blocks
      gemm_bf<128, 128, 0, 0, 0><<<dim3(8, 16, 4), blk256, 0, stream>>>(
          S3b, woS, bo_s + (long)i * kD, Spart, nullptr, 256, 1024, 1024, 1024,
          1, 256, 0, 256, 0, kPART, 0, 1.0f, 0, 0);
      add_ln_v3<<<dim3(kM), blk256, 0, stream>>>(x, xb, Spart, 4,
          ln1g + (long)i * kD, ln1b + (long)i * kD);

      // -------- cross attention (merged Q/K/V via z: xb|encb|encb2) --------
      gemm_bf<128, 128, 1, 1, 1><<<dim3(8, 16, 3), blk256, 0, stream>>>(
          xb, wqkvC, bqkvC + i * 3072, Sqkv, vt, 1024, 1024, 1024, 3072,
          3, 0, (long)2048 * 1024, 0, (long)1024 * 1024, 0, 1024, 1.0f, 0, 1024);
      attn_fused<0><<<dim3(4, 64), dim3(512), 0, stream>>>(Sqkv, Sqkv + 1024, vt, wCross, S3b);
      gemm_bf<128, 128, 0, 0, 0><<<dim3(8, 16, 4), blk256, 0, stream>>>(
          S3b, woC, bo_c + (long)i * kD, Spart, nullptr, 256, 1024, 1024, 1024,
          1, 256, 0, 256, 0, kPART, 0, 1.0f, 0, 0);
      add_ln_v3<<<dim3(kM), blk256, 0, stream>>>(x, xb, Spart, 4,
          ln2g + (long)i * kD, ln2b + (long)i * kD);

      // -------- FFN --------
      gemm_bf<128, 128, 1, 0, 1><<<dim3(32, 16, 1), blk256, 0, stream>>>(
          xb, w1t, b1 + (long)i * kF, Hb, nullptr, 1024, 1024, 1024, 4096,
          1, 0, 0, 0, 0, 0, 0, 1.0f, 1, 0);
      // FFN2: split-K x4 (K=1024 each), single-buffer GEMM, 512 blocks
      gemm_bf<128, 128, 0, 0, 0><<<dim3(8, 16, 4), blk256, 0, stream>>>(
          Hb, w2t, b2 + (long)i * kD, Spart, nullptr, 1024, 4096, 4096, 1024,
          1, 1024, 0, 1024, 0, kPART, 0, 1.0f, 0, 0);
      add_ln_v3<<<dim3(kM), blk256, 0, stream>>>(x, xb, Spart, 4,
          ln3g + (long)i * kD, ln3b + (long)i * kD);
    }

    gemm_bf<128, 128, 0, 0, 1><<<dim3(250, 16, 1), blk256, 0, stream>>>(
        xb, woutT, bout, out, nullptr, 1024, 1024, 1024, 32000,
        1, 0, 0, 0, 0, 0, 0, 1.0f, 0, 0);
    return;
  }

  // =================== FALLBACK (Round-3 verified) ===================
  float* x = (float*)d_ws;
  char* sc = (char*)d_out;
  float* S0 = (float*)sc;
  float* S1 = (float*)(sc + (8l  << 20));
  float* S2 = (float*)(sc + (16l << 20));
  float* S3 = (float*)(sc + (24l << 20));
  float* S4 = (float*)(sc + (32l << 20));
  u16*   vt = (u16*)  (sc + (40l << 20));

  embed_kernel<<<dim3(kM), blk256, 0, stream>>>(tgt, emb, x);
  auto wgemm = [&](const float* A, const float* W, const float* bias, float* C) {
    gemm_kernel<128, 128, float, float, 1><<<dim3(kD / 128, kM / 128, 1), blk256, 0, stream>>>(
        A, W, bias, C, kD, kD, kD, kD, 1, 0, 0, 0, 0, 0, 0, 1.0f, 0);
  };
  for (int i = 0; i < kL; ++i) {
    const long wOff = (long)i * DD;
    float* wSelf  = out + kLOG + (long)i * kBHTT;
    float* wCross = out + kLOG + (long)kL * kBHTT + (long)i * kBHTT;
    wgemm(x, Wq_s + wOff, bq_s + (long)i * kD, S0);
    wgemm(x, Wk_s + wOff, bk_s + (long)i * kD, S1);
    wgemm(x, Wv_s + wOff, bv_s + (long)i * kD, S2);
    transpose_v_kernel<<<dim3(16, 2, 64), blkT, 0, stream>>>(S2, vt);
    gemm_kernel<128, 128, float, float, 0><<<dim3(4, 4, 64), blk256, 0, stream>>>(
        S0, S1, nullptr, wSelf, kDK, kD, kD, kT,
        kH, kTD, (long)kDK, kTD, (long)kDK, kHTT, kTT, 0.125f, 0);
    softmax_kernel<<<dim3(kB * kH * kT / 4), blk256, 0, stream>>>(wSelf, 1);
    gemm_kernel<128, 64, float, u16, 0><<<dim3(1, 4, 64), blk256, 0, stream>>>(
        wSelf, vt, nullptr, S3, kT, kT, kT, kD,
        kH, kHTT, kTT, (long)kH * kDK * kT, (long)kDK * kT, kTD, (long)kDK, 1.0f, 0);
    wgemm(S3, Wo_s + wOff, bo_s + (long)i * kD, S0);
    add_ln_kernel<<<dim3(kM), blk256, 0, stream>>>(x, S0, ln1g + (long)i * kD, ln1b + (long)i * kD);
    wgemm(x,   Wq_c + wOff, bq_c + (long)i * kD, S0);
    wgemm(enc, Wk_c + wOff, bk_c + (long)i * kD, S1);
    wgemm(enc, Wv_c + wOff, bv_c + (long)i * kD, S2);
    transpose_v_kernel<<<dim3(16, 2, 64), blkT, 0, stream>>>(S2, vt);
    gemm_kernel<128, 128, float, float, 0><<<dim3(4, 4, 64), blk256, 0, stream>>>(
        S0, S1, nullptr, wCross, kDK, kD, kD, kT,
        kH, kTD, (long)kDK, kTD, (long)kDK, kHTT, kTT, 0.125f, 0);
    softmax_kernel<<<dim3(kB * kH * kT / 4), blk256, 0, stream>>>(wCross, 0);
    gemm_kernel<128, 64, float, u16, 0><<<dim3(1, 4, 64), blk256, 0, stream>>>(
        wCross, vt, nullptr, S3, kT, kT, kT, kD,
        kH, kHTT, kTT, (long)kH * kDK * kT, (long)kDK * kT, kTD, (long)kDK, 1.0f, 0);
    wgemm(S3, Wo_c + wOff, bo_c + (long)i * kD, S0);
    add_ln_kernel<<<dim3(kM), blk256, 0, stream>>>(x, S0, ln2g + (long)i * kD, ln2b + (long)i * kD);
    gemm_kernel<128, 128, float, float, 1><<<dim3(kF / 128, kM / 128, 1), blk256, 0, stream>>>(
        x, W1 + (long)i * kD * kF, b1 + (long)i * kF, S0, kD, kD, kF, kF,
        1, 0, 0, 0, 0, 0, 0, 1.0f, 1);
    gemm_kernel<128, 128, float, float, 1><<<dim3(kD / 128, kM / 128, 1), blk256, 0, stream>>>(
        S0, W2 + (long)i * kF * kD, b2 + (long)i * kD, S4, kF, kF, kD, kD,
        1, 0, 0, 0, 0, 0, 0, 1.0f, 0);
    add_ln_kernel<<<dim3(kM), blk256, 0, stream>>>(x, S4, ln3g + (long)i * kD, ln3b + (long)i * kD);
  }
  gemm_kernel<128, 128, float, float, 1><<<dim3(kV / 128, kM / 128, 1), blk256, 0, stream>>>(
      x, Wout, bout, out, kD, kD, kV, kV,
      1, 0, 0, 0, 0, 0, 0, 1.0f, 0);
}